// Round 10
// baseline (2488.239 us; speedup 1.0000x reference)
//
#include <hip/hip_runtime.h>
#include <hip/hip_bf16.h>
#include <cstdint>

typedef unsigned short u16;
typedef unsigned short us8 __attribute__((ext_vector_type(8)));
typedef __bf16 bf16x8 __attribute__((ext_vector_type(8)));
typedef float f32x4 __attribute__((ext_vector_type(4)));

// ---------- helpers ----------
__device__ __forceinline__ float b2f(u16 u) {
    union { float f; uint32_t i; } x; x.i = ((uint32_t)u) << 16; return x.f;
}
__device__ __forceinline__ u16 f2b(float f) {
    uint32_t u = __float_as_uint(f);
    uint32_t r = (u + 0x7FFFu + ((u >> 16) & 1u)) >> 16;
    return (u16)r;
}
__device__ __forceinline__ float sigm(float x) { return 1.0f / (1.0f + __expf(-x)); }
__device__ __forceinline__ float ldv(const void* p, size_t i, int dt) {
    return dt ? b2f(((const u16*)p)[i]) : ((const float*)p)[i];
}

__device__ __forceinline__ float wave_sum(float v) {
#pragma unroll
    for (int o = 32; o > 0; o >>= 1) v += __shfl_xor(v, o, 64);
    return v;
}
__device__ __forceinline__ void block_reduce2(float& a, float& b, float* sm) {
    int tid = threadIdx.x, wid = tid >> 6, lane = tid & 63;
    float as = wave_sum(a), bs = wave_sum(b);
    __syncthreads();
    if (lane == 0) { sm[wid] = as; sm[8 + wid] = bs; }
    __syncthreads();
    a = sm[0] + sm[1] + sm[2] + sm[3];
    b = sm[8] + sm[9] + sm[10] + sm[11];
}

// 64-lane sum via DPP ladder; full sum lands in lane 63.
__device__ __forceinline__ float dpp_sum64(float x) {
    x += __int_as_float(__builtin_amdgcn_update_dpp(0, __float_as_int(x), 0x111, 0xf, 0xf, true)); // row_shr:1
    x += __int_as_float(__builtin_amdgcn_update_dpp(0, __float_as_int(x), 0x112, 0xf, 0xf, true)); // row_shr:2
    x += __int_as_float(__builtin_amdgcn_update_dpp(0, __float_as_int(x), 0x114, 0xf, 0xf, true)); // row_shr:4
    x += __int_as_float(__builtin_amdgcn_update_dpp(0, __float_as_int(x), 0x118, 0xf, 0xf, true)); // row_shr:8
    x += __int_as_float(__builtin_amdgcn_update_dpp(0, __float_as_int(x), 0x142, 0xa, 0xf, true)); // row_bcast:15
    x += __int_as_float(__builtin_amdgcn_update_dpp(0, __float_as_int(x), 0x143, 0xc, 0xf, true)); // row_bcast:31
    return x;
}

// ---------- probe: dtype (hdr[0]) + which big array is x (hdr[1]) ----------
__global__ void k_probe(const u16* __restrict__ a0, const u16* __restrict__ a1,
                        const u16* __restrict__ a2, int* __restrict__ hdr) {
    __shared__ int wcnt;
    __shared__ float part[256];
    __shared__ float mag[3];
    int tid = threadIdx.x;
    if (tid == 0) wcnt = 0;
    __syncthreads();
    const u16* arr[3] = { a0, a1, a2 };
    int wild = 0;
    for (int s = 0; s < 3; ++s)
        for (int i = tid; i < 4096; i += 256) {
            u16 u = arr[s][i];
            int e = (u >> 7) & 0xFF;
            float av = fabsf(b2f(u));
            if (e == 0xFF || av > 100.f) wild++;
        }
    atomicAdd(&wcnt, wild);
    __syncthreads();
    int dt = (wcnt < 96) ? 1 : 0;
    for (int s = 0; s < 3; ++s) {
        float m = 0.f;
        if (dt) { for (int i = tid; i < 4096; i += 256) m += fabsf(b2f(arr[s][i])); }
        else    { const float* f = (const float*)arr[s];
                  for (int i = tid; i < 2048; i += 256) m += fabsf(f[i]); }
        part[tid] = m; __syncthreads();
        if (tid == 0) { float t = 0; for (int i = 0; i < 256; ++i) t += part[i]; mag[s] = t; }
        __syncthreads();
    }
    if (tid == 0) {
        int xs = 0;
        if (mag[1] > mag[xs]) xs = 1;
        if (mag[2] > mag[xs]) xs = 2;   // x ~N(0,1) vs 0.02-scale weights
        hdr[0] = dt; hdr[1] = xs;
    }
}

// ---------- double layernorm: x -> resid bf16, hs bf16 ----------
__global__ __launch_bounds__(256) void k_ln_in(
    const void* __restrict__ xa, const void* __restrict__ xb, const void* __restrict__ xc,
    const void* __restrict__ pw, const void* __restrict__ pb,
    const void* __restrict__ aw, const void* __restrict__ ab,
    u16* __restrict__ resid, u16* __restrict__ hs, const int* __restrict__ hdr)
{
    __shared__ float sm[16];
    const int dt = hdr[0], xs = hdr[1];
    const void* x = (xs == 0) ? xa : (xs == 1 ? xb : xc);
    int tok = blockIdx.x, tid = threadIdx.x;
    int c = tid * 4;
    size_t off = (size_t)tok * 1024 + c;
    float v0, v1, v2, v3;
    if (dt) {
        ushort4 xv = *(const ushort4*)((const u16*)x + off);
        v0 = b2f(xv.x); v1 = b2f(xv.y); v2 = b2f(xv.z); v3 = b2f(xv.w);
    } else {
        float4 xv = *(const float4*)((const float*)x + off);
        v0 = xv.x; v1 = xv.y; v2 = xv.z; v3 = xv.w;
    }
    float s = v0 + v1 + v2 + v3;
    float q = v0*v0 + v1*v1 + v2*v2 + v3*v3;
    block_reduce2(s, q, sm);
    float mean = s * (1.f/1024.f);
    float var  = q * (1.f/1024.f) - mean*mean;
    float rs = rsqrtf(var + 1e-5f);
    float h0 = (v0-mean)*rs*ldv(pw,c+0,dt) + ldv(pb,c+0,dt);
    float h1 = (v1-mean)*rs*ldv(pw,c+1,dt) + ldv(pb,c+1,dt);
    float h2 = (v2-mean)*rs*ldv(pw,c+2,dt) + ldv(pb,c+2,dt);
    float h3 = (v3-mean)*rs*ldv(pw,c+3,dt) + ldv(pb,c+3,dt);
    ushort4 rv; rv.x = f2b(h0); rv.y = f2b(h1); rv.z = f2b(h2); rv.w = f2b(h3);
    *(ushort4*)(resid + off) = rv;
    float s2 = h0 + h1 + h2 + h3;
    float q2 = h0*h0 + h1*h1 + h2*h2 + h3*h3;
    block_reduce2(s2, q2, sm);
    float m2 = s2 * (1.f/1024.f);
    float vr2 = q2 * (1.f/1024.f) - m2*m2;
    float rs2 = rsqrtf(vr2 + 1e-5f);
    ushort4 o;
    o.x = f2b((h0-m2)*rs2*ldv(aw,c+0,dt) + ldv(ab,c+0,dt));
    o.y = f2b((h1-m2)*rs2*ldv(aw,c+1,dt) + ldv(ab,c+1,dt));
    o.z = f2b((h2-m2)*rs2*ldv(aw,c+2,dt) + ldv(ab,c+2,dt));
    o.w = f2b((h3-m2)*rs2*ldv(aw,c+3,dt) + ldv(ab,c+3,dt));
    *(ushort4*)(hs + off) = o;
}

// ---------- layernorm bf16(ws) -> bf16 ----------
__global__ __launch_bounds__(256) void k_ln_bf(
    const u16* __restrict__ in, const void* __restrict__ w, const void* __restrict__ b,
    u16* __restrict__ out, const int* __restrict__ hdr)
{
    __shared__ float sm[16];
    const int dt = hdr[0];
    int tok = blockIdx.x, tid = threadIdx.x;
    int c = tid * 4;
    size_t off = (size_t)tok * 1024 + c;
    ushort4 xv = *(const ushort4*)(in + off);
    float v0 = b2f(xv.x), v1 = b2f(xv.y), v2 = b2f(xv.z), v3 = b2f(xv.w);
    float s = v0 + v1 + v2 + v3;
    float q = v0*v0 + v1*v1 + v2*v2 + v3*v3;
    block_reduce2(s, q, sm);
    float mean = s * (1.f/1024.f);
    float var  = q * (1.f/1024.f) - mean*mean;
    float rs = rsqrtf(var + 1e-5f);
    ushort4 o;
    o.x = f2b((v0-mean)*rs*ldv(w,c+0,dt) + ldv(b,c+0,dt));
    o.y = f2b((v1-mean)*rs*ldv(w,c+1,dt) + ldv(b,c+1,dt));
    o.z = f2b((v2-mean)*rs*ldv(w,c+2,dt) + ldv(b,c+2,dt));
    o.w = f2b((v3-mean)*rs*ldv(w,c+3,dt) + ldv(b,c+3,dt));
    *(ushort4*)(out + off) = o;
}

// ---------- weight transpose: W[K][N] (f32|bf16) -> WT[N][K] bf16 ----------
__global__ __launch_bounds__(256) void k_tr(
    const void* __restrict__ W, int K, int N, u16* __restrict__ WT,
    const int* __restrict__ hdr)
{
    const int dt = hdr[0];
    __shared__ u16 t[32][33];
    int n0 = blockIdx.x * 32, k0 = blockIdx.y * 32;
    int tx = threadIdx.x & 31, ty = threadIdx.x >> 5;   // 32 x 8
#pragma unroll
    for (int r = 0; r < 32; r += 8) {
        int k = k0 + ty + r;
        t[ty + r][tx] = f2b(ldv(W, (size_t)k * N + n0 + tx, dt));  // f2b(b2f(u))==u
    }
    __syncthreads();
#pragma unroll
    for (int r = 0; r < 32; r += 8) {
        int n = n0 + ty + r;
        WT[(size_t)n * K + k0 + tx] = t[tx][ty + r];
    }
}

// ---------- shared epilogue for MFMA GEMMs ----------
// modes: 1=raw 2=tanh 3=sigm 4=exp(-0.6065*sigm(v+bias)) 5=sigm(v+bias)
//        6=F32 OUT v+add 7=relu^2 8=bf16 v+add
__device__ __forceinline__ void mf_epi(
    void* D, int ldd, int mode, const void* bias,
    const u16* add, int ldadd, int dt,
    int row, int col, float v)
{
    size_t di = (size_t)row * ldd + col;
    if (mode == 6) {
        ((float*)D)[di] = v + b2f(add[(size_t)row * ldadd + col]);
        return;
    }
    float rr;
    switch (mode) {
        default: rr = v; break;
        case 2: rr = tanhf(v); break;
        case 3: rr = sigm(v); break;
        case 4: rr = __expf(-0.6065306597126334f * sigm(v + ldv(bias, col, dt))); break;
        case 5: rr = sigm(v + ldv(bias, col, dt)); break;
        case 7: { float t = fmaxf(v, 0.f); rr = t * t; } break;
        case 8: rr = v + b2f(add[(size_t)row * ldadd + col]); break;
    }
    ((u16*)D)[di] = f2b(rr);
}

// ---------- MFMA GEMM: 128x128 tile (for N=4096 outputs) ----------
__global__ __launch_bounds__(256, 2) void k_mf(
    const u16* __restrict__ A, int lda, const void* __restrict__ mixc,
    const u16* __restrict__ BT,
    void* __restrict__ D, int ldd,
    int K, int mode,
    const void* __restrict__ bias,
    const u16* __restrict__ add, int ldadd, const int* __restrict__ hdr)
{
    __shared__ u16 As[128 * 40];     // 10240 B
    __shared__ u16 Bs[128 * 40];     // 10240 B
    const int dt = hdr[0];
    const int tid = threadIdx.x;
    const int m0 = blockIdx.y * 128, n0 = blockIdx.x * 128;
    const int wid = tid >> 6, lane = tid & 63;
    const int wr = wid >> 1, wc = wid & 1;
    const int lg = lane >> 4, lc = lane & 15;
    const int srow = tid >> 1, shalf = tid & 1;   // staging: 128 rows x 2 k-halves

    f32x4 acc[4][4];
#pragma unroll
    for (int i = 0; i < 4; ++i)
#pragma unroll
        for (int j = 0; j < 4; ++j) acc[i][j] = (f32x4)0.f;

    for (int kb = 0; kb < K; kb += 32) {
        {
            int gr = m0 + srow;
            const u16* ap = A + (size_t)gr * lda + kb + 16 * shalf;
            us8 c1 = *(const us8*)ap;
            us8 c2 = *(const us8*)(ap + 8);
            if (mixc) {
                const u16* pp = ap - ((gr & 2047) ? lda : 0);
                float pz = (gr & 2047) ? 1.f : 0.f;
                us8 p1 = *(const us8*)pp;
                us8 p2 = *(const us8*)(pp + 8);
                int kbase = kb + 16 * shalf;
#pragma unroll
                for (int e = 0; e < 8; ++e) {
                    float cu1 = b2f(c1[e]), cu2 = b2f(c2[e]);
                    c1[e] = f2b(cu1 + (pz * b2f(p1[e]) - cu1) * ldv(mixc, kbase + e, dt));
                    c2[e] = f2b(cu2 + (pz * b2f(p2[e]) - cu2) * ldv(mixc, kbase + 8 + e, dt));
                }
            }
            u16* dst = As + srow * 40 + 16 * shalf;
            *(us8*)dst = c1;
            *(us8*)(dst + 8) = c2;
        }
        {
            const u16* bp = BT + (size_t)(n0 + srow) * K + kb + 16 * shalf;
            u16* dst = Bs + srow * 40 + 16 * shalf;
            *(us8*)dst = *(const us8*)bp;
            *(us8*)(dst + 8) = *(const us8*)(bp + 8);
        }
        __syncthreads();
        bf16x8 af[4], bf[4];
#pragma unroll
        for (int fm = 0; fm < 4; ++fm) {
            const u16* p = As + (wr * 64 + fm * 16 + lc) * 40 + lg * 8;
            union { us8 s; bf16x8 v; } u;
            u.s = *(const us8*)p;
            af[fm] = u.v;
        }
#pragma unroll
        for (int fc = 0; fc < 4; ++fc) {
            const u16* p = Bs + (wc * 64 + fc * 16 + lc) * 40 + lg * 8;
            union { us8 s; bf16x8 v; } u;
            u.s = *(const us8*)p;
            bf[fc] = u.v;
        }
#pragma unroll
        for (int fm = 0; fm < 4; ++fm)
#pragma unroll
            for (int fc = 0; fc < 4; ++fc)
                acc[fm][fc] = __builtin_amdgcn_mfma_f32_16x16x32_bf16(
                    af[fm], bf[fc], acc[fm][fc], 0, 0, 0);
        __syncthreads();
    }

#pragma unroll
    for (int fm = 0; fm < 4; ++fm)
#pragma unroll
        for (int fc = 0; fc < 4; ++fc)
#pragma unroll
            for (int r = 0; r < 4; ++r)
                mf_epi(D, ldd, mode, bias, add, ldadd, dt,
                       m0 + wr * 64 + fm * 16 + lg * 4 + r,
                       n0 + wc * 64 + fc * 16 + lc, acc[fm][fc][r]);
}

// ---------- MFMA GEMM: 64x64 tile (for N<=1024 outputs) ----------
__global__ __launch_bounds__(256, 4) void k_mf64(
    const u16* __restrict__ A, int lda, const void* __restrict__ mixc,
    const u16* __restrict__ BT,
    void* __restrict__ D, int ldd,
    int K, int mode,
    const void* __restrict__ bias,
    const u16* __restrict__ add, int ldadd, const int* __restrict__ hdr)
{
    __shared__ u16 As[64 * 40];      // 5120 B
    __shared__ u16 Bs[64 * 40];      // 5120 B
    const int dt = hdr[0];
    const int tid = threadIdx.x;
    const int m0 = blockIdx.y * 64, n0 = blockIdx.x * 64;
    const int wid = tid >> 6, lane = tid & 63;
    const int wr = wid >> 1, wc = wid & 1;
    const int lg = lane >> 4, lc = lane & 15;
    const int srow = tid >> 2, sq = tid & 3;      // staging: 64 rows x 4 k-quarters

    f32x4 acc[2][2];
#pragma unroll
    for (int i = 0; i < 2; ++i)
#pragma unroll
        for (int j = 0; j < 2; ++j) acc[i][j] = (f32x4)0.f;

    for (int kb = 0; kb < K; kb += 32) {
        {
            int gr = m0 + srow;
            const u16* ap = A + (size_t)gr * lda + kb + 8 * sq;
            us8 c1 = *(const us8*)ap;
            if (mixc) {
                const u16* pp = ap - ((gr & 2047) ? lda : 0);
                float pz = (gr & 2047) ? 1.f : 0.f;
                us8 p1 = *(const us8*)pp;
                int kbase = kb + 8 * sq;
#pragma unroll
                for (int e = 0; e < 8; ++e) {
                    float cu = b2f(c1[e]);
                    c1[e] = f2b(cu + (pz * b2f(p1[e]) - cu) * ldv(mixc, kbase + e, dt));
                }
            }
            *(us8*)(As + srow * 40 + 8 * sq) = c1;
        }
        {
            const u16* bp = BT + (size_t)(n0 + srow) * K + kb + 8 * sq;
            *(us8*)(Bs + srow * 40 + 8 * sq) = *(const us8*)bp;
        }
        __syncthreads();
        bf16x8 af[2], bf[2];
#pragma unroll
        for (int fm = 0; fm < 2; ++fm) {
            const u16* p = As + (wr * 32 + fm * 16 + lc) * 40 + lg * 8;
            union { us8 s; bf16x8 v; } u;
            u.s = *(const us8*)p;
            af[fm] = u.v;
        }
#pragma unroll
        for (int fc = 0; fc < 2; ++fc) {
            const u16* p = Bs + (wc * 32 + fc * 16 + lc) * 40 + lg * 8;
            union { us8 s; bf16x8 v; } u;
            u.s = *(const us8*)p;
            bf[fc] = u.v;
        }
#pragma unroll
        for (int fm = 0; fm < 2; ++fm)
#pragma unroll
            for (int fc = 0; fc < 2; ++fc)
                acc[fm][fc] = __builtin_amdgcn_mfma_f32_16x16x32_bf16(
                    af[fm], bf[fc], acc[fm][fc], 0, 0, 0);
        __syncthreads();
    }

#pragma unroll
    for (int fm = 0; fm < 2; ++fm)
#pragma unroll
        for (int fc = 0; fc < 2; ++fc)
#pragma unroll
            for (int r = 0; r < 4; ++r)
                mf_epi(D, ldd, mode, bias, add, ldadd, dt,
                       m0 + wr * 32 + fm * 16 + lg * 4 + r,
                       n0 + wc * 32 + fc * 16 + lc, acc[fm][fc][r]);
}

// ---------- per-head prep ----------
__global__ __launch_bounds__(256) void k_prep(
    u16* __restrict__ k_bf, const u16* __restrict__ a_buf,
    const void* __restrict__ k_k, const void* __restrict__ k_a,
    u16* __restrict__ av, u16* __restrict__ bv, const int* __restrict__ hdr)
{
    const int dt = hdr[0];
    int ht = blockIdx.x * 4 + (threadIdx.x >> 6);
    int j = threadIdx.x & 63;
    int tok = ht >> 4, h = ht & 15, n = h * 64 + j;
    size_t idx = (size_t)tok * 1024 + n;
    float kv = b2f(k_bf[idx]);
    float a  = b2f(a_buf[idx]);
    float kk = kv * ldv(k_k, n, dt);
    float ss = wave_sum(kk * kk);
    float den = fmaxf(sqrtf(ss), 1e-12f);
    float kkn = kk / den;
    k_bf[idx] = f2b(kv * (1.f + (a - 1.f) * ldv(k_a, n, dt)));
    av[idx] = f2b(-kkn);
    bv[idx] = f2b(kkn * a);
}

// ---------- recurrence v6: v5 columns-pair + LEAN depth-8 prefetch ----------
// R7-R9 diagnosis: all prefetch-1 variants pin at ~675 cy/step == HBM
// first-touch latency (waves sharing a bh advance in lockstep, colliding on
// the same un-fetched line each step). R6's depth-8 failed on issue cost:
// u16 slot arrays were bit-packed (insert/extract) and 16-30KB offsets
// regenerated 64-bit address math. v6: uint32_t slots (zext ushort loads,
// 1 VGPR each, no packing) + two running 32-bit byte offsets (+2048/step).
__global__ __launch_bounds__(256) void k_rec(
    const u16* __restrict__ r_bf, const u16* __restrict__ dcy,
    const u16* __restrict__ km, const u16* __restrict__ v_bf,
    const u16* __restrict__ av, const u16* __restrict__ bv,
    u16* __restrict__ o_buf)
{
    const int T = 2048;
    int rq = blockIdx.x & 7, q = blockIdx.x >> 3;   // xcd slot, 8 blocks per bh
    int wid = threadIdx.x >> 6, lane = threadIdx.x & 63;
    int bh = rq * 4 + (q >> 3);          // 0..31
    int jj = (q & 7) * 4 + wid;          // 0..31 column pair -> cols 2jj, 2jj+1
    int b = bh >> 4, h = bh & 15;
    uint32_t off  = (uint32_t)(((b * T) * 1024 + h * 64 + lane) * 2);  // u16 byte off
    uint32_t voff = (uint32_t)(((b * T) * 512 + h * 32 + jj) * 4);     // u32 byte off
    uint32_t ooff = voff;
    uint32_t R[8], Dd[8], Kk[8], Aa[8], Bb[8], Vv[8];
#pragma unroll
    for (int u = 0; u < 8; ++u) {        // prologue: steps 0..7 in flight
        R[u]  = *(const u16*)((const char*)r_bf + off);
        Dd[u] = *(const u16*)((const char*)dcy  + off);
        Kk[u] = *(const u16*)((const char*)km   + off);
        Aa[u] = *(const u16*)((const char*)av   + off);
        Bb[u] = *(const u16*)((const char*)bv   + off);
        Vv[u] = *(const uint32_t*)((const char*)v_bf + voff);
        off += 2048; voff += 2048;       // now points at step 8
    }
    float S0 = 0.f, S1 = 0.f;
    for (int t0 = 0; t0 < T; t0 += 8) {
        bool more = (t0 + 8) < T;
#pragma unroll
        for (int u = 0; u < 8; ++u) {
            float rf  = __uint_as_float(R[u]  << 16);
            float df  = __uint_as_float(Dd[u] << 16);
            float kf  = __uint_as_float(Kk[u] << 16);
            float af  = __uint_as_float(Aa[u] << 16);
            float bf_ = __uint_as_float(Bb[u] << 16);
            uint32_t vv = Vv[u];
            float vf0 = __uint_as_float(vv << 16);
            float vf1 = __uint_as_float(vv & 0xFFFF0000u);
            if (more) {                  // refill slot u for step t0+u+8
                R[u]  = *(const u16*)((const char*)r_bf + off);
                Dd[u] = *(const u16*)((const char*)dcy  + off);
                Kk[u] = *(const u16*)((const char*)km   + off);
                Aa[u] = *(const u16*)((const char*)av   + off);
                Bb[u] = *(const u16*)((const char*)bv   + off);
                Vv[u] = *(const uint32_t*)((const char*)v_bf + voff);
                off += 2048; voff += 2048;
            }
            float sa0 = dpp_sum64(af * S0);
            float sa1 = dpp_sum64(af * S1);
            float X0 = fmaf(kf, vf0, S0 * df);   // independent of sa; overlaps ladders
            float X1 = fmaf(kf, vf1, S1 * df);
            sa0 = __int_as_float(__builtin_amdgcn_readlane(__float_as_int(sa0), 63));
            sa1 = __int_as_float(__builtin_amdgcn_readlane(__float_as_int(sa1), 63));
            S0 = fmaf(bf_, sa0, X0);
            S1 = fmaf(bf_, sa1, X1);
            float o0 = dpp_sum64(rf * S0);
            float o1 = dpp_sum64(rf * S1);
            if (lane == 63)
                *(uint32_t*)((char*)o_buf + ooff) =
                    (uint32_t)f2b(o0) | ((uint32_t)f2b(o1) << 16);
            ooff += 2048;
        }
    }
}

// ---------- groupnorm + bonus + gate ----------
__global__ __launch_bounds__(256) void k_post(
    const u16* __restrict__ o_buf, const u16* __restrict__ r_bf,
    const u16* __restrict__ km, const u16* __restrict__ v_bf,
    const u16* __restrict__ g_buf, const void* __restrict__ r_k,
    const void* __restrict__ gnw, const void* __restrict__ gnb,
    u16* __restrict__ ao, const int* __restrict__ hdr)
{
    const int dt = hdr[0];
    int ht = blockIdx.x * 4 + (threadIdx.x >> 6);
    int j = threadIdx.x & 63;
    int tok = ht >> 4, h = ht & 15, n = h * 64 + j;
    size_t idx = (size_t)tok * 1024 + n;
    float o = b2f(o_buf[idx]);
    float mu = wave_sum(o) * (1.f/64.f);
    float d = o - mu;
    float var = wave_sum(d * d) * (1.f/64.f);
    float og = d * rsqrtf(var + 6.4e-4f) * ldv(gnw, n, dt) + ldv(gnb, n, dt);
    float r = b2f(r_bf[idx]), kmv = b2f(km[idx]), v = b2f(v_bf[idx]);
    float bonus = wave_sum(r * kmv * ldv(r_k, n, dt));
    float val = (og + bonus * v) * b2f(g_buf[idx]);
    ao[idx] = f2b(val);
}

// ---------- host ----------
extern "C" void kernel_launch(void* const* d_in, const int* in_sizes, int n_in,
                              void* d_out, int out_size, void* d_ws, size_t ws_size,
                              hipStream_t stream) {
    (void)in_sizes; (void)n_in; (void)out_size; (void)ws_size;
    const void* xP     = d_in[0];
    const void* pre_w  = d_in[1];
    const void* pre_b  = d_in[2];
    const void* attn_w = d_in[3];
    const void* attn_b = d_in[4];
    const void* ffn_w  = d_in[5];
    const void* ffn_b  = d_in[6];
    const void* x_r    = d_in[7];
    const void* x_w    = d_in[8];
    const void* x_k    = d_in[9];
    const void* x_v    = d_in[10];
    const void* x_a    = d_in[11];
    const void* x_g    = d_in[12];
    const void* W_r    = d_in[13];
    const void* W_k    = d_in[14];
    const void* W_v    = d_in[15];
    const void* W_o    = d_in[16];
    const void* w1     = d_in[17];
    const void* w2     = d_in[18];
    const void* w_b    = d_in[19];
    const void* a1     = d_in[20];
    const void* a2     = d_in[21];
    const void* a_b    = d_in[22];
    const void* g1     = d_in[23];
    const void* g2     = d_in[24];
    const void* k_k    = d_in[25];
    const void* k_a    = d_in[26];
    const void* r_k    = d_in[27];
    const void* gn_w   = d_in[28];
    const void* gn_b   = d_in[29];
    const void* ffn_xk = d_in[30];
    const void* WkeyP  = d_in[31];
    const void* WvalP  = d_in[32];

    char* ws = (char*)d_ws;
    const size_t SL = 8388608ull;          // [4096][1024] bf16 slab
    int* hdr    = (int*)(ws + 0);
    u16* hs     = (u16*)(ws + 4096 + SL*0);
    u16* resid1 = (u16*)(ws + 4096 + SL*1);
    u16* dcy    = (u16*)(ws + 4096 + SL*2);
    u16* r_bf   = (u16*)(ws + 4096 + SL*3);
    u16* k_bf   = (u16*)(ws + 4096 + SL*4);
    u16* v_bf   = (u16*)(ws + 4096 + SL*5);
    u16* av_bf  = (u16*)(ws + 4096 + SL*6);
    u16* bv_bf  = (u16*)(ws + 4096 + SL*7);
    u16* a_buf  = (u16*)(ws + 4096 + SL*8);
    u16* g_buf  = (u16*)(ws + 4096 + SL*9);
    u16* tmpw   = (u16*)(ws + 4096 + SL*10);
    u16* tmpa   = (u16*)(ws + 4096 + SL*10 + 524288);
    u16* tmpg   = (u16*)(ws + 4096 + SL*10 + 1048576);
    u16* wT     = (u16*)(ws + 4096 + SL*10 + 2097152);   // 8MB transpose scratch; peak ~90MB
    // overlays (later lifetimes)
    u16* o_buf  = a_buf;                   // a dead after k_prep
    u16* ao_in  = bv_bf;                   // bv dead after k_rec
    u16* hid2   = dcy;                     // dcy dead after k_rec
    u16* hs2    = hs;                      // hs dead after projections
    u16* ffh    = r_bf;                    // [4096,4096] bf16 over r,k,v,av (dead after k_post)

    dim3 blk(256);
    dim3 gm64(16, 64);                     // 64x64-tile grid for N=1024
    dim3 g4096(32, 32);
    dim3 t1024(32, 32), tKey(128, 32), tVal(32, 128), t64(32, 2), t128(32, 4);
    dim3 tl64(2, 32), tl128(4, 32);        // lora up-weight transposes
    k_probe<<<1, blk, 0, stream>>>((const u16*)xP, (const u16*)WkeyP, (const u16*)WvalP, hdr);
    k_ln_in<<<4096, blk, 0, stream>>>(xP, WkeyP, WvalP, pre_w, pre_b, attn_w, attn_b, resid1, hs, hdr);

    // attn projections (fused token-shift mix) -- all MFMA now
    k_tr<<<t1024, blk, 0, stream>>>(W_r, 1024, 1024, wT, hdr);
    k_mf64<<<gm64, blk, 0, stream>>>(hs, 1024, x_r, wT, r_bf, 1024, 1024, 1, nullptr, nullptr, 0, hdr);
    k_tr<<<tl64, blk, 0, stream>>>(w1, 1024, 64, wT, hdr);
    k_mf64<<<dim3(1, 64), blk, 0, stream>>>(hs, 1024, x_w, wT, tmpw, 64, 1024, 2, nullptr, nullptr, 0, hdr);
    k_tr<<<t64, blk, 0, stream>>>(w2, 64, 1024, wT, hdr);
    k_mf64<<<gm64, blk, 0, stream>>>(tmpw, 64, nullptr, wT, dcy, 1024, 64, 4, w_b, nullptr, 0, hdr);
    k_tr<<<t1024, blk, 0, stream>>>(W_k, 1024, 1024, wT, hdr);
    k_mf64<<<gm64, blk, 0, stream>>>(hs, 1024, x_k, wT, k_bf, 1024, 1024, 1, nullptr, nullptr, 0, hdr);
    k_tr<<<t1024, blk, 0, stream>>>(W_v, 1024, 1024, wT, hdr);
    k_mf64<<<gm64, blk, 0, stream>>>(hs, 1024, x_v, wT, v_bf, 1024, 1024, 1, nullptr, nullptr, 0, hdr);
    k_tr<<<tl64, blk, 0, stream>>>(a1, 1024, 64, wT, hdr);
    k_mf64<<<dim3(1, 64), blk, 0, stream>>>(hs, 1024, x_a, wT, tmpa, 64, 1024, 1, nullptr, nullptr, 0, hdr);
    k_tr<<<t64, blk, 0, stream>>>(a2, 64, 1024, wT, hdr);
    k_mf64<<<gm64, blk, 0, stream>>>(tmpa, 64, nullptr, wT, a_buf, 1024, 64, 5, a_b, nullptr, 0, hdr);
    k_tr<<<tl128, blk, 0, stream>>>(g1, 1024, 128, wT, hdr);
    k_mf64<<<dim3(2, 64), blk, 0, stream>>>(hs, 1024, x_g, wT, tmpg, 128, 1024, 3, nullptr, nullptr, 0, hdr);
    k_tr<<<t128, blk, 0, stream>>>(g2, 128, 1024, wT, hdr);
    k_mf64<<<gm64, blk, 0, stream>>>(tmpg, 128, nullptr, wT, g_buf, 1024, 128, 1, nullptr, nullptr, 0, hdr);

    k_prep<<<16384, blk, 0, stream>>>(k_bf, a_buf, k_k, k_a, av_bf, bv_bf, hdr);
    k_rec<<<256, blk, 0, stream>>>(r_bf, dcy, k_bf, v_bf, av_bf, bv_bf, o_buf);
    k_post<<<16384, blk, 0, stream>>>(o_buf, r_bf, k_bf, v_bf, g_buf, r_k, gn_w, gn_b, ao_in, hdr);

    // output projection + residual -> hid2 (bf16)
    k_tr<<<t1024, blk, 0, stream>>>(W_o, 1024, 1024, wT, hdr);
    k_mf64<<<gm64, blk, 0, stream>>>(ao_in, 1024, nullptr, wT, hid2, 1024, 1024, 8, nullptr, resid1, 1024, hdr);

    // FFN; final GEMM writes FLOAT32 output
    k_ln_bf<<<4096, blk, 0, stream>>>(hid2, ffn_w, ffn_b, hs2, hdr);
    k_tr<<<tKey, blk, 0, stream>>>(WkeyP, 1024, 4096, wT, hdr);
    k_mf<<<g4096, blk, 0, stream>>>(hs2, 1024, ffn_xk, wT, ffh, 4096, 1024, 7, nullptr, nullptr, 0, hdr);
    k_tr<<<tVal, blk, 0, stream>>>(WvalP, 4096, 1024, wT, hdr);
    k_mf64<<<gm64, blk, 0, stream>>>(ffh, 4096, nullptr, wT, (float*)d_out, 1024, 4096, 6, nullptr, hid2, 1024, hdr);
}

// Round 11
// 1361.293 us; speedup vs baseline: 1.8278x; 1.8278x over previous
//
#include <hip/hip_runtime.h>
#include <hip/hip_bf16.h>
#include <cstdint>

typedef unsigned short u16;
typedef unsigned short us8 __attribute__((ext_vector_type(8)));
typedef __bf16 bf16x8 __attribute__((ext_vector_type(8)));
typedef float f32x4 __attribute__((ext_vector_type(4)));

// ---------- helpers ----------
__device__ __forceinline__ float b2f(u16 u) {
    union { float f; uint32_t i; } x; x.i = ((uint32_t)u) << 16; return x.f;
}
__device__ __forceinline__ u16 f2b(float f) {
    uint32_t u = __float_as_uint(f);
    uint32_t r = (u + 0x7FFFu + ((u >> 16) & 1u)) >> 16;
    return (u16)r;
}
__device__ __forceinline__ float sigm(float x) { return 1.0f / (1.0f + __expf(-x)); }
__device__ __forceinline__ float ldv(const void* p, size_t i, int dt) {
    return dt ? b2f(((const u16*)p)[i]) : ((const float*)p)[i];
}

__device__ __forceinline__ float wave_sum(float v) {
#pragma unroll
    for (int o = 32; o > 0; o >>= 1) v += __shfl_xor(v, o, 64);
    return v;
}
__device__ __forceinline__ void block_reduce2(float& a, float& b, float* sm) {
    int tid = threadIdx.x, wid = tid >> 6, lane = tid & 63;
    float as = wave_sum(a), bs = wave_sum(b);
    __syncthreads();
    if (lane == 0) { sm[wid] = as; sm[8 + wid] = bs; }
    __syncthreads();
    a = sm[0] + sm[1] + sm[2] + sm[3];
    b = sm[8] + sm[9] + sm[10] + sm[11];
}

// 64-lane sum via DPP ladder; full sum lands in lane 63.
__device__ __forceinline__ float dpp_sum64(float x) {
    x += __int_as_float(__builtin_amdgcn_update_dpp(0, __float_as_int(x), 0x111, 0xf, 0xf, true)); // row_shr:1
    x += __int_as_float(__builtin_amdgcn_update_dpp(0, __float_as_int(x), 0x112, 0xf, 0xf, true)); // row_shr:2
    x += __int_as_float(__builtin_amdgcn_update_dpp(0, __float_as_int(x), 0x114, 0xf, 0xf, true)); // row_shr:4
    x += __int_as_float(__builtin_amdgcn_update_dpp(0, __float_as_int(x), 0x118, 0xf, 0xf, true)); // row_shr:8
    x += __int_as_float(__builtin_amdgcn_update_dpp(0, __float_as_int(x), 0x142, 0xa, 0xf, true)); // row_bcast:15
    x += __int_as_float(__builtin_amdgcn_update_dpp(0, __float_as_int(x), 0x143, 0xc, 0xf, true)); // row_bcast:31
    return x;
}

// ---------- probe: dtype (hdr[0]) + which big array is x (hdr[1]) ----------
__global__ void k_probe(const u16* __restrict__ a0, const u16* __restrict__ a1,
                        const u16* __restrict__ a2, int* __restrict__ hdr) {
    __shared__ int wcnt;
    __shared__ float part[256];
    __shared__ float mag[3];
    int tid = threadIdx.x;
    if (tid == 0) wcnt = 0;
    __syncthreads();
    const u16* arr[3] = { a0, a1, a2 };
    int wild = 0;
    for (int s = 0; s < 3; ++s)
        for (int i = tid; i < 4096; i += 256) {
            u16 u = arr[s][i];
            int e = (u >> 7) & 0xFF;
            float av = fabsf(b2f(u));
            if (e == 0xFF || av > 100.f) wild++;
        }
    atomicAdd(&wcnt, wild);
    __syncthreads();
    int dt = (wcnt < 96) ? 1 : 0;
    for (int s = 0; s < 3; ++s) {
        float m = 0.f;
        if (dt) { for (int i = tid; i < 4096; i += 256) m += fabsf(b2f(arr[s][i])); }
        else    { const float* f = (const float*)arr[s];
                  for (int i = tid; i < 2048; i += 256) m += fabsf(f[i]); }
        part[tid] = m; __syncthreads();
        if (tid == 0) { float t = 0; for (int i = 0; i < 256; ++i) t += part[i]; mag[s] = t; }
        __syncthreads();
    }
    if (tid == 0) {
        int xs = 0;
        if (mag[1] > mag[xs]) xs = 1;
        if (mag[2] > mag[xs]) xs = 2;   // x ~N(0,1) vs 0.02-scale weights
        hdr[0] = dt; hdr[1] = xs;
    }
}

// ---------- double layernorm: x -> resid bf16, hs bf16 ----------
__global__ __launch_bounds__(256) void k_ln_in(
    const void* __restrict__ xa, const void* __restrict__ xb, const void* __restrict__ xc,
    const void* __restrict__ pw, const void* __restrict__ pb,
    const void* __restrict__ aw, const void* __restrict__ ab,
    u16* __restrict__ resid, u16* __restrict__ hs, const int* __restrict__ hdr)
{
    __shared__ float sm[16];
    const int dt = hdr[0], xs = hdr[1];
    const void* x = (xs == 0) ? xa : (xs == 1 ? xb : xc);
    int tok = blockIdx.x, tid = threadIdx.x;
    int c = tid * 4;
    size_t off = (size_t)tok * 1024 + c;
    float v0, v1, v2, v3;
    if (dt) {
        ushort4 xv = *(const ushort4*)((const u16*)x + off);
        v0 = b2f(xv.x); v1 = b2f(xv.y); v2 = b2f(xv.z); v3 = b2f(xv.w);
    } else {
        float4 xv = *(const float4*)((const float*)x + off);
        v0 = xv.x; v1 = xv.y; v2 = xv.z; v3 = xv.w;
    }
    float s = v0 + v1 + v2 + v3;
    float q = v0*v0 + v1*v1 + v2*v2 + v3*v3;
    block_reduce2(s, q, sm);
    float mean = s * (1.f/1024.f);
    float var  = q * (1.f/1024.f) - mean*mean;
    float rs = rsqrtf(var + 1e-5f);
    float h0 = (v0-mean)*rs*ldv(pw,c+0,dt) + ldv(pb,c+0,dt);
    float h1 = (v1-mean)*rs*ldv(pw,c+1,dt) + ldv(pb,c+1,dt);
    float h2 = (v2-mean)*rs*ldv(pw,c+2,dt) + ldv(pb,c+2,dt);
    float h3 = (v3-mean)*rs*ldv(pw,c+3,dt) + ldv(pb,c+3,dt);
    ushort4 rv; rv.x = f2b(h0); rv.y = f2b(h1); rv.z = f2b(h2); rv.w = f2b(h3);
    *(ushort4*)(resid + off) = rv;
    float s2 = h0 + h1 + h2 + h3;
    float q2 = h0*h0 + h1*h1 + h2*h2 + h3*h3;
    block_reduce2(s2, q2, sm);
    float m2 = s2 * (1.f/1024.f);
    float vr2 = q2 * (1.f/1024.f) - m2*m2;
    float rs2 = rsqrtf(vr2 + 1e-5f);
    ushort4 o;
    o.x = f2b((h0-m2)*rs2*ldv(aw,c+0,dt) + ldv(ab,c+0,dt));
    o.y = f2b((h1-m2)*rs2*ldv(aw,c+1,dt) + ldv(ab,c+1,dt));
    o.z = f2b((h2-m2)*rs2*ldv(aw,c+2,dt) + ldv(ab,c+2,dt));
    o.w = f2b((h3-m2)*rs2*ldv(aw,c+3,dt) + ldv(ab,c+3,dt));
    *(ushort4*)(hs + off) = o;
}

// ---------- layernorm bf16(ws) -> bf16 ----------
__global__ __launch_bounds__(256) void k_ln_bf(
    const u16* __restrict__ in, const void* __restrict__ w, const void* __restrict__ b,
    u16* __restrict__ out, const int* __restrict__ hdr)
{
    __shared__ float sm[16];
    const int dt = hdr[0];
    int tok = blockIdx.x, tid = threadIdx.x;
    int c = tid * 4;
    size_t off = (size_t)tok * 1024 + c;
    ushort4 xv = *(const ushort4*)(in + off);
    float v0 = b2f(xv.x), v1 = b2f(xv.y), v2 = b2f(xv.z), v3 = b2f(xv.w);
    float s = v0 + v1 + v2 + v3;
    float q = v0*v0 + v1*v1 + v2*v2 + v3*v3;
    block_reduce2(s, q, sm);
    float mean = s * (1.f/1024.f);
    float var  = q * (1.f/1024.f) - mean*mean;
    float rs = rsqrtf(var + 1e-5f);
    ushort4 o;
    o.x = f2b((v0-mean)*rs*ldv(w,c+0,dt) + ldv(b,c+0,dt));
    o.y = f2b((v1-mean)*rs*ldv(w,c+1,dt) + ldv(b,c+1,dt));
    o.z = f2b((v2-mean)*rs*ldv(w,c+2,dt) + ldv(b,c+2,dt));
    o.w = f2b((v3-mean)*rs*ldv(w,c+3,dt) + ldv(b,c+3,dt));
    *(ushort4*)(out + off) = o;
}

// ---------- weight transpose: W[K][N] (f32|bf16) -> WT[N][K] bf16 ----------
__global__ __launch_bounds__(256) void k_tr(
    const void* __restrict__ W, int K, int N, u16* __restrict__ WT,
    const int* __restrict__ hdr)
{
    const int dt = hdr[0];
    __shared__ u16 t[32][33];
    int n0 = blockIdx.x * 32, k0 = blockIdx.y * 32;
    int tx = threadIdx.x & 31, ty = threadIdx.x >> 5;   // 32 x 8
#pragma unroll
    for (int r = 0; r < 32; r += 8) {
        int k = k0 + ty + r;
        t[ty + r][tx] = f2b(ldv(W, (size_t)k * N + n0 + tx, dt));  // f2b(b2f(u))==u
    }
    __syncthreads();
#pragma unroll
    for (int r = 0; r < 32; r += 8) {
        int n = n0 + ty + r;
        WT[(size_t)n * K + k0 + tx] = t[tx][ty + r];
    }
}

// ---------- shared epilogue for MFMA GEMMs ----------
// modes: 1=raw 2=tanh 3=sigm 4=exp(-0.6065*sigm(v+bias)) 5=sigm(v+bias)
//        6=F32 OUT v+add 7=relu^2 8=bf16 v+add
__device__ __forceinline__ void mf_epi(
    void* D, int ldd, int mode, const void* bias,
    const u16* add, int ldadd, int dt,
    int row, int col, float v)
{
    size_t di = (size_t)row * ldd + col;
    if (mode == 6) {
        ((float*)D)[di] = v + b2f(add[(size_t)row * ldadd + col]);
        return;
    }
    float rr;
    switch (mode) {
        default: rr = v; break;
        case 2: rr = tanhf(v); break;
        case 3: rr = sigm(v); break;
        case 4: rr = __expf(-0.6065306597126334f * sigm(v + ldv(bias, col, dt))); break;
        case 5: rr = sigm(v + ldv(bias, col, dt)); break;
        case 7: { float t = fmaxf(v, 0.f); rr = t * t; } break;
        case 8: rr = v + b2f(add[(size_t)row * ldadd + col]); break;
    }
    ((u16*)D)[di] = f2b(rr);
}

// ---------- MFMA GEMM: 128x128 tile (for N=4096 outputs) ----------
__global__ __launch_bounds__(256, 2) void k_mf(
    const u16* __restrict__ A, int lda, const void* __restrict__ mixc,
    const u16* __restrict__ BT,
    void* __restrict__ D, int ldd,
    int K, int mode,
    const void* __restrict__ bias,
    const u16* __restrict__ add, int ldadd, const int* __restrict__ hdr)
{
    __shared__ u16 As[128 * 40];     // 10240 B
    __shared__ u16 Bs[128 * 40];     // 10240 B
    const int dt = hdr[0];
    const int tid = threadIdx.x;
    const int m0 = blockIdx.y * 128, n0 = blockIdx.x * 128;
    const int wid = tid >> 6, lane = tid & 63;
    const int wr = wid >> 1, wc = wid & 1;
    const int lg = lane >> 4, lc = lane & 15;
    const int srow = tid >> 1, shalf = tid & 1;   // staging: 128 rows x 2 k-halves

    f32x4 acc[4][4];
#pragma unroll
    for (int i = 0; i < 4; ++i)
#pragma unroll
        for (int j = 0; j < 4; ++j) acc[i][j] = (f32x4)0.f;

    for (int kb = 0; kb < K; kb += 32) {
        {
            int gr = m0 + srow;
            const u16* ap = A + (size_t)gr * lda + kb + 16 * shalf;
            us8 c1 = *(const us8*)ap;
            us8 c2 = *(const us8*)(ap + 8);
            if (mixc) {
                const u16* pp = ap - ((gr & 2047) ? lda : 0);
                float pz = (gr & 2047) ? 1.f : 0.f;
                us8 p1 = *(const us8*)pp;
                us8 p2 = *(const us8*)(pp + 8);
                int kbase = kb + 16 * shalf;
#pragma unroll
                for (int e = 0; e < 8; ++e) {
                    float cu1 = b2f(c1[e]), cu2 = b2f(c2[e]);
                    c1[e] = f2b(cu1 + (pz * b2f(p1[e]) - cu1) * ldv(mixc, kbase + e, dt));
                    c2[e] = f2b(cu2 + (pz * b2f(p2[e]) - cu2) * ldv(mixc, kbase + 8 + e, dt));
                }
            }
            u16* dst = As + srow * 40 + 16 * shalf;
            *(us8*)dst = c1;
            *(us8*)(dst + 8) = c2;
        }
        {
            const u16* bp = BT + (size_t)(n0 + srow) * K + kb + 16 * shalf;
            u16* dst = Bs + srow * 40 + 16 * shalf;
            *(us8*)dst = *(const us8*)bp;
            *(us8*)(dst + 8) = *(const us8*)(bp + 8);
        }
        __syncthreads();
        bf16x8 af[4], bf[4];
#pragma unroll
        for (int fm = 0; fm < 4; ++fm) {
            const u16* p = As + (wr * 64 + fm * 16 + lc) * 40 + lg * 8;
            union { us8 s; bf16x8 v; } u;
            u.s = *(const us8*)p;
            af[fm] = u.v;
        }
#pragma unroll
        for (int fc = 0; fc < 4; ++fc) {
            const u16* p = Bs + (wc * 64 + fc * 16 + lc) * 40 + lg * 8;
            union { us8 s; bf16x8 v; } u;
            u.s = *(const us8*)p;
            bf[fc] = u.v;
        }
#pragma unroll
        for (int fm = 0; fm < 4; ++fm)
#pragma unroll
            for (int fc = 0; fc < 4; ++fc)
                acc[fm][fc] = __builtin_amdgcn_mfma_f32_16x16x32_bf16(
                    af[fm], bf[fc], acc[fm][fc], 0, 0, 0);
        __syncthreads();
    }

#pragma unroll
    for (int fm = 0; fm < 4; ++fm)
#pragma unroll
        for (int fc = 0; fc < 4; ++fc)
#pragma unroll
            for (int r = 0; r < 4; ++r)
                mf_epi(D, ldd, mode, bias, add, ldadd, dt,
                       m0 + wr * 64 + fm * 16 + lg * 4 + r,
                       n0 + wc * 64 + fc * 16 + lc, acc[fm][fc][r]);
}

// ---------- MFMA GEMM: 64x64 tile (for N<=1024 outputs) ----------
__global__ __launch_bounds__(256, 4) void k_mf64(
    const u16* __restrict__ A, int lda, const void* __restrict__ mixc,
    const u16* __restrict__ BT,
    void* __restrict__ D, int ldd,
    int K, int mode,
    const void* __restrict__ bias,
    const u16* __restrict__ add, int ldadd, const int* __restrict__ hdr)
{
    __shared__ u16 As[64 * 40];      // 5120 B
    __shared__ u16 Bs[64 * 40];      // 5120 B
    const int dt = hdr[0];
    const int tid = threadIdx.x;
    const int m0 = blockIdx.y * 64, n0 = blockIdx.x * 64;
    const int wid = tid >> 6, lane = tid & 63;
    const int wr = wid >> 1, wc = wid & 1;
    const int lg = lane >> 4, lc = lane & 15;
    const int srow = tid >> 2, sq = tid & 3;      // staging: 64 rows x 4 k-quarters

    f32x4 acc[2][2];
#pragma unroll
    for (int i = 0; i < 2; ++i)
#pragma unroll
        for (int j = 0; j < 2; ++j) acc[i][j] = (f32x4)0.f;

    for (int kb = 0; kb < K; kb += 32) {
        {
            int gr = m0 + srow;
            const u16* ap = A + (size_t)gr * lda + kb + 8 * sq;
            us8 c1 = *(const us8*)ap;
            if (mixc) {
                const u16* pp = ap - ((gr & 2047) ? lda : 0);
                float pz = (gr & 2047) ? 1.f : 0.f;
                us8 p1 = *(const us8*)pp;
                int kbase = kb + 8 * sq;
#pragma unroll
                for (int e = 0; e < 8; ++e) {
                    float cu = b2f(c1[e]);
                    c1[e] = f2b(cu + (pz * b2f(p1[e]) - cu) * ldv(mixc, kbase + e, dt));
                }
            }
            *(us8*)(As + srow * 40 + 8 * sq) = c1;
        }
        {
            const u16* bp = BT + (size_t)(n0 + srow) * K + kb + 8 * sq;
            *(us8*)(Bs + srow * 40 + 8 * sq) = *(const us8*)bp;
        }
        __syncthreads();
        bf16x8 af[2], bf[2];
#pragma unroll
        for (int fm = 0; fm < 2; ++fm) {
            const u16* p = As + (wr * 32 + fm * 16 + lc) * 40 + lg * 8;
            union { us8 s; bf16x8 v; } u;
            u.s = *(const us8*)p;
            af[fm] = u.v;
        }
#pragma unroll
        for (int fc = 0; fc < 2; ++fc) {
            const u16* p = Bs + (wc * 32 + fc * 16 + lc) * 40 + lg * 8;
            union { us8 s; bf16x8 v; } u;
            u.s = *(const us8*)p;
            bf[fc] = u.v;
        }
#pragma unroll
        for (int fm = 0; fm < 2; ++fm)
#pragma unroll
            for (int fc = 0; fc < 2; ++fc)
                acc[fm][fc] = __builtin_amdgcn_mfma_f32_16x16x32_bf16(
                    af[fm], bf[fc], acc[fm][fc], 0, 0, 0);
        __syncthreads();
    }

#pragma unroll
    for (int fm = 0; fm < 2; ++fm)
#pragma unroll
        for (int fc = 0; fc < 2; ++fc)
#pragma unroll
            for (int r = 0; r < 4; ++r)
                mf_epi(D, ldd, mode, bias, add, ldadd, dt,
                       m0 + wr * 32 + fm * 16 + lg * 4 + r,
                       n0 + wc * 32 + fc * 16 + lc, acc[fm][fc][r]);
}

// ---------- per-head prep ----------
__global__ __launch_bounds__(256) void k_prep(
    u16* __restrict__ k_bf, const u16* __restrict__ a_buf,
    const void* __restrict__ k_k, const void* __restrict__ k_a,
    u16* __restrict__ av, u16* __restrict__ bv, const int* __restrict__ hdr)
{
    const int dt = hdr[0];
    int ht = blockIdx.x * 4 + (threadIdx.x >> 6);
    int j = threadIdx.x & 63;
    int tok = ht >> 4, h = ht & 15, n = h * 64 + j;
    size_t idx = (size_t)tok * 1024 + n;
    float kv = b2f(k_bf[idx]);
    float a  = b2f(a_buf[idx]);
    float kk = kv * ldv(k_k, n, dt);
    float ss = wave_sum(kk * kk);
    float den = fmaxf(sqrtf(ss), 1e-12f);
    float kkn = kk / den;
    k_bf[idx] = f2b(kv * (1.f + (a - 1.f) * ldv(k_a, n, dt)));
    av[idx] = f2b(-kkn);
    bv[idx] = f2b(kkn * a);
}

// ---------- recurrence v5 (REVERTED from v6): one WAVE per (b,h,column-PAIR) ----------
// v6's depth-8 regressed (R10: 1693us, VALUBusy 20% — compiler sank the
// prefetch loads to their uses, destroying the pipeline). v5 = measured
// 587us best (R8/R9). Source-level prefetch restructuring is exhausted;
// only an algorithmic (chunked-MFMA) rewrite can beat this.
__global__ __launch_bounds__(256) void k_rec(
    const u16* __restrict__ r_bf, const u16* __restrict__ dcy,
    const u16* __restrict__ km, const u16* __restrict__ v_bf,
    const u16* __restrict__ av, const u16* __restrict__ bv,
    u16* __restrict__ o_buf)
{
    const int T = 2048;
    int rq = blockIdx.x & 7, q = blockIdx.x >> 3;
    int wid = threadIdx.x >> 6, lane = threadIdx.x & 63;
    int bh = rq * 4 + (q >> 3);          // 0..31; 8 blocks of a bh share an XCD
    int jj = (q & 7) * 4 + wid;          // 0..31 column pair -> cols 2jj, 2jj+1
    int b = bh >> 4, h = bh & 15;
    size_t base = (size_t)(b * T) * 1024 + h * 64 + lane;
    size_t vidx = (size_t)(b * T) * 512 + h * 32 + jj;
    size_t oidx = vidx;
    const uint32_t* v32 = (const uint32_t*)v_bf;
    uint32_t* o32 = (uint32_t*)o_buf;
    float S0 = 0.f, S1 = 0.f;
    u16 rv = r_bf[base], dv = dcy[base], kv = km[base];
    u16 avv = av[base], bvv = bv[base];
    uint32_t vv = v32[vidx];
#pragma unroll 2
    for (int t = 0; t < T; ++t) {
        float rf = b2f(rv), df = b2f(dv), kf = b2f(kv);
        float af = b2f(avv), bf_ = b2f(bvv);
        float vf0 = __uint_as_float(vv << 16);
        float vf1 = __uint_as_float(vv & 0xFFFF0000u);
        if (t + 1 < T) {
            base += 1024; vidx += 512;
            rv = r_bf[base]; dv = dcy[base]; kv = km[base];
            avv = av[base]; bvv = bv[base];
            vv = v32[vidx];
        }
        float sa0 = dpp_sum64(af * S0);
        float sa1 = dpp_sum64(af * S1);
        float X0 = fmaf(kf, vf0, S0 * df);
        float X1 = fmaf(kf, vf1, S1 * df);
        sa0 = __int_as_float(__builtin_amdgcn_readlane(__float_as_int(sa0), 63));
        sa1 = __int_as_float(__builtin_amdgcn_readlane(__float_as_int(sa1), 63));
        S0 = fmaf(bf_, sa0, X0);
        S1 = fmaf(bf_, sa1, X1);
        float o0 = dpp_sum64(rf * S0);
        float o1 = dpp_sum64(rf * S1);
        if (lane == 63)
            o32[oidx] = (uint32_t)f2b(o0) | ((uint32_t)f2b(o1) << 16);
        oidx += 512;
    }
}

// ---------- groupnorm + bonus + gate ----------
__global__ __launch_bounds__(256) void k_post(
    const u16* __restrict__ o_buf, const u16* __restrict__ r_bf,
    const u16* __restrict__ km, const u16* __restrict__ v_bf,
    const u16* __restrict__ g_buf, const void* __restrict__ r_k,
    const void* __restrict__ gnw, const void* __restrict__ gnb,
    u16* __restrict__ ao, const int* __restrict__ hdr)
{
    const int dt = hdr[0];
    int ht = blockIdx.x * 4 + (threadIdx.x >> 6);
    int j = threadIdx.x & 63;
    int tok = ht >> 4, h = ht & 15, n = h * 64 + j;
    size_t idx = (size_t)tok * 1024 + n;
    float o = b2f(o_buf[idx]);
    float mu = wave_sum(o) * (1.f/64.f);
    float d = o - mu;
    float var = wave_sum(d * d) * (1.f/64.f);
    float og = d * rsqrtf(var + 6.4e-4f) * ldv(gnw, n, dt) + ldv(gnb, n, dt);
    float r = b2f(r_bf[idx]), kmv = b2f(km[idx]), v = b2f(v_bf[idx]);
    float bonus = wave_sum(r * kmv * ldv(r_k, n, dt));
    float val = (og + bonus * v) * b2f(g_buf[idx]);
    ao[idx] = f2b(val);
}

// ---------- host ----------
extern "C" void kernel_launch(void* const* d_in, const int* in_sizes, int n_in,
                              void* d_out, int out_size, void* d_ws, size_t ws_size,
                              hipStream_t stream) {
    (void)in_sizes; (void)n_in; (void)out_size; (void)ws_size;
    const void* xP     = d_in[0];
    const void* pre_w  = d_in[1];
    const void* pre_b  = d_in[2];
    const void* attn_w = d_in[3];
    const void* attn_b = d_in[4];
    const void* ffn_w  = d_in[5];
    const void* ffn_b  = d_in[6];
    const void* x_r    = d_in[7];
    const void* x_w    = d_in[8];
    const void* x_k    = d_in[9];
    const void* x_v    = d_in[10];
    const void* x_a    = d_in[11];
    const void* x_g    = d_in[12];
    const void* W_r    = d_in[13];
    const void* W_k    = d_in[14];
    const void* W_v    = d_in[15];
    const void* W_o    = d_in[16];
    const void* w1     = d_in[17];
    const void* w2     = d_in[18];
    const void* w_b    = d_in[19];
    const void* a1     = d_in[20];
    const void* a2     = d_in[21];
    const void* a_b    = d_in[22];
    const void* g1     = d_in[23];
    const void* g2     = d_in[24];
    const void* k_k    = d_in[25];
    const void* k_a    = d_in[26];
    const void* r_k    = d_in[27];
    const void* gn_w   = d_in[28];
    const void* gn_b   = d_in[29];
    const void* ffn_xk = d_in[30];
    const void* WkeyP  = d_in[31];
    const void* WvalP  = d_in[32];

    char* ws = (char*)d_ws;
    const size_t SL = 8388608ull;          // [4096][1024] bf16 slab
    int* hdr    = (int*)(ws + 0);
    u16* hs     = (u16*)(ws + 4096 + SL*0);
    u16* resid1 = (u16*)(ws + 4096 + SL*1);
    u16* dcy    = (u16*)(ws + 4096 + SL*2);
    u16* r_bf   = (u16*)(ws + 4096 + SL*3);
    u16* k_bf   = (u16*)(ws + 4096 + SL*4);
    u16* v_bf   = (u16*)(ws + 4096 + SL*5);
    u16* av_bf  = (u16*)(ws + 4096 + SL*6);
    u16* bv_bf  = (u16*)(ws + 4096 + SL*7);
    u16* a_buf  = (u16*)(ws + 4096 + SL*8);
    u16* g_buf  = (u16*)(ws + 4096 + SL*9);
    u16* tmpw   = (u16*)(ws + 4096 + SL*10);
    u16* tmpa   = (u16*)(ws + 4096 + SL*10 + 524288);
    u16* tmpg   = (u16*)(ws + 4096 + SL*10 + 1048576);
    u16* wT     = (u16*)(ws + 4096 + SL*10 + 2097152);   // 8MB transpose scratch; peak ~90MB
    // overlays (later lifetimes)
    u16* o_buf  = a_buf;                   // a dead after k_prep
    u16* ao_in  = bv_bf;                   // bv dead after k_rec
    u16* hid2   = dcy;                     // dcy dead after k_rec
    u16* hs2    = hs;                      // hs dead after projections
    u16* ffh    = r_bf;                    // [4096,4096] bf16 over r,k,v,av (dead after k_post)

    dim3 blk(256);
    dim3 gm64(16, 64);                     // 64x64-tile grid for N=1024
    dim3 g4096(32, 32);
    dim3 t1024(32, 32), tKey(128, 32), tVal(32, 128), t64(32, 2), t128(32, 4);
    dim3 tl64(2, 32), tl128(4, 32);        // lora up-weight transposes
    k_probe<<<1, blk, 0, stream>>>((const u16*)xP, (const u16*)WkeyP, (const u16*)WvalP, hdr);
    k_ln_in<<<4096, blk, 0, stream>>>(xP, WkeyP, WvalP, pre_w, pre_b, attn_w, attn_b, resid1, hs, hdr);

    // attn projections (fused token-shift mix) -- all MFMA
    k_tr<<<t1024, blk, 0, stream>>>(W_r, 1024, 1024, wT, hdr);
    k_mf64<<<gm64, blk, 0, stream>>>(hs, 1024, x_r, wT, r_bf, 1024, 1024, 1, nullptr, nullptr, 0, hdr);
    k_tr<<<tl64, blk, 0, stream>>>(w1, 1024, 64, wT, hdr);
    k_mf64<<<dim3(1, 64), blk, 0, stream>>>(hs, 1024, x_w, wT, tmpw, 64, 1024, 2, nullptr, nullptr, 0, hdr);
    k_tr<<<t64, blk, 0, stream>>>(w2, 64, 1024, wT, hdr);
    k_mf64<<<gm64, blk, 0, stream>>>(tmpw, 64, nullptr, wT, dcy, 1024, 64, 4, w_b, nullptr, 0, hdr);
    k_tr<<<t1024, blk, 0, stream>>>(W_k, 1024, 1024, wT, hdr);
    k_mf64<<<gm64, blk, 0, stream>>>(hs, 1024, x_k, wT, k_bf, 1024, 1024, 1, nullptr, nullptr, 0, hdr);
    k_tr<<<t1024, blk, 0, stream>>>(W_v, 1024, 1024, wT, hdr);
    k_mf64<<<gm64, blk, 0, stream>>>(hs, 1024, x_v, wT, v_bf, 1024, 1024, 1, nullptr, nullptr, 0, hdr);
    k_tr<<<tl64, blk, 0, stream>>>(a1, 1024, 64, wT, hdr);
    k_mf64<<<dim3(1, 64), blk, 0, stream>>>(hs, 1024, x_a, wT, tmpa, 64, 1024, 1, nullptr, nullptr, 0, hdr);
    k_tr<<<t64, blk, 0, stream>>>(a2, 64, 1024, wT, hdr);
    k_mf64<<<gm64, blk, 0, stream>>>(tmpa, 64, nullptr, wT, a_buf, 1024, 64, 5, a_b, nullptr, 0, hdr);
    k_tr<<<tl128, blk, 0, stream>>>(g1, 1024, 128, wT, hdr);
    k_mf64<<<dim3(2, 64), blk, 0, stream>>>(hs, 1024, x_g, wT, tmpg, 128, 1024, 3, nullptr, nullptr, 0, hdr);
    k_tr<<<t128, blk, 0, stream>>>(g2, 128, 1024, wT, hdr);
    k_mf64<<<gm64, blk, 0, stream>>>(tmpg, 128, nullptr, wT, g_buf, 1024, 128, 1, nullptr, nullptr, 0, hdr);

    k_prep<<<16384, blk, 0, stream>>>(k_bf, a_buf, k_k, k_a, av_bf, bv_bf, hdr);
    k_rec<<<256, blk, 0, stream>>>(r_bf, dcy, k_bf, v_bf, av_bf, bv_bf, o_buf);
    k_post<<<16384, blk, 0, stream>>>(o_buf, r_bf, k_bf, v_bf, g_buf, r_k, gn_w, gn_b, ao_in, hdr);

    // output projection + residual -> hid2 (bf16)
    k_tr<<<t1024, blk, 0, stream>>>(W_o, 1024, 1024, wT, hdr);
    k_mf64<<<gm64, blk, 0, stream>>>(ao_in, 1024, nullptr, wT, hid2, 1024, 1024, 8, nullptr, resid1, 1024, hdr);

    // FFN; final GEMM writes FLOAT32 output
    k_ln_bf<<<4096, blk, 0, stream>>>(hid2, ffn_w, ffn_b, hs2, hdr);
    k_tr<<<tKey, blk, 0, stream>>>(WkeyP, 1024, 4096, wT, hdr);
    k_mf<<<g4096, blk, 0, stream>>>(hs2, 1024, ffn_xk, wT, ffh, 4096, 1024, 7, nullptr, nullptr, 0, hdr);
    k_tr<<<tVal, blk, 0, stream>>>(WvalP, 4096, 1024, wT, hdr);
    k_mf64<<<gm64, blk, 0, stream>>>(ffh, 4096, nullptr, wT, (float*)d_out, 1024, 4096, 6, nullptr, hid2, 1024, hdr);
}

// Round 12
// 1304.655 us; speedup vs baseline: 1.9072x; 1.0434x over previous
//
#include <hip/hip_runtime.h>
#include <hip/hip_bf16.h>
#include <cstdint>

typedef unsigned short u16;
typedef unsigned short us8 __attribute__((ext_vector_type(8)));
typedef __bf16 bf16x8 __attribute__((ext_vector_type(8)));
typedef float f32x4 __attribute__((ext_vector_type(4)));

// ---------- helpers ----------
__device__ __forceinline__ float b2f(u16 u) {
    union { float f; uint32_t i; } x; x.i = ((uint32_t)u) << 16; return x.f;
}
__device__ __forceinline__ u16 f2b(float f) {
    uint32_t u = __float_as_uint(f);
    uint32_t r = (u + 0x7FFFu + ((u >> 16) & 1u)) >> 16;
    return (u16)r;
}
__device__ __forceinline__ float sigm(float x) { return 1.0f / (1.0f + __expf(-x)); }
__device__ __forceinline__ float ldv(const void* p, size_t i, int dt) {
    return dt ? b2f(((const u16*)p)[i]) : ((const float*)p)[i];
}

__device__ __forceinline__ float wave_sum(float v) {
#pragma unroll
    for (int o = 32; o > 0; o >>= 1) v += __shfl_xor(v, o, 64);
    return v;
}
__device__ __forceinline__ void block_reduce2(float& a, float& b, float* sm) {
    int tid = threadIdx.x, wid = tid >> 6, lane = tid & 63;
    float as = wave_sum(a), bs = wave_sum(b);
    __syncthreads();
    if (lane == 0) { sm[wid] = as; sm[8 + wid] = bs; }
    __syncthreads();
    a = sm[0] + sm[1] + sm[2] + sm[3];
    b = sm[8] + sm[9] + sm[10] + sm[11];
}

// 64-lane sum via DPP ladder; full sum lands in lane 63.
__device__ __forceinline__ float dpp_sum64(float x) {
    x += __int_as_float(__builtin_amdgcn_update_dpp(0, __float_as_int(x), 0x111, 0xf, 0xf, true)); // row_shr:1
    x += __int_as_float(__builtin_amdgcn_update_dpp(0, __float_as_int(x), 0x112, 0xf, 0xf, true)); // row_shr:2
    x += __int_as_float(__builtin_amdgcn_update_dpp(0, __float_as_int(x), 0x114, 0xf, 0xf, true)); // row_shr:4
    x += __int_as_float(__builtin_amdgcn_update_dpp(0, __float_as_int(x), 0x118, 0xf, 0xf, true)); // row_shr:8
    x += __int_as_float(__builtin_amdgcn_update_dpp(0, __float_as_int(x), 0x142, 0xa, 0xf, true)); // row_bcast:15
    x += __int_as_float(__builtin_amdgcn_update_dpp(0, __float_as_int(x), 0x143, 0xc, 0xf, true)); // row_bcast:31
    return x;
}

// ---------- probe: dtype (hdr[0]) + which big array is x (hdr[1]) ----------
__global__ void k_probe(const u16* __restrict__ a0, const u16* __restrict__ a1,
                        const u16* __restrict__ a2, int* __restrict__ hdr) {
    __shared__ int wcnt;
    __shared__ float part[256];
    __shared__ float mag[3];
    int tid = threadIdx.x;
    if (tid == 0) wcnt = 0;
    __syncthreads();
    const u16* arr[3] = { a0, a1, a2 };
    int wild = 0;
    for (int s = 0; s < 3; ++s)
        for (int i = tid; i < 4096; i += 256) {
            u16 u = arr[s][i];
            int e = (u >> 7) & 0xFF;
            float av = fabsf(b2f(u));
            if (e == 0xFF || av > 100.f) wild++;
        }
    atomicAdd(&wcnt, wild);
    __syncthreads();
    int dt = (wcnt < 96) ? 1 : 0;
    for (int s = 0; s < 3; ++s) {
        float m = 0.f;
        if (dt) { for (int i = tid; i < 4096; i += 256) m += fabsf(b2f(arr[s][i])); }
        else    { const float* f = (const float*)arr[s];
                  for (int i = tid; i < 2048; i += 256) m += fabsf(f[i]); }
        part[tid] = m; __syncthreads();
        if (tid == 0) { float t = 0; for (int i = 0; i < 256; ++i) t += part[i]; mag[s] = t; }
        __syncthreads();
    }
    if (tid == 0) {
        int xs = 0;
        if (mag[1] > mag[xs]) xs = 1;
        if (mag[2] > mag[xs]) xs = 2;   // x ~N(0,1) vs 0.02-scale weights
        hdr[0] = dt; hdr[1] = xs;
    }
}

// ---------- double layernorm: x -> resid bf16, hs bf16 ----------
__global__ __launch_bounds__(256) void k_ln_in(
    const void* __restrict__ xa, const void* __restrict__ xb, const void* __restrict__ xc,
    const void* __restrict__ pw, const void* __restrict__ pb,
    const void* __restrict__ aw, const void* __restrict__ ab,
    u16* __restrict__ resid, u16* __restrict__ hs, const int* __restrict__ hdr)
{
    __shared__ float sm[16];
    const int dt = hdr[0], xs = hdr[1];
    const void* x = (xs == 0) ? xa : (xs == 1 ? xb : xc);
    int tok = blockIdx.x, tid = threadIdx.x;
    int c = tid * 4;
    size_t off = (size_t)tok * 1024 + c;
    float v0, v1, v2, v3;
    if (dt) {
        ushort4 xv = *(const ushort4*)((const u16*)x + off);
        v0 = b2f(xv.x); v1 = b2f(xv.y); v2 = b2f(xv.z); v3 = b2f(xv.w);
    } else {
        float4 xv = *(const float4*)((const float*)x + off);
        v0 = xv.x; v1 = xv.y; v2 = xv.z; v3 = xv.w;
    }
    float s = v0 + v1 + v2 + v3;
    float q = v0*v0 + v1*v1 + v2*v2 + v3*v3;
    block_reduce2(s, q, sm);
    float mean = s * (1.f/1024.f);
    float var  = q * (1.f/1024.f) - mean*mean;
    float rs = rsqrtf(var + 1e-5f);
    float h0 = (v0-mean)*rs*ldv(pw,c+0,dt) + ldv(pb,c+0,dt);
    float h1 = (v1-mean)*rs*ldv(pw,c+1,dt) + ldv(pb,c+1,dt);
    float h2 = (v2-mean)*rs*ldv(pw,c+2,dt) + ldv(pb,c+2,dt);
    float h3 = (v3-mean)*rs*ldv(pw,c+3,dt) + ldv(pb,c+3,dt);
    ushort4 rv; rv.x = f2b(h0); rv.y = f2b(h1); rv.z = f2b(h2); rv.w = f2b(h3);
    *(ushort4*)(resid + off) = rv;
    float s2 = h0 + h1 + h2 + h3;
    float q2 = h0*h0 + h1*h1 + h2*h2 + h3*h3;
    block_reduce2(s2, q2, sm);
    float m2 = s2 * (1.f/1024.f);
    float vr2 = q2 * (1.f/1024.f) - m2*m2;
    float rs2 = rsqrtf(vr2 + 1e-5f);
    ushort4 o;
    o.x = f2b((h0-m2)*rs2*ldv(aw,c+0,dt) + ldv(ab,c+0,dt));
    o.y = f2b((h1-m2)*rs2*ldv(aw,c+1,dt) + ldv(ab,c+1,dt));
    o.z = f2b((h2-m2)*rs2*ldv(aw,c+2,dt) + ldv(ab,c+2,dt));
    o.w = f2b((h3-m2)*rs2*ldv(aw,c+3,dt) + ldv(ab,c+3,dt));
    *(ushort4*)(hs + off) = o;
}

// ---------- layernorm bf16(ws) -> bf16 ----------
__global__ __launch_bounds__(256) void k_ln_bf(
    const u16* __restrict__ in, const void* __restrict__ w, const void* __restrict__ b,
    u16* __restrict__ out, const int* __restrict__ hdr)
{
    __shared__ float sm[16];
    const int dt = hdr[0];
    int tok = blockIdx.x, tid = threadIdx.x;
    int c = tid * 4;
    size_t off = (size_t)tok * 1024 + c;
    ushort4 xv = *(const ushort4*)(in + off);
    float v0 = b2f(xv.x), v1 = b2f(xv.y), v2 = b2f(xv.z), v3 = b2f(xv.w);
    float s = v0 + v1 + v2 + v3;
    float q = v0*v0 + v1*v1 + v2*v2 + v3*v3;
    block_reduce2(s, q, sm);
    float mean = s * (1.f/1024.f);
    float var  = q * (1.f/1024.f) - mean*mean;
    float rs = rsqrtf(var + 1e-5f);
    ushort4 o;
    o.x = f2b((v0-mean)*rs*ldv(w,c+0,dt) + ldv(b,c+0,dt));
    o.y = f2b((v1-mean)*rs*ldv(w,c+1,dt) + ldv(b,c+1,dt));
    o.z = f2b((v2-mean)*rs*ldv(w,c+2,dt) + ldv(b,c+2,dt));
    o.w = f2b((v3-mean)*rs*ldv(w,c+3,dt) + ldv(b,c+3,dt));
    *(ushort4*)(out + off) = o;
}

// ---------- weight transpose: W[K][N] (f32|bf16) -> WT[N][K] bf16 ----------
__global__ __launch_bounds__(256) void k_tr(
    const void* __restrict__ W, int K, int N, u16* __restrict__ WT,
    const int* __restrict__ hdr)
{
    const int dt = hdr[0];
    __shared__ u16 t[32][33];
    int n0 = blockIdx.x * 32, k0 = blockIdx.y * 32;
    int tx = threadIdx.x & 31, ty = threadIdx.x >> 5;   // 32 x 8
#pragma unroll
    for (int r = 0; r < 32; r += 8) {
        int k = k0 + ty + r;
        t[ty + r][tx] = f2b(ldv(W, (size_t)k * N + n0 + tx, dt));  // f2b(b2f(u))==u
    }
    __syncthreads();
#pragma unroll
    for (int r = 0; r < 32; r += 8) {
        int n = n0 + ty + r;
        WT[(size_t)n * K + k0 + tx] = t[tx][ty + r];
    }
}

// ---------- shared epilogue for MFMA GEMMs ----------
// modes: 1=raw 2=tanh 3=sigm 4=exp(-0.6065*sigm(v+bias)) 5=sigm(v+bias)
//        6=F32 OUT v+add 7=relu^2 8=bf16 v+add
__device__ __forceinline__ void mf_epi(
    void* D, int ldd, int mode, const void* bias,
    const u16* add, int ldadd, int dt,
    int row, int col, float v)
{
    size_t di = (size_t)row * ldd + col;
    if (mode == 6) {
        ((float*)D)[di] = v + b2f(add[(size_t)row * ldadd + col]);
        return;
    }
    float rr;
    switch (mode) {
        default: rr = v; break;
        case 2: rr = tanhf(v); break;
        case 3: rr = sigm(v); break;
        case 4: rr = __expf(-0.6065306597126334f * sigm(v + ldv(bias, col, dt))); break;
        case 5: rr = sigm(v + ldv(bias, col, dt)); break;
        case 7: { float t = fmaxf(v, 0.f); rr = t * t; } break;
        case 8: rr = v + b2f(add[(size_t)row * ldadd + col]); break;
    }
    ((u16*)D)[di] = f2b(rr);
}

// ---------- MFMA GEMM: 128x128 tile (for N=4096 outputs) ----------
__global__ __launch_bounds__(256, 2) void k_mf(
    const u16* __restrict__ A, int lda, const void* __restrict__ mixc,
    const u16* __restrict__ BT,
    void* __restrict__ D, int ldd,
    int K, int mode,
    const void* __restrict__ bias,
    const u16* __restrict__ add, int ldadd, const int* __restrict__ hdr)
{
    __shared__ u16 As[128 * 40];     // 10240 B
    __shared__ u16 Bs[128 * 40];     // 10240 B
    const int dt = hdr[0];
    const int tid = threadIdx.x;
    const int m0 = blockIdx.y * 128, n0 = blockIdx.x * 128;
    const int wid = tid >> 6, lane = tid & 63;
    const int wr = wid >> 1, wc = wid & 1;
    const int lg = lane >> 4, lc = lane & 15;
    const int srow = tid >> 1, shalf = tid & 1;   // staging: 128 rows x 2 k-halves

    f32x4 acc[4][4];
#pragma unroll
    for (int i = 0; i < 4; ++i)
#pragma unroll
        for (int j = 0; j < 4; ++j) acc[i][j] = (f32x4)0.f;

    for (int kb = 0; kb < K; kb += 32) {
        {
            int gr = m0 + srow;
            const u16* ap = A + (size_t)gr * lda + kb + 16 * shalf;
            us8 c1 = *(const us8*)ap;
            us8 c2 = *(const us8*)(ap + 8);
            if (mixc) {
                const u16* pp = ap - ((gr & 2047) ? lda : 0);
                float pz = (gr & 2047) ? 1.f : 0.f;
                us8 p1 = *(const us8*)pp;
                us8 p2 = *(const us8*)(pp + 8);
                int kbase = kb + 16 * shalf;
#pragma unroll
                for (int e = 0; e < 8; ++e) {
                    float cu1 = b2f(c1[e]), cu2 = b2f(c2[e]);
                    c1[e] = f2b(cu1 + (pz * b2f(p1[e]) - cu1) * ldv(mixc, kbase + e, dt));
                    c2[e] = f2b(cu2 + (pz * b2f(p2[e]) - cu2) * ldv(mixc, kbase + 8 + e, dt));
                }
            }
            u16* dst = As + srow * 40 + 16 * shalf;
            *(us8*)dst = c1;
            *(us8*)(dst + 8) = c2;
        }
        {
            const u16* bp = BT + (size_t)(n0 + srow) * K + kb + 16 * shalf;
            u16* dst = Bs + srow * 40 + 16 * shalf;
            *(us8*)dst = *(const us8*)bp;
            *(us8*)(dst + 8) = *(const us8*)(bp + 8);
        }
        __syncthreads();
        bf16x8 af[4], bf[4];
#pragma unroll
        for (int fm = 0; fm < 4; ++fm) {
            const u16* p = As + (wr * 64 + fm * 16 + lc) * 40 + lg * 8;
            union { us8 s; bf16x8 v; } u;
            u.s = *(const us8*)p;
            af[fm] = u.v;
        }
#pragma unroll
        for (int fc = 0; fc < 4; ++fc) {
            const u16* p = Bs + (wc * 64 + fc * 16 + lc) * 40 + lg * 8;
            union { us8 s; bf16x8 v; } u;
            u.s = *(const us8*)p;
            bf[fc] = u.v;
        }
#pragma unroll
        for (int fm = 0; fm < 4; ++fm)
#pragma unroll
            for (int fc = 0; fc < 4; ++fc)
                acc[fm][fc] = __builtin_amdgcn_mfma_f32_16x16x32_bf16(
                    af[fm], bf[fc], acc[fm][fc], 0, 0, 0);
        __syncthreads();
    }

#pragma unroll
    for (int fm = 0; fm < 4; ++fm)
#pragma unroll
        for (int fc = 0; fc < 4; ++fc)
#pragma unroll
            for (int r = 0; r < 4; ++r)
                mf_epi(D, ldd, mode, bias, add, ldadd, dt,
                       m0 + wr * 64 + fm * 16 + lg * 4 + r,
                       n0 + wc * 64 + fc * 16 + lc, acc[fm][fc][r]);
}

// ---------- MFMA GEMM: 64x64 tile (for N<=1024 outputs) ----------
__global__ __launch_bounds__(256, 4) void k_mf64(
    const u16* __restrict__ A, int lda, const void* __restrict__ mixc,
    const u16* __restrict__ BT,
    void* __restrict__ D, int ldd,
    int K, int mode,
    const void* __restrict__ bias,
    const u16* __restrict__ add, int ldadd, const int* __restrict__ hdr)
{
    __shared__ u16 As[64 * 40];      // 5120 B
    __shared__ u16 Bs[64 * 40];      // 5120 B
    const int dt = hdr[0];
    const int tid = threadIdx.x;
    const int m0 = blockIdx.y * 64, n0 = blockIdx.x * 64;
    const int wid = tid >> 6, lane = tid & 63;
    const int wr = wid >> 1, wc = wid & 1;
    const int lg = lane >> 4, lc = lane & 15;
    const int srow = tid >> 2, sq = tid & 3;      // staging: 64 rows x 4 k-quarters

    f32x4 acc[2][2];
#pragma unroll
    for (int i = 0; i < 2; ++i)
#pragma unroll
        for (int j = 0; j < 2; ++j) acc[i][j] = (f32x4)0.f;

    for (int kb = 0; kb < K; kb += 32) {
        {
            int gr = m0 + srow;
            const u16* ap = A + (size_t)gr * lda + kb + 8 * sq;
            us8 c1 = *(const us8*)ap;
            if (mixc) {
                const u16* pp = ap - ((gr & 2047) ? lda : 0);
                float pz = (gr & 2047) ? 1.f : 0.f;
                us8 p1 = *(const us8*)pp;
                int kbase = kb + 8 * sq;
#pragma unroll
                for (int e = 0; e < 8; ++e) {
                    float cu = b2f(c1[e]);
                    c1[e] = f2b(cu + (pz * b2f(p1[e]) - cu) * ldv(mixc, kbase + e, dt));
                }
            }
            *(us8*)(As + srow * 40 + 8 * sq) = c1;
        }
        {
            const u16* bp = BT + (size_t)(n0 + srow) * K + kb + 8 * sq;
            *(us8*)(Bs + srow * 40 + 8 * sq) = *(const us8*)bp;
        }
        __syncthreads();
        bf16x8 af[2], bf[2];
#pragma unroll
        for (int fm = 0; fm < 2; ++fm) {
            const u16* p = As + (wr * 32 + fm * 16 + lc) * 40 + lg * 8;
            union { us8 s; bf16x8 v; } u;
            u.s = *(const us8*)p;
            af[fm] = u.v;
        }
#pragma unroll
        for (int fc = 0; fc < 2; ++fc) {
            const u16* p = Bs + (wc * 32 + fc * 16 + lc) * 40 + lg * 8;
            union { us8 s; bf16x8 v; } u;
            u.s = *(const us8*)p;
            bf[fc] = u.v;
        }
#pragma unroll
        for (int fm = 0; fm < 2; ++fm)
#pragma unroll
            for (int fc = 0; fc < 2; ++fc)
                acc[fm][fc] = __builtin_amdgcn_mfma_f32_16x16x32_bf16(
                    af[fm], bf[fc], acc[fm][fc], 0, 0, 0);
        __syncthreads();
    }

#pragma unroll
    for (int fm = 0; fm < 2; ++fm)
#pragma unroll
        for (int fc = 0; fc < 2; ++fc)
#pragma unroll
            for (int r = 0; r < 4; ++r)
                mf_epi(D, ldd, mode, bias, add, ldadd, dt,
                       m0 + wr * 32 + fm * 16 + lg * 4 + r,
                       n0 + wc * 32 + fc * 16 + lc, acc[fm][fc][r]);
}

// ---------- per-head prep ----------
__global__ __launch_bounds__(256) void k_prep(
    u16* __restrict__ k_bf, const u16* __restrict__ a_buf,
    const void* __restrict__ k_k, const void* __restrict__ k_a,
    u16* __restrict__ av, u16* __restrict__ bv, const int* __restrict__ hdr)
{
    const int dt = hdr[0];
    int ht = blockIdx.x * 4 + (threadIdx.x >> 6);
    int j = threadIdx.x & 63;
    int tok = ht >> 4, h = ht & 15, n = h * 64 + j;
    size_t idx = (size_t)tok * 1024 + n;
    float kv = b2f(k_bf[idx]);
    float a  = b2f(a_buf[idx]);
    float kk = kv * ldv(k_k, n, dt);
    float ss = wave_sum(kk * kk);
    float den = fmaxf(sqrtf(ss), 1e-12f);
    float kkn = kk / den;
    k_bf[idx] = f2b(kv * (1.f + (a - 1.f) * ldv(k_a, n, dt)));
    av[idx] = f2b(-kkn);
    bv[idx] = f2b(kkn * a);
}

// ---------- recurrence v7: v5 math + chunked double-buffered LDS pipeline ----------
// All 4 waves of a block share (b,h) => the 5 lane-indexed streams (r,d,k,a,b)
// are block-shared; only v is per-wave. Per 16-step chunk: issue global loads
// to regs EARLY (T14 split), compute 16 steps from LDS buf[cur], then ds_write
// the next chunk + ONE barrier. Sinking damage is capped at one stall per 16
// steps; consumer latency is LDS (~120cy), not L2 (~500cy). Math order is
// identical to v5 -> bit-identical output.
#define KREC_LOADS(T0)                                                          \
    {                                                                           \
        _Pragma("unroll")                                                       \
        for (int it = 0; it < 10; ++it) {                                       \
            const u16* sp = (it < 2) ? r_bf : (it < 4) ? dcy                    \
                          : (it < 6) ? km  : (it < 8) ? av : bv;                \
            int i = ((it & 1) << 8) + tid;                                      \
            int step = i >> 5, dp = i & 31;                                     \
            stg[it] = *(const uint32_t*)(sp +                                   \
                (size_t)(tbase + (T0) + step) * 1024 + h * 64 + dp * 2);        \
        }                                                                       \
        if (tid < 64)                                                           \
            stg[10] = v32[(size_t)(tbase + (T0) + (tid >> 2)) * 512             \
                          + h * 32 + jj0 + (tid & 3)];                          \
    }
#define KREC_WRITES(DST)                                                        \
    {                                                                           \
        uint32_t* lb_ = &lds[DST][0];                                           \
        _Pragma("unroll")                                                       \
        for (int it = 0; it < 10; ++it) {                                       \
            int s = it >> 1;                                                    \
            int i = ((it & 1) << 8) + tid;                                      \
            lb_[s * 512 + i] = stg[it];                                         \
        }                                                                       \
        if (tid < 64) lb_[2560 + tid] = stg[10];                                \
    }
__global__ __launch_bounds__(256) void k_rec(
    const u16* __restrict__ r_bf, const u16* __restrict__ dcy,
    const u16* __restrict__ km, const u16* __restrict__ v_bf,
    const u16* __restrict__ av, const u16* __restrict__ bv,
    u16* __restrict__ o_buf)
{
    const int T = 2048;
    const int tid = threadIdx.x;
    int rq = blockIdx.x & 7, q = blockIdx.x >> 3;
    int wid = tid >> 6, lane = tid & 63;
    int bh = rq * 4 + (q >> 3);          // 0..31; 8 blocks of a bh share an XCD
    int jj0 = (q & 7) * 4;               // block's column-pair base
    int jj = jj0 + wid;                  // this wave's pair -> cols 2jj, 2jj+1
    int b = bh >> 4, h = bh & 15;
    int tbase = b * T;
    const uint32_t* v32 = (const uint32_t*)v_bf;
    uint32_t* o32 = (uint32_t*)o_buf;
    size_t oidx = (size_t)tbase * 512 + h * 32 + jj;

    __shared__ uint32_t lds[2][2624];    // [5 streams][16 steps][32 dw] + 64 dw v
    uint32_t stg[11];

    // prologue: stage chunk 0
    KREC_LOADS(0)
    KREC_WRITES(0)
    __syncthreads();

    float S0 = 0.f, S1 = 0.f;
    for (int c = 0; c < 128; ++c) {
        int cur = c & 1;
        bool more = (c + 1) < 128;
        if (more) KREC_LOADS((c + 1) * 16)          // issue early; hidden by compute
        const u16* lb = (const u16*)&lds[cur][0];
        const uint32_t* lv = &lds[cur][2560];
#pragma unroll
        for (int step = 0; step < 16; ++step) {
            float rf  = b2f(lb[0 * 1024 + step * 64 + lane]);
            float df  = b2f(lb[1 * 1024 + step * 64 + lane]);
            float kf  = b2f(lb[2 * 1024 + step * 64 + lane]);
            float af  = b2f(lb[3 * 1024 + step * 64 + lane]);
            float bf_ = b2f(lb[4 * 1024 + step * 64 + lane]);
            uint32_t vv = lv[step * 4 + wid];       // wave-uniform broadcast
            float vf0 = __uint_as_float(vv << 16);
            float vf1 = __uint_as_float(vv & 0xFFFF0000u);
            float sa0 = dpp_sum64(af * S0);
            float sa1 = dpp_sum64(af * S1);
            float X0 = fmaf(kf, vf0, S0 * df);
            float X1 = fmaf(kf, vf1, S1 * df);
            sa0 = __int_as_float(__builtin_amdgcn_readlane(__float_as_int(sa0), 63));
            sa1 = __int_as_float(__builtin_amdgcn_readlane(__float_as_int(sa1), 63));
            S0 = fmaf(bf_, sa0, X0);
            S1 = fmaf(bf_, sa1, X1);
            float o0 = dpp_sum64(rf * S0);
            float o1 = dpp_sum64(rf * S1);
            if (lane == 63)
                o32[oidx] = (uint32_t)f2b(o0) | ((uint32_t)f2b(o1) << 16);
            oidx += 512;
        }
        if (more) KREC_WRITES(cur ^ 1)
        __syncthreads();
    }
}

// ---------- groupnorm + bonus + gate ----------
__global__ __launch_bounds__(256) void k_post(
    const u16* __restrict__ o_buf, const u16* __restrict__ r_bf,
    const u16* __restrict__ km, const u16* __restrict__ v_bf,
    const u16* __restrict__ g_buf, const void* __restrict__ r_k,
    const void* __restrict__ gnw, const void* __restrict__ gnb,
    u16* __restrict__ ao, const int* __restrict__ hdr)
{
    const int dt = hdr[0];
    int ht = blockIdx.x * 4 + (threadIdx.x >> 6);
    int j = threadIdx.x & 63;
    int tok = ht >> 4, h = ht & 15, n = h * 64 + j;
    size_t idx = (size_t)tok * 1024 + n;
    float o = b2f(o_buf[idx]);
    float mu = wave_sum(o) * (1.f/64.f);
    float d = o - mu;
    float var = wave_sum(d * d) * (1.f/64.f);
    float og = d * rsqrtf(var + 6.4e-4f) * ldv(gnw, n, dt) + ldv(gnb, n, dt);
    float r = b2f(r_bf[idx]), kmv = b2f(km[idx]), v = b2f(v_bf[idx]);
    float bonus = wave_sum(r * kmv * ldv(r_k, n, dt));
    float val = (og + bonus * v) * b2f(g_buf[idx]);
    ao[idx] = f2b(val);
}

// ---------- host ----------
extern "C" void kernel_launch(void* const* d_in, const int* in_sizes, int n_in,
                              void* d_out, int out_size, void* d_ws, size_t ws_size,
                              hipStream_t stream) {
    (void)in_sizes; (void)n_in; (void)out_size; (void)ws_size;
    const void* xP     = d_in[0];
    const void* pre_w  = d_in[1];
    const void* pre_b  = d_in[2];
    const void* attn_w = d_in[3];
    const void* attn_b = d_in[4];
    const void* ffn_w  = d_in[5];
    const void* ffn_b  = d_in[6];
    const void* x_r    = d_in[7];
    const void* x_w    = d_in[8];
    const void* x_k    = d_in[9];
    const void* x_v    = d_in[10];
    const void* x_a    = d_in[11];
    const void* x_g    = d_in[12];
    const void* W_r    = d_in[13];
    const void* W_k    = d_in[14];
    const void* W_v    = d_in[15];
    const void* W_o    = d_in[16];
    const void* w1     = d_in[17];
    const void* w2     = d_in[18];
    const void* w_b    = d_in[19];
    const void* a1     = d_in[20];
    const void* a2     = d_in[21];
    const void* a_b    = d_in[22];
    const void* g1     = d_in[23];
    const void* g2     = d_in[24];
    const void* k_k    = d_in[25];
    const void* k_a    = d_in[26];
    const void* r_k    = d_in[27];
    const void* gn_w   = d_in[28];
    const void* gn_b   = d_in[29];
    const void* ffn_xk = d_in[30];
    const void* WkeyP  = d_in[31];
    const void* WvalP  = d_in[32];

    char* ws = (char*)d_ws;
    const size_t SL = 8388608ull;          // [4096][1024] bf16 slab
    int* hdr    = (int*)(ws + 0);
    u16* hs     = (u16*)(ws + 4096 + SL*0);
    u16* resid1 = (u16*)(ws + 4096 + SL*1);
    u16* dcy    = (u16*)(ws + 4096 + SL*2);
    u16* r_bf   = (u16*)(ws + 4096 + SL*3);
    u16* k_bf   = (u16*)(ws + 4096 + SL*4);
    u16* v_bf   = (u16*)(ws + 4096 + SL*5);
    u16* av_bf  = (u16*)(ws + 4096 + SL*6);
    u16* bv_bf  = (u16*)(ws + 4096 + SL*7);
    u16* a_buf  = (u16*)(ws + 4096 + SL*8);
    u16* g_buf  = (u16*)(ws + 4096 + SL*9);
    u16* tmpw   = (u16*)(ws + 4096 + SL*10);
    u16* tmpa   = (u16*)(ws + 4096 + SL*10 + 524288);
    u16* tmpg   = (u16*)(ws + 4096 + SL*10 + 1048576);
    u16* wT     = (u16*)(ws + 4096 + SL*10 + 2097152);   // 8MB transpose scratch; peak ~90MB
    // overlays (later lifetimes)
    u16* o_buf  = a_buf;                   // a dead after k_prep
    u16* ao_in  = bv_bf;                   // bv dead after k_rec
    u16* hid2   = dcy;                     // dcy dead after k_rec
    u16* hs2    = hs;                      // hs dead after projections
    u16* ffh    = r_bf;                    // [4096,4096] bf16 over r,k,v,av (dead after k_post)

    dim3 blk(256);
    dim3 gm64(16, 64);                     // 64x64-tile grid for N=1024
    dim3 g4096(32, 32);
    dim3 t1024(32, 32), tKey(128, 32), tVal(32, 128), t64(32, 2), t128(32, 4);
    dim3 tl64(2, 32), tl128(4, 32);        // lora up-weight transposes
    k_probe<<<1, blk, 0, stream>>>((const u16*)xP, (const u16*)WkeyP, (const u16*)WvalP, hdr);
    k_ln_in<<<4096, blk, 0, stream>>>(xP, WkeyP, WvalP, pre_w, pre_b, attn_w, attn_b, resid1, hs, hdr);

    // attn projections (fused token-shift mix) -- all MFMA
    k_tr<<<t1024, blk, 0, stream>>>(W_r, 1024, 1024, wT, hdr);
    k_mf64<<<gm64, blk, 0, stream>>>(hs, 1024, x_r, wT, r_bf, 1024, 1024, 1, nullptr, nullptr, 0, hdr);
    k_tr<<<tl64, blk, 0, stream>>>(w1, 1024, 64, wT, hdr);
    k_mf64<<<dim3(1, 64), blk, 0, stream>>>(hs, 1024, x_w, wT, tmpw, 64, 1024, 2, nullptr, nullptr, 0, hdr);
    k_tr<<<t64, blk, 0, stream>>>(w2, 64, 1024, wT, hdr);
    k_mf64<<<gm64, blk, 0, stream>>>(tmpw, 64, nullptr, wT, dcy, 1024, 64, 4, w_b, nullptr, 0, hdr);
    k_tr<<<t1024, blk, 0, stream>>>(W_k, 1024, 1024, wT, hdr);
    k_mf64<<<gm64, blk, 0, stream>>>(hs, 1024, x_k, wT, k_bf, 1024, 1024, 1, nullptr, nullptr, 0, hdr);
    k_tr<<<t1024, blk, 0, stream>>>(W_v, 1024, 1024, wT, hdr);
    k_mf64<<<gm64, blk, 0, stream>>>(hs, 1024, x_v, wT, v_bf, 1024, 1024, 1, nullptr, nullptr, 0, hdr);
    k_tr<<<tl64, blk, 0, stream>>>(a1, 1024, 64, wT, hdr);
    k_mf64<<<dim3(1, 64), blk, 0, stream>>>(hs, 1024, x_a, wT, tmpa, 64, 1024, 1, nullptr, nullptr, 0, hdr);
    k_tr<<<t64, blk, 0, stream>>>(a2, 64, 1024, wT, hdr);
    k_mf64<<<gm64, blk, 0, stream>>>(tmpa, 64, nullptr, wT, a_buf, 1024, 64, 5, a_b, nullptr, 0, hdr);
    k_tr<<<tl128, blk, 0, stream>>>(g1, 1024, 128, wT, hdr);
    k_mf64<<<dim3(2, 64), blk, 0, stream>>>(hs, 1024, x_g, wT, tmpg, 128, 1024, 3, nullptr, nullptr, 0, hdr);
    k_tr<<<t128, blk, 0, stream>>>(g2, 128, 1024, wT, hdr);
    k_mf64<<<gm64, blk, 0, stream>>>(tmpg, 128, nullptr, wT, g_buf, 1024, 128, 1, nullptr, nullptr, 0, hdr);

    k_prep<<<16384, blk, 0, stream>>>(k_bf, a_buf, k_k, k_a, av_bf, bv_bf, hdr);
    k_rec<<<256, blk, 0, stream>>>(r_bf, dcy, k_bf, v_bf, av_bf, bv_bf, o_buf);
    k_post<<<16384, blk, 0, stream>>>(o_buf, r_bf, k_bf, v_bf, g_buf, r_k, gn_w, gn_b, ao_in, hdr);

    // output projection + residual -> hid2 (bf16)
    k_tr<<<t1024, blk, 0, stream>>>(W_o, 1024, 1024, wT, hdr);
    k_mf64<<<gm64, blk, 0, stream>>>(ao_in, 1024, nullptr, wT, hid2, 1024, 1024, 8, nullptr, resid1, 1024, hdr);

    // FFN; final GEMM writes FLOAT32 output
    k_ln_bf<<<4096, blk, 0, stream>>>(hid2, ffn_w, ffn_b, hs2, hdr);
    k_tr<<<tKey, blk, 0, stream>>>(WkeyP, 1024, 4096, wT, hdr);
    k_mf<<<g4096, blk, 0, stream>>>(hs2, 1024, ffn_xk, wT, ffh, 4096, 1024, 7, nullptr, nullptr, 0, hdr);
    k_tr<<<tVal, blk, 0, stream>>>(WvalP, 4096, 1024, wT, hdr);
    k_mf64<<<gm64, blk, 0, stream>>>(ffh, 4096, nullptr, wT, (float*)d_out, 1024, 4096, 6, nullptr, hid2, 1024, hdr);
}

// Round 13
// 1248.801 us; speedup vs baseline: 1.9925x; 1.0447x over previous
//
#include <hip/hip_runtime.h>
#include <hip/hip_bf16.h>
#include <cstdint>

typedef unsigned short u16;
typedef unsigned short us8 __attribute__((ext_vector_type(8)));
typedef __bf16 bf16x8 __attribute__((ext_vector_type(8)));
typedef float f32x4 __attribute__((ext_vector_type(4)));
typedef uint32_t u32x2 __attribute__((ext_vector_type(2)));
typedef uint32_t u32x4v __attribute__((ext_vector_type(4)));

// ---------- helpers ----------
__device__ __forceinline__ float b2f(u16 u) {
    union { float f; uint32_t i; } x; x.i = ((uint32_t)u) << 16; return x.f;
}
__device__ __forceinline__ u16 f2b(float f) {
    uint32_t u = __float_as_uint(f);
    uint32_t r = (u + 0x7FFFu + ((u >> 16) & 1u)) >> 16;
    return (u16)r;
}
__device__ __forceinline__ float sigm(float x) { return 1.0f / (1.0f + __expf(-x)); }
__device__ __forceinline__ float ldv(const void* p, size_t i, int dt) {
    return dt ? b2f(((const u16*)p)[i]) : ((const float*)p)[i];
}

__device__ __forceinline__ float wave_sum(float v) {
#pragma unroll
    for (int o = 32; o > 0; o >>= 1) v += __shfl_xor(v, o, 64);
    return v;
}
__device__ __forceinline__ void block_reduce2(float& a, float& b, float* sm) {
    int tid = threadIdx.x, wid = tid >> 6, lane = tid & 63;
    float as = wave_sum(a), bs = wave_sum(b);
    __syncthreads();
    if (lane == 0) { sm[wid] = as; sm[8 + wid] = bs; }
    __syncthreads();
    a = sm[0] + sm[1] + sm[2] + sm[3];
    b = sm[8] + sm[9] + sm[10] + sm[11];
}

// 64-lane sum via DPP ladder; full sum lands in lane 63.
__device__ __forceinline__ float dpp_sum64(float x) {
    x += __int_as_float(__builtin_amdgcn_update_dpp(0, __float_as_int(x), 0x111, 0xf, 0xf, true)); // row_shr:1
    x += __int_as_float(__builtin_amdgcn_update_dpp(0, __float_as_int(x), 0x112, 0xf, 0xf, true)); // row_shr:2
    x += __int_as_float(__builtin_amdgcn_update_dpp(0, __float_as_int(x), 0x114, 0xf, 0xf, true)); // row_shr:4
    x += __int_as_float(__builtin_amdgcn_update_dpp(0, __float_as_int(x), 0x118, 0xf, 0xf, true)); // row_shr:8
    x += __int_as_float(__builtin_amdgcn_update_dpp(0, __float_as_int(x), 0x142, 0xa, 0xf, true)); // row_bcast:15
    x += __int_as_float(__builtin_amdgcn_update_dpp(0, __float_as_int(x), 0x143, 0xc, 0xf, true)); // row_bcast:31
    return x;
}

// ---------- probe: dtype (hdr[0]) + which big array is x (hdr[1]) ----------
__global__ void k_probe(const u16* __restrict__ a0, const u16* __restrict__ a1,
                        const u16* __restrict__ a2, int* __restrict__ hdr) {
    __shared__ int wcnt;
    __shared__ float part[256];
    __shared__ float mag[3];
    int tid = threadIdx.x;
    if (tid == 0) wcnt = 0;
    __syncthreads();
    const u16* arr[3] = { a0, a1, a2 };
    int wild = 0;
    for (int s = 0; s < 3; ++s)
        for (int i = tid; i < 4096; i += 256) {
            u16 u = arr[s][i];
            int e = (u >> 7) & 0xFF;
            float av = fabsf(b2f(u));
            if (e == 0xFF || av > 100.f) wild++;
        }
    atomicAdd(&wcnt, wild);
    __syncthreads();
    int dt = (wcnt < 96) ? 1 : 0;
    for (int s = 0; s < 3; ++s) {
        float m = 0.f;
        if (dt) { for (int i = tid; i < 4096; i += 256) m += fabsf(b2f(arr[s][i])); }
        else    { const float* f = (const float*)arr[s];
                  for (int i = tid; i < 2048; i += 256) m += fabsf(f[i]); }
        part[tid] = m; __syncthreads();
        if (tid == 0) { float t = 0; for (int i = 0; i < 256; ++i) t += part[i]; mag[s] = t; }
        __syncthreads();
    }
    if (tid == 0) {
        int xs = 0;
        if (mag[1] > mag[xs]) xs = 1;
        if (mag[2] > mag[xs]) xs = 2;   // x ~N(0,1) vs 0.02-scale weights
        hdr[0] = dt; hdr[1] = xs;
    }
}

// ---------- double layernorm: x -> resid bf16, hs bf16 ----------
__global__ __launch_bounds__(256) void k_ln_in(
    const void* __restrict__ xa, const void* __restrict__ xb, const void* __restrict__ xc,
    const void* __restrict__ pw, const void* __restrict__ pb,
    const void* __restrict__ aw, const void* __restrict__ ab,
    u16* __restrict__ resid, u16* __restrict__ hs, const int* __restrict__ hdr)
{
    __shared__ float sm[16];
    const int dt = hdr[0], xs = hdr[1];
    const void* x = (xs == 0) ? xa : (xs == 1 ? xb : xc);
    int tok = blockIdx.x, tid = threadIdx.x;
    int c = tid * 4;
    size_t off = (size_t)tok * 1024 + c;
    float v0, v1, v2, v3;
    if (dt) {
        ushort4 xv = *(const ushort4*)((const u16*)x + off);
        v0 = b2f(xv.x); v1 = b2f(xv.y); v2 = b2f(xv.z); v3 = b2f(xv.w);
    } else {
        float4 xv = *(const float4*)((const float*)x + off);
        v0 = xv.x; v1 = xv.y; v2 = xv.z; v3 = xv.w;
    }
    float s = v0 + v1 + v2 + v3;
    float q = v0*v0 + v1*v1 + v2*v2 + v3*v3;
    block_reduce2(s, q, sm);
    float mean = s * (1.f/1024.f);
    float var  = q * (1.f/1024.f) - mean*mean;
    float rs = rsqrtf(var + 1e-5f);
    float h0 = (v0-mean)*rs*ldv(pw,c+0,dt) + ldv(pb,c+0,dt);
    float h1 = (v1-mean)*rs*ldv(pw,c+1,dt) + ldv(pb,c+1,dt);
    float h2 = (v2-mean)*rs*ldv(pw,c+2,dt) + ldv(pb,c+2,dt);
    float h3 = (v3-mean)*rs*ldv(pw,c+3,dt) + ldv(pb,c+3,dt);
    ushort4 rv; rv.x = f2b(h0); rv.y = f2b(h1); rv.z = f2b(h2); rv.w = f2b(h3);
    *(ushort4*)(resid + off) = rv;
    float s2 = h0 + h1 + h2 + h3;
    float q2 = h0*h0 + h1*h1 + h2*h2 + h3*h3;
    block_reduce2(s2, q2, sm);
    float m2 = s2 * (1.f/1024.f);
    float vr2 = q2 * (1.f/1024.f) - m2*m2;
    float rs2 = rsqrtf(vr2 + 1e-5f);
    ushort4 o;
    o.x = f2b((h0-m2)*rs2*ldv(aw,c+0,dt) + ldv(ab,c+0,dt));
    o.y = f2b((h1-m2)*rs2*ldv(aw,c+1,dt) + ldv(ab,c+1,dt));
    o.z = f2b((h2-m2)*rs2*ldv(aw,c+2,dt) + ldv(ab,c+2,dt));
    o.w = f2b((h3-m2)*rs2*ldv(aw,c+3,dt) + ldv(ab,c+3,dt));
    *(ushort4*)(hs + off) = o;
}

// ---------- layernorm bf16(ws) -> bf16 ----------
__global__ __launch_bounds__(256) void k_ln_bf(
    const u16* __restrict__ in, const void* __restrict__ w, const void* __restrict__ b,
    u16* __restrict__ out, const int* __restrict__ hdr)
{
    __shared__ float sm[16];
    const int dt = hdr[0];
    int tok = blockIdx.x, tid = threadIdx.x;
    int c = tid * 4;
    size_t off = (size_t)tok * 1024 + c;
    ushort4 xv = *(const ushort4*)(in + off);
    float v0 = b2f(xv.x), v1 = b2f(xv.y), v2 = b2f(xv.z), v3 = b2f(xv.w);
    float s = v0 + v1 + v2 + v3;
    float q = v0*v0 + v1*v1 + v2*v2 + v3*v3;
    block_reduce2(s, q, sm);
    float mean = s * (1.f/1024.f);
    float var  = q * (1.f/1024.f) - mean*mean;
    float rs = rsqrtf(var + 1e-5f);
    ushort4 o;
    o.x = f2b((v0-mean)*rs*ldv(w,c+0,dt) + ldv(b,c+0,dt));
    o.y = f2b((v1-mean)*rs*ldv(w,c+1,dt) + ldv(b,c+1,dt));
    o.z = f2b((v2-mean)*rs*ldv(w,c+2,dt) + ldv(b,c+2,dt));
    o.w = f2b((v3-mean)*rs*ldv(w,c+3,dt) + ldv(b,c+3,dt));
    *(ushort4*)(out + off) = o;
}

// ---------- weight transpose: W[K][N] (f32|bf16) -> WT[N][K] bf16 ----------
__global__ __launch_bounds__(256) void k_tr(
    const void* __restrict__ W, int K, int N, u16* __restrict__ WT,
    const int* __restrict__ hdr)
{
    const int dt = hdr[0];
    __shared__ u16 t[32][33];
    int n0 = blockIdx.x * 32, k0 = blockIdx.y * 32;
    int tx = threadIdx.x & 31, ty = threadIdx.x >> 5;   // 32 x 8
#pragma unroll
    for (int r = 0; r < 32; r += 8) {
        int k = k0 + ty + r;
        t[ty + r][tx] = f2b(ldv(W, (size_t)k * N + n0 + tx, dt));  // f2b(b2f(u))==u
    }
    __syncthreads();
#pragma unroll
    for (int r = 0; r < 32; r += 8) {
        int n = n0 + ty + r;
        WT[(size_t)n * K + k0 + tx] = t[tx][ty + r];
    }
}

// ---------- shared epilogue for MFMA GEMMs ----------
// modes: 1=raw 2=tanh 3=sigm 4=exp(-0.6065*sigm(v+bias)) 5=sigm(v+bias)
//        6=F32 OUT v+add 7=relu^2 8=bf16 v+add
__device__ __forceinline__ void mf_epi(
    void* D, int ldd, int mode, const void* bias,
    const u16* add, int ldadd, int dt,
    int row, int col, float v)
{
    size_t di = (size_t)row * ldd + col;
    if (mode == 6) {
        ((float*)D)[di] = v + b2f(add[(size_t)row * ldadd + col]);
        return;
    }
    float rr;
    switch (mode) {
        default: rr = v; break;
        case 2: rr = tanhf(v); break;
        case 3: rr = sigm(v); break;
        case 4: rr = __expf(-0.6065306597126334f * sigm(v + ldv(bias, col, dt))); break;
        case 5: rr = sigm(v + ldv(bias, col, dt)); break;
        case 7: { float t = fmaxf(v, 0.f); rr = t * t; } break;
        case 8: rr = v + b2f(add[(size_t)row * ldadd + col]); break;
    }
    ((u16*)D)[di] = f2b(rr);
}

// ---------- MFMA GEMM: 128x128 tile (for N=4096 outputs) ----------
__global__ __launch_bounds__(256, 2) void k_mf(
    const u16* __restrict__ A, int lda, const void* __restrict__ mixc,
    const u16* __restrict__ BT,
    void* __restrict__ D, int ldd,
    int K, int mode,
    const void* __restrict__ bias,
    const u16* __restrict__ add, int ldadd, const int* __restrict__ hdr)
{
    __shared__ u16 As[128 * 40];     // 10240 B
    __shared__ u16 Bs[128 * 40];     // 10240 B
    const int dt = hdr[0];
    const int tid = threadIdx.x;
    const int m0 = blockIdx.y * 128, n0 = blockIdx.x * 128;
    const int wid = tid >> 6, lane = tid & 63;
    const int wr = wid >> 1, wc = wid & 1;
    const int lg = lane >> 4, lc = lane & 15;
    const int srow = tid >> 1, shalf = tid & 1;   // staging: 128 rows x 2 k-halves

    f32x4 acc[4][4];
#pragma unroll
    for (int i = 0; i < 4; ++i)
#pragma unroll
        for (int j = 0; j < 4; ++j) acc[i][j] = (f32x4)0.f;

    for (int kb = 0; kb < K; kb += 32) {
        {
            int gr = m0 + srow;
            const u16* ap = A + (size_t)gr * lda + kb + 16 * shalf;
            us8 c1 = *(const us8*)ap;
            us8 c2 = *(const us8*)(ap + 8);
            if (mixc) {
                const u16* pp = ap - ((gr & 2047) ? lda : 0);
                float pz = (gr & 2047) ? 1.f : 0.f;
                us8 p1 = *(const us8*)pp;
                us8 p2 = *(const us8*)(pp + 8);
                int kbase = kb + 16 * shalf;
#pragma unroll
                for (int e = 0; e < 8; ++e) {
                    float cu1 = b2f(c1[e]), cu2 = b2f(c2[e]);
                    c1[e] = f2b(cu1 + (pz * b2f(p1[e]) - cu1) * ldv(mixc, kbase + e, dt));
                    c2[e] = f2b(cu2 + (pz * b2f(p2[e]) - cu2) * ldv(mixc, kbase + 8 + e, dt));
                }
            }
            u16* dst = As + srow * 40 + 16 * shalf;
            *(us8*)dst = c1;
            *(us8*)(dst + 8) = c2;
        }
        {
            const u16* bp = BT + (size_t)(n0 + srow) * K + kb + 16 * shalf;
            u16* dst = Bs + srow * 40 + 16 * shalf;
            *(us8*)dst = *(const us8*)bp;
            *(us8*)(dst + 8) = *(const us8*)(bp + 8);
        }
        __syncthreads();
        bf16x8 af[4], bf[4];
#pragma unroll
        for (int fm = 0; fm < 4; ++fm) {
            const u16* p = As + (wr * 64 + fm * 16 + lc) * 40 + lg * 8;
            union { us8 s; bf16x8 v; } u;
            u.s = *(const us8*)p;
            af[fm] = u.v;
        }
#pragma unroll
        for (int fc = 0; fc < 4; ++fc) {
            const u16* p = Bs + (wc * 64 + fc * 16 + lc) * 40 + lg * 8;
            union { us8 s; bf16x8 v; } u;
            u.s = *(const us8*)p;
            bf[fc] = u.v;
        }
#pragma unroll
        for (int fm = 0; fm < 4; ++fm)
#pragma unroll
            for (int fc = 0; fc < 4; ++fc)
                acc[fm][fc] = __builtin_amdgcn_mfma_f32_16x16x32_bf16(
                    af[fm], bf[fc], acc[fm][fc], 0, 0, 0);
        __syncthreads();
    }

#pragma unroll
    for (int fm = 0; fm < 4; ++fm)
#pragma unroll
        for (int fc = 0; fc < 4; ++fc)
#pragma unroll
            for (int r = 0; r < 4; ++r)
                mf_epi(D, ldd, mode, bias, add, ldadd, dt,
                       m0 + wr * 64 + fm * 16 + lg * 4 + r,
                       n0 + wc * 64 + fc * 16 + lc, acc[fm][fc][r]);
}

// ---------- MFMA GEMM: 64x64 tile (for N<=1024 outputs) ----------
__global__ __launch_bounds__(256, 4) void k_mf64(
    const u16* __restrict__ A, int lda, const void* __restrict__ mixc,
    const u16* __restrict__ BT,
    void* __restrict__ D, int ldd,
    int K, int mode,
    const void* __restrict__ bias,
    const u16* __restrict__ add, int ldadd, const int* __restrict__ hdr)
{
    __shared__ u16 As[64 * 40];      // 5120 B
    __shared__ u16 Bs[64 * 40];      // 5120 B
    const int dt = hdr[0];
    const int tid = threadIdx.x;
    const int m0 = blockIdx.y * 64, n0 = blockIdx.x * 64;
    const int wid = tid >> 6, lane = tid & 63;
    const int wr = wid >> 1, wc = wid & 1;
    const int lg = lane >> 4, lc = lane & 15;
    const int srow = tid >> 2, sq = tid & 3;      // staging: 64 rows x 4 k-quarters

    f32x4 acc[2][2];
#pragma unroll
    for (int i = 0; i < 2; ++i)
#pragma unroll
        for (int j = 0; j < 2; ++j) acc[i][j] = (f32x4)0.f;

    for (int kb = 0; kb < K; kb += 32) {
        {
            int gr = m0 + srow;
            const u16* ap = A + (size_t)gr * lda + kb + 8 * sq;
            us8 c1 = *(const us8*)ap;
            if (mixc) {
                const u16* pp = ap - ((gr & 2047) ? lda : 0);
                float pz = (gr & 2047) ? 1.f : 0.f;
                us8 p1 = *(const us8*)pp;
                int kbase = kb + 8 * sq;
#pragma unroll
                for (int e = 0; e < 8; ++e) {
                    float cu = b2f(c1[e]);
                    c1[e] = f2b(cu + (pz * b2f(p1[e]) - cu) * ldv(mixc, kbase + e, dt));
                }
            }
            *(us8*)(As + srow * 40 + 8 * sq) = c1;
        }
        {
            const u16* bp = BT + (size_t)(n0 + srow) * K + kb + 8 * sq;
            *(us8*)(Bs + srow * 40 + 8 * sq) = *(const us8*)bp;
        }
        __syncthreads();
        bf16x8 af[2], bf[2];
#pragma unroll
        for (int fm = 0; fm < 2; ++fm) {
            const u16* p = As + (wr * 32 + fm * 16 + lc) * 40 + lg * 8;
            union { us8 s; bf16x8 v; } u;
            u.s = *(const us8*)p;
            af[fm] = u.v;
        }
#pragma unroll
        for (int fc = 0; fc < 2; ++fc) {
            const u16* p = Bs + (wc * 32 + fc * 16 + lc) * 40 + lg * 8;
            union { us8 s; bf16x8 v; } u;
            u.s = *(const us8*)p;
            bf[fc] = u.v;
        }
#pragma unroll
        for (int fm = 0; fm < 2; ++fm)
#pragma unroll
            for (int fc = 0; fc < 2; ++fc)
                acc[fm][fc] = __builtin_amdgcn_mfma_f32_16x16x32_bf16(
                    af[fm], bf[fc], acc[fm][fc], 0, 0, 0);
        __syncthreads();
    }

#pragma unroll
    for (int fm = 0; fm < 2; ++fm)
#pragma unroll
        for (int fc = 0; fc < 2; ++fc)
#pragma unroll
            for (int r = 0; r < 4; ++r)
                mf_epi(D, ldd, mode, bias, add, ldadd, dt,
                       m0 + wr * 32 + fm * 16 + lg * 4 + r,
                       n0 + wc * 32 + fc * 16 + lc, acc[fm][fc][r]);
}

// ---------- per-head prep ----------
__global__ __launch_bounds__(256) void k_prep(
    u16* __restrict__ k_bf, const u16* __restrict__ a_buf,
    const void* __restrict__ k_k, const void* __restrict__ k_a,
    u16* __restrict__ av, u16* __restrict__ bv, const int* __restrict__ hdr)
{
    const int dt = hdr[0];
    int ht = blockIdx.x * 4 + (threadIdx.x >> 6);
    int j = threadIdx.x & 63;
    int tok = ht >> 4, h = ht & 15, n = h * 64 + j;
    size_t idx = (size_t)tok * 1024 + n;
    float kv = b2f(k_bf[idx]);
    float a  = b2f(a_buf[idx]);
    float kk = kv * ldv(k_k, n, dt);
    float ss = wave_sum(kk * kk);
    float den = fmaxf(sqrtf(ss), 1e-12f);
    float kkn = kk / den;
    k_bf[idx] = f2b(kv * (1.f + (a - 1.f) * ldv(k_a, n, dt)));
    av[idx] = f2b(-kkn);
    bv[idx] = f2b(kkn * a);
}

// ---------- recurrence v8: v7 pipeline + TRANSPOSED LDS ([stream][lane][16 steps]) ----------
// R12 diagnosis: v7's 6 scalar ds_read_u16/step, read->use serialized at ~120cy
// LDS latency = ~600cy/step of exposed latency (per-SIMD issue only ~13%).
// v8: lane-major LDS rows (20 u16 = 40B stride; dword-stride 10, gcd(10,32)=2
// -> 4-way aliasing on b64, ~1.6x, cheap). Each lane reads a whole 16-step
// chunk per stream with 4x ds_read_b64 (20 reads/chunk total + 4 broadcast
// b128 for v); the 16-step body is then register-only. Math order identical.
#define KREC_LOADS(T0)                                                          \
    {                                                                           \
        _Pragma("unroll")                                                       \
        for (int it = 0; it < 10; ++it) {                                       \
            const u16* sp = (it < 2) ? r_bf : (it < 4) ? dcy                    \
                          : (it < 6) ? km  : (it < 8) ? av : bv;                \
            int i = ((it & 1) << 8) + tid;                                      \
            int step = i >> 5, dp = i & 31;                                     \
            stg[it] = *(const uint32_t*)(sp +                                   \
                (size_t)(tbase + (T0) + step) * 1024 + h * 64 + dp * 2);        \
        }                                                                       \
        if (tid < 64)                                                           \
            stg[10] = v32[(size_t)(tbase + (T0) + (tid >> 2)) * 512             \
                          + h * 32 + jj0 + (tid & 3)];                          \
    }
#define KREC_WRITES(DST)                                                        \
    {                                                                           \
        u16* b_ = (u16*)&lds[DST][0];                                           \
        _Pragma("unroll")                                                       \
        for (int it = 0; it < 10; ++it) {                                       \
            int s = it >> 1;                                                    \
            int i = ((it & 1) << 8) + tid;                                      \
            int step = i >> 5, dp = i & 31;                                     \
            b_[s * 1280 + (2 * dp) * 20 + step]     = (u16)(stg[it] & 0xFFFFu); \
            b_[s * 1280 + (2 * dp + 1) * 20 + step] = (u16)(stg[it] >> 16);     \
        }                                                                       \
        if (tid < 64) lds[DST][3200 + (tid & 3) * 16 + (tid >> 2)] = stg[10];   \
    }
__device__ __forceinline__ float bfsel(uint32_t u, int hi) {
    return hi ? __uint_as_float(u & 0xFFFF0000u) : __uint_as_float(u << 16);
}
__global__ __launch_bounds__(256) void k_rec(
    const u16* __restrict__ r_bf, const u16* __restrict__ dcy,
    const u16* __restrict__ km, const u16* __restrict__ v_bf,
    const u16* __restrict__ av, const u16* __restrict__ bv,
    u16* __restrict__ o_buf)
{
    const int T = 2048;
    const int tid = threadIdx.x;
    int rq = blockIdx.x & 7, q = blockIdx.x >> 3;
    int wid = tid >> 6, lane = tid & 63;
    int bh = rq * 4 + (q >> 3);          // 0..31; 8 blocks of a bh share an XCD
    int jj0 = (q & 7) * 4;               // block's column-pair base
    int jj = jj0 + wid;                  // this wave's pair -> cols 2jj, 2jj+1
    int b = bh >> 4, h = bh & 15;
    int tbase = b * T;
    const uint32_t* v32 = (const uint32_t*)v_bf;
    uint32_t* o32 = (uint32_t*)o_buf;
    size_t oidx = (size_t)tbase * 512 + h * 32 + jj;

    // per buffer: 5 streams x 64 lanes x 20 u16 (16 data + 4 pad) = 3200 dw,
    // then v: 4 waves x 16 steps u32 = 64 dw. Total 3264 dw = 13056 B; x2.
    __shared__ uint32_t lds[2][3264];
    uint32_t stg[11];

    // prologue: stage chunk 0
    KREC_LOADS(0)
    KREC_WRITES(0)
    __syncthreads();

    float S0 = 0.f, S1 = 0.f;
    for (int c = 0; c < 128; ++c) {
        int cur = c & 1;
        bool more = (c + 1) < 128;
        if (more) KREC_LOADS((c + 1) * 16)          // issue early; hidden by compute
        // bulk LDS -> registers: 4x b64 per stream + 4x b128 broadcast for v
        const char* lbb = (const char*)&lds[cur][0];
        u32x2 rA[4], dA[4], kA[4], aA[4], bA[4];
        u32x4v vA[4];
#pragma unroll
        for (int qq = 0; qq < 4; ++qq) {
            rA[qq] = *(const u32x2*)(lbb + 0 * 2560 + lane * 40 + qq * 8);
            dA[qq] = *(const u32x2*)(lbb + 1 * 2560 + lane * 40 + qq * 8);
            kA[qq] = *(const u32x2*)(lbb + 2 * 2560 + lane * 40 + qq * 8);
            aA[qq] = *(const u32x2*)(lbb + 3 * 2560 + lane * 40 + qq * 8);
            bA[qq] = *(const u32x2*)(lbb + 4 * 2560 + lane * 40 + qq * 8);
            vA[qq] = *(const u32x4v*)(lbb + 12800 + wid * 64 + qq * 16);
        }
#pragma unroll
        for (int step = 0; step < 16; ++step) {
            const int qq = step >> 2, ee = (step >> 1) & 1, hi = step & 1;
            float rf  = bfsel(rA[qq][ee], hi);
            float df  = bfsel(dA[qq][ee], hi);
            float kf  = bfsel(kA[qq][ee], hi);
            float af  = bfsel(aA[qq][ee], hi);
            float bf_ = bfsel(bA[qq][ee], hi);
            uint32_t vv = vA[qq][step & 3];
            float vf0 = __uint_as_float(vv << 16);
            float vf1 = __uint_as_float(vv & 0xFFFF0000u);
            float sa0 = dpp_sum64(af * S0);
            float sa1 = dpp_sum64(af * S1);
            float X0 = fmaf(kf, vf0, S0 * df);
            float X1 = fmaf(kf, vf1, S1 * df);
            sa0 = __int_as_float(__builtin_amdgcn_readlane(__float_as_int(sa0), 63));
            sa1 = __int_as_float(__builtin_amdgcn_readlane(__float_as_int(sa1), 63));
            S0 = fmaf(bf_, sa0, X0);
            S1 = fmaf(bf_, sa1, X1);
            float o0 = dpp_sum64(rf * S0);
            float o1 = dpp_sum64(rf * S1);
            if (lane == 63)
                o32[oidx] = (uint32_t)f2b(o0) | ((uint32_t)f2b(o1) << 16);
            oidx += 512;
        }
        if (more) KREC_WRITES(cur ^ 1)
        __syncthreads();
    }
}

// ---------- groupnorm + bonus + gate ----------
__global__ __launch_bounds__(256) void k_post(
    const u16* __restrict__ o_buf, const u16* __restrict__ r_bf,
    const u16* __restrict__ km, const u16* __restrict__ v_bf,
    const u16* __restrict__ g_buf, const void* __restrict__ r_k,
    const void* __restrict__ gnw, const void* __restrict__ gnb,
    u16* __restrict__ ao, const int* __restrict__ hdr)
{
    const int dt = hdr[0];
    int ht = blockIdx.x * 4 + (threadIdx.x >> 6);
    int j = threadIdx.x & 63;
    int tok = ht >> 4, h = ht & 15, n = h * 64 + j;
    size_t idx = (size_t)tok * 1024 + n;
    float o = b2f(o_buf[idx]);
    float mu = wave_sum(o) * (1.f/64.f);
    float d = o - mu;
    float var = wave_sum(d * d) * (1.f/64.f);
    float og = d * rsqrtf(var + 6.4e-4f) * ldv(gnw, n, dt) + ldv(gnb, n, dt);
    float r = b2f(r_bf[idx]), kmv = b2f(km[idx]), v = b2f(v_bf[idx]);
    float bonus = wave_sum(r * kmv * ldv(r_k, n, dt));
    float val = (og + bonus * v) * b2f(g_buf[idx]);
    ao[idx] = f2b(val);
}

// ---------- host ----------
extern "C" void kernel_launch(void* const* d_in, const int* in_sizes, int n_in,
                              void* d_out, int out_size, void* d_ws, size_t ws_size,
                              hipStream_t stream) {
    (void)in_sizes; (void)n_in; (void)out_size; (void)ws_size;
    const void* xP     = d_in[0];
    const void* pre_w  = d_in[1];
    const void* pre_b  = d_in[2];
    const void* attn_w = d_in[3];
    const void* attn_b = d_in[4];
    const void* ffn_w  = d_in[5];
    const void* ffn_b  = d_in[6];
    const void* x_r    = d_in[7];
    const void* x_w    = d_in[8];
    const void* x_k    = d_in[9];
    const void* x_v    = d_in[10];
    const void* x_a    = d_in[11];
    const void* x_g    = d_in[12];
    const void* W_r    = d_in[13];
    const void* W_k    = d_in[14];
    const void* W_v    = d_in[15];
    const void* W_o    = d_in[16];
    const void* w1     = d_in[17];
    const void* w2     = d_in[18];
    const void* w_b    = d_in[19];
    const void* a1     = d_in[20];
    const void* a2     = d_in[21];
    const void* a_b    = d_in[22];
    const void* g1     = d_in[23];
    const void* g2     = d_in[24];
    const void* k_k    = d_in[25];
    const void* k_a    = d_in[26];
    const void* r_k    = d_in[27];
    const void* gn_w   = d_in[28];
    const void* gn_b   = d_in[29];
    const void* ffn_xk = d_in[30];
    const void* WkeyP  = d_in[31];
    const void* WvalP  = d_in[32];

    char* ws = (char*)d_ws;
    const size_t SL = 8388608ull;          // [4096][1024] bf16 slab
    int* hdr    = (int*)(ws + 0);
    u16* hs     = (u16*)(ws + 4096 + SL*0);
    u16* resid1 = (u16*)(ws + 4096 + SL*1);
    u16* dcy    = (u16*)(ws + 4096 + SL*2);
    u16* r_bf   = (u16*)(ws + 4096 + SL*3);
    u16* k_bf   = (u16*)(ws + 4096 + SL*4);
    u16* v_bf   = (u16*)(ws + 4096 + SL*5);
    u16* av_bf  = (u16*)(ws + 4096 + SL*6);
    u16* bv_bf  = (u16*)(ws + 4096 + SL*7);
    u16* a_buf  = (u16*)(ws + 4096 + SL*8);
    u16* g_buf  = (u16*)(ws + 4096 + SL*9);
    u16* tmpw   = (u16*)(ws + 4096 + SL*10);
    u16* tmpa   = (u16*)(ws + 4096 + SL*10 + 524288);
    u16* tmpg   = (u16*)(ws + 4096 + SL*10 + 1048576);
    u16* wT     = (u16*)(ws + 4096 + SL*10 + 2097152);   // 8MB transpose scratch; peak ~90MB
    // overlays (later lifetimes)
    u16* o_buf  = a_buf;                   // a dead after k_prep
    u16* ao_in  = bv_bf;                   // bv dead after k_rec
    u16* hid2   = dcy;                     // dcy dead after k_rec
    u16* hs2    = hs;                      // hs dead after projections
    u16* ffh    = r_bf;                    // [4096,4096] bf16 over r,k,v,av (dead after k_post)

    dim3 blk(256);
    dim3 gm64(16, 64);                     // 64x64-tile grid for N=1024
    dim3 g4096(32, 32);
    dim3 t1024(32, 32), tKey(128, 32), tVal(32, 128), t64(32, 2), t128(32, 4);
    dim3 tl64(2, 32), tl128(4, 32);        // lora up-weight transposes
    k_probe<<<1, blk, 0, stream>>>((const u16*)xP, (const u16*)WkeyP, (const u16*)WvalP, hdr);
    k_ln_in<<<4096, blk, 0, stream>>>(xP, WkeyP, WvalP, pre_w, pre_b, attn_w, attn_b, resid1, hs, hdr);

    // attn projections (fused token-shift mix) -- all MFMA
    k_tr<<<t1024, blk, 0, stream>>>(W_r, 1024, 1024, wT, hdr);
    k_mf64<<<gm64, blk, 0, stream>>>(hs, 1024, x_r, wT, r_bf, 1024, 1024, 1, nullptr, nullptr, 0, hdr);
    k_tr<<<tl64, blk, 0, stream>>>(w1, 1024, 64, wT, hdr);
    k_mf64<<<dim3(1, 64), blk, 0, stream>>>(hs, 1024, x_w, wT, tmpw, 64, 1024, 2, nullptr, nullptr, 0, hdr);
    k_tr<<<t64, blk, 0, stream>>>(w2, 64, 1024, wT, hdr);
    k_mf64<<<gm64, blk, 0, stream>>>(tmpw, 64, nullptr, wT, dcy, 1024, 64, 4, w_b, nullptr, 0, hdr);
    k_tr<<<t1024, blk, 0, stream>>>(W_k, 1024, 1024, wT, hdr);
    k_mf64<<<gm64, blk, 0, stream>>>(hs, 1024, x_k, wT, k_bf, 1024, 1024, 1, nullptr, nullptr, 0, hdr);
    k_tr<<<t1024, blk, 0, stream>>>(W_v, 1024, 1024, wT, hdr);
    k_mf64<<<gm64, blk, 0, stream>>>(hs, 1024, x_v, wT, v_bf, 1024, 1024, 1, nullptr, nullptr, 0, hdr);
    k_tr<<<tl64, blk, 0, stream>>>(a1, 1024, 64, wT, hdr);
    k_mf64<<<dim3(1, 64), blk, 0, stream>>>(hs, 1024, x_a, wT, tmpa, 64, 1024, 1, nullptr, nullptr, 0, hdr);
    k_tr<<<t64, blk, 0, stream>>>(a2, 64, 1024, wT, hdr);
    k_mf64<<<gm64, blk, 0, stream>>>(tmpa, 64, nullptr, wT, a_buf, 1024, 64, 5, a_b, nullptr, 0, hdr);
    k_tr<<<tl128, blk, 0, stream>>>(g1, 1024, 128, wT, hdr);
    k_mf64<<<dim3(2, 64), blk, 0, stream>>>(hs, 1024, x_g, wT, tmpg, 128, 1024, 3, nullptr, nullptr, 0, hdr);
    k_tr<<<t128, blk, 0, stream>>>(g2, 128, 1024, wT, hdr);
    k_mf64<<<gm64, blk, 0, stream>>>(tmpg, 128, nullptr, wT, g_buf, 1024, 128, 1, nullptr, nullptr, 0, hdr);

    k_prep<<<16384, blk, 0, stream>>>(k_bf, a_buf, k_k, k_a, av_bf, bv_bf, hdr);
    k_rec<<<256, blk, 0, stream>>>(r_bf, dcy, k_bf, v_bf, av_bf, bv_bf, o_buf);
    k_post<<<16384, blk, 0, stream>>>(o_buf, r_bf, k_bf, v_bf, g_buf, r_k, gn_w, gn_b, ao_in, hdr);

    // output projection + residual -> hid2 (bf16)
    k_tr<<<t1024, blk, 0, stream>>>(W_o, 1024, 1024, wT, hdr);
    k_mf64<<<gm64, blk, 0, stream>>>(ao_in, 1024, nullptr, wT, hid2, 1024, 1024, 8, nullptr, resid1, 1024, hdr);

    // FFN; final GEMM writes FLOAT32 output
    k_ln_bf<<<4096, blk, 0, stream>>>(hid2, ffn_w, ffn_b, hs2, hdr);
    k_tr<<<tKey, blk, 0, stream>>>(WkeyP, 1024, 4096, wT, hdr);
    k_mf<<<g4096, blk, 0, stream>>>(hs2, 1024, ffn_xk, wT, ffh, 4096, 1024, 7, nullptr, nullptr, 0, hdr);
    k_tr<<<tVal, blk, 0, stream>>>(WvalP, 4096, 1024, wT, hdr);
    k_mf64<<<gm64, blk, 0, stream>>>(ffh, 4096, nullptr, wT, (float*)d_out, 1024, 4096, 6, nullptr, hid2, 1024, hdr);
}

// Round 14
// 1202.783 us; speedup vs baseline: 2.0687x; 1.0383x over previous
//
#include <hip/hip_runtime.h>
#include <hip/hip_bf16.h>
#include <cstdint>

typedef unsigned short u16;
typedef unsigned short us8 __attribute__((ext_vector_type(8)));
typedef __bf16 bf16x8 __attribute__((ext_vector_type(8)));
typedef float f32x4 __attribute__((ext_vector_type(4)));
typedef uint32_t u32x2 __attribute__((ext_vector_type(2)));
typedef uint32_t u32x4v __attribute__((ext_vector_type(4)));

// ---------- helpers ----------
__device__ __forceinline__ float b2f(u16 u) {
    union { float f; uint32_t i; } x; x.i = ((uint32_t)u) << 16; return x.f;
}
__device__ __forceinline__ u16 f2b(float f) {
    uint32_t u = __float_as_uint(f);
    uint32_t r = (u + 0x7FFFu + ((u >> 16) & 1u)) >> 16;
    return (u16)r;
}
__device__ __forceinline__ float sigm(float x) { return 1.0f / (1.0f + __expf(-x)); }
__device__ __forceinline__ float ldv(const void* p, size_t i, int dt) {
    return dt ? b2f(((const u16*)p)[i]) : ((const float*)p)[i];
}

__device__ __forceinline__ float wave_sum(float v) {
#pragma unroll
    for (int o = 32; o > 0; o >>= 1) v += __shfl_xor(v, o, 64);
    return v;
}
__device__ __forceinline__ void block_reduce2(float& a, float& b, float* sm) {
    int tid = threadIdx.x, wid = tid >> 6, lane = tid & 63;
    float as = wave_sum(a), bs = wave_sum(b);
    __syncthreads();
    if (lane == 0) { sm[wid] = as; sm[8 + wid] = bs; }
    __syncthreads();
    a = sm[0] + sm[1] + sm[2] + sm[3];
    b = sm[8] + sm[9] + sm[10] + sm[11];
}

// 64-lane sum via DPP ladder; full sum lands in lane 63.
__device__ __forceinline__ float dpp_sum64(float x) {
    x += __int_as_float(__builtin_amdgcn_update_dpp(0, __float_as_int(x), 0x111, 0xf, 0xf, true)); // row_shr:1
    x += __int_as_float(__builtin_amdgcn_update_dpp(0, __float_as_int(x), 0x112, 0xf, 0xf, true)); // row_shr:2
    x += __int_as_float(__builtin_amdgcn_update_dpp(0, __float_as_int(x), 0x114, 0xf, 0xf, true)); // row_shr:4
    x += __int_as_float(__builtin_amdgcn_update_dpp(0, __float_as_int(x), 0x118, 0xf, 0xf, true)); // row_shr:8
    x += __int_as_float(__builtin_amdgcn_update_dpp(0, __float_as_int(x), 0x142, 0xa, 0xf, true)); // row_bcast:15
    x += __int_as_float(__builtin_amdgcn_update_dpp(0, __float_as_int(x), 0x143, 0xc, 0xf, true)); // row_bcast:31
    return x;
}

// 4 independent 64-lane sums, rounds interleaved so each chain's DPP latency
// is hidden by the other three (in-order wave: program order = issue order).
#define DPP1(x, ctrl, rm, bm) \
    x += __int_as_float(__builtin_amdgcn_update_dpp(0, __float_as_int(x), ctrl, rm, bm, true));
__device__ __forceinline__ void dpp_sum64_x4(float& a, float& b, float& c, float& d) {
#define RND(ctrl, rm, bm) \
    DPP1(a, ctrl, rm, bm) DPP1(b, ctrl, rm, bm) DPP1(c, ctrl, rm, bm) DPP1(d, ctrl, rm, bm)
    RND(0x111, 0xf, 0xf)   // row_shr:1
    RND(0x112, 0xf, 0xf)   // row_shr:2
    RND(0x114, 0xf, 0xf)   // row_shr:4
    RND(0x118, 0xf, 0xf)   // row_shr:8
    RND(0x142, 0xa, 0xf)   // row_bcast:15
    RND(0x143, 0xc, 0xf)   // row_bcast:31
#undef RND
}

// ---------- probe: dtype (hdr[0]) + which big array is x (hdr[1]) ----------
__global__ void k_probe(const u16* __restrict__ a0, const u16* __restrict__ a1,
                        const u16* __restrict__ a2, int* __restrict__ hdr) {
    __shared__ int wcnt;
    __shared__ float part[256];
    __shared__ float mag[3];
    int tid = threadIdx.x;
    if (tid == 0) wcnt = 0;
    __syncthreads();
    const u16* arr[3] = { a0, a1, a2 };
    int wild = 0;
    for (int s = 0; s < 3; ++s)
        for (int i = tid; i < 4096; i += 256) {
            u16 u = arr[s][i];
            int e = (u >> 7) & 0xFF;
            float av = fabsf(b2f(u));
            if (e == 0xFF || av > 100.f) wild++;
        }
    atomicAdd(&wcnt, wild);
    __syncthreads();
    int dt = (wcnt < 96) ? 1 : 0;
    for (int s = 0; s < 3; ++s) {
        float m = 0.f;
        if (dt) { for (int i = tid; i < 4096; i += 256) m += fabsf(b2f(arr[s][i])); }
        else    { const float* f = (const float*)arr[s];
                  for (int i = tid; i < 2048; i += 256) m += fabsf(f[i]); }
        part[tid] = m; __syncthreads();
        if (tid == 0) { float t = 0; for (int i = 0; i < 256; ++i) t += part[i]; mag[s] = t; }
        __syncthreads();
    }
    if (tid == 0) {
        int xs = 0;
        if (mag[1] > mag[xs]) xs = 1;
        if (mag[2] > mag[xs]) xs = 2;   // x ~N(0,1) vs 0.02-scale weights
        hdr[0] = dt; hdr[1] = xs;
    }
}

// ---------- double layernorm: x -> resid bf16, hs bf16 ----------
__global__ __launch_bounds__(256) void k_ln_in(
    const void* __restrict__ xa, const void* __restrict__ xb, const void* __restrict__ xc,
    const void* __restrict__ pw, const void* __restrict__ pb,
    const void* __restrict__ aw, const void* __restrict__ ab,
    u16* __restrict__ resid, u16* __restrict__ hs, const int* __restrict__ hdr)
{
    __shared__ float sm[16];
    const int dt = hdr[0], xs = hdr[1];
    const void* x = (xs == 0) ? xa : (xs == 1 ? xb : xc);
    int tok = blockIdx.x, tid = threadIdx.x;
    int c = tid * 4;
    size_t off = (size_t)tok * 1024 + c;
    float v0, v1, v2, v3;
    if (dt) {
        ushort4 xv = *(const ushort4*)((const u16*)x + off);
        v0 = b2f(xv.x); v1 = b2f(xv.y); v2 = b2f(xv.z); v3 = b2f(xv.w);
    } else {
        float4 xv = *(const float4*)((const float*)x + off);
        v0 = xv.x; v1 = xv.y; v2 = xv.z; v3 = xv.w;
    }
    float s = v0 + v1 + v2 + v3;
    float q = v0*v0 + v1*v1 + v2*v2 + v3*v3;
    block_reduce2(s, q, sm);
    float mean = s * (1.f/1024.f);
    float var  = q * (1.f/1024.f) - mean*mean;
    float rs = rsqrtf(var + 1e-5f);
    float h0 = (v0-mean)*rs*ldv(pw,c+0,dt) + ldv(pb,c+0,dt);
    float h1 = (v1-mean)*rs*ldv(pw,c+1,dt) + ldv(pb,c+1,dt);
    float h2 = (v2-mean)*rs*ldv(pw,c+2,dt) + ldv(pb,c+2,dt);
    float h3 = (v3-mean)*rs*ldv(pw,c+3,dt) + ldv(pb,c+3,dt);
    ushort4 rv; rv.x = f2b(h0); rv.y = f2b(h1); rv.z = f2b(h2); rv.w = f2b(h3);
    *(ushort4*)(resid + off) = rv;
    float s2 = h0 + h1 + h2 + h3;
    float q2 = h0*h0 + h1*h1 + h2*h2 + h3*h3;
    block_reduce2(s2, q2, sm);
    float m2 = s2 * (1.f/1024.f);
    float vr2 = q2 * (1.f/1024.f) - m2*m2;
    float rs2 = rsqrtf(vr2 + 1e-5f);
    ushort4 o;
    o.x = f2b((h0-m2)*rs2*ldv(aw,c+0,dt) + ldv(ab,c+0,dt));
    o.y = f2b((h1-m2)*rs2*ldv(aw,c+1,dt) + ldv(ab,c+1,dt));
    o.z = f2b((h2-m2)*rs2*ldv(aw,c+2,dt) + ldv(ab,c+2,dt));
    o.w = f2b((h3-m2)*rs2*ldv(aw,c+3,dt) + ldv(ab,c+3,dt));
    *(ushort4*)(hs + off) = o;
}

// ---------- layernorm bf16(ws) -> bf16 ----------
__global__ __launch_bounds__(256) void k_ln_bf(
    const u16* __restrict__ in, const void* __restrict__ w, const void* __restrict__ b,
    u16* __restrict__ out, const int* __restrict__ hdr)
{
    __shared__ float sm[16];
    const int dt = hdr[0];
    int tok = blockIdx.x, tid = threadIdx.x;
    int c = tid * 4;
    size_t off = (size_t)tok * 1024 + c;
    ushort4 xv = *(const ushort4*)(in + off);
    float v0 = b2f(xv.x), v1 = b2f(xv.y), v2 = b2f(xv.z), v3 = b2f(xv.w);
    float s = v0 + v1 + v2 + v3;
    float q = v0*v0 + v1*v1 + v2*v2 + v3*v3;
    block_reduce2(s, q, sm);
    float mean = s * (1.f/1024.f);
    float var  = q * (1.f/1024.f) - mean*mean;
    float rs = rsqrtf(var + 1e-5f);
    ushort4 o;
    o.x = f2b((v0-mean)*rs*ldv(w,c+0,dt) + ldv(b,c+0,dt));
    o.y = f2b((v1-mean)*rs*ldv(w,c+1,dt) + ldv(b,c+1,dt));
    o.z = f2b((v2-mean)*rs*ldv(w,c+2,dt) + ldv(b,c+2,dt));
    o.w = f2b((v3-mean)*rs*ldv(w,c+3,dt) + ldv(b,c+3,dt));
    *(ushort4*)(out + off) = o;
}

// ---------- weight transpose: W[K][N] (f32|bf16) -> WT[N][K] bf16 ----------
__global__ __launch_bounds__(256) void k_tr(
    const void* __restrict__ W, int K, int N, u16* __restrict__ WT,
    const int* __restrict__ hdr)
{
    const int dt = hdr[0];
    __shared__ u16 t[32][33];
    int n0 = blockIdx.x * 32, k0 = blockIdx.y * 32;
    int tx = threadIdx.x & 31, ty = threadIdx.x >> 5;   // 32 x 8
#pragma unroll
    for (int r = 0; r < 32; r += 8) {
        int k = k0 + ty + r;
        t[ty + r][tx] = f2b(ldv(W, (size_t)k * N + n0 + tx, dt));  // f2b(b2f(u))==u
    }
    __syncthreads();
#pragma unroll
    for (int r = 0; r < 32; r += 8) {
        int n = n0 + ty + r;
        WT[(size_t)n * K + k0 + tx] = t[tx][ty + r];
    }
}

// ---------- shared epilogue for MFMA GEMMs ----------
// modes: 1=raw 2=tanh 3=sigm 4=exp(-0.6065*sigm(v+bias)) 5=sigm(v+bias)
//        6=F32 OUT v+add 7=relu^2 8=bf16 v+add
__device__ __forceinline__ void mf_epi(
    void* D, int ldd, int mode, const void* bias,
    const u16* add, int ldadd, int dt,
    int row, int col, float v)
{
    size_t di = (size_t)row * ldd + col;
    if (mode == 6) {
        ((float*)D)[di] = v + b2f(add[(size_t)row * ldadd + col]);
        return;
    }
    float rr;
    switch (mode) {
        default: rr = v; break;
        case 2: rr = tanhf(v); break;
        case 3: rr = sigm(v); break;
        case 4: rr = __expf(-0.6065306597126334f * sigm(v + ldv(bias, col, dt))); break;
        case 5: rr = sigm(v + ldv(bias, col, dt)); break;
        case 7: { float t = fmaxf(v, 0.f); rr = t * t; } break;
        case 8: rr = v + b2f(add[(size_t)row * ldadd + col]); break;
    }
    ((u16*)D)[di] = f2b(rr);
}

// ---------- MFMA GEMM: 128x128 tile (for N=4096 outputs) ----------
__global__ __launch_bounds__(256, 2) void k_mf(
    const u16* __restrict__ A, int lda, const void* __restrict__ mixc,
    const u16* __restrict__ BT,
    void* __restrict__ D, int ldd,
    int K, int mode,
    const void* __restrict__ bias,
    const u16* __restrict__ add, int ldadd, const int* __restrict__ hdr)
{
    __shared__ u16 As[128 * 40];     // 10240 B
    __shared__ u16 Bs[128 * 40];     // 10240 B
    const int dt = hdr[0];
    const int tid = threadIdx.x;
    const int m0 = blockIdx.y * 128, n0 = blockIdx.x * 128;
    const int wid = tid >> 6, lane = tid & 63;
    const int wr = wid >> 1, wc = wid & 1;
    const int lg = lane >> 4, lc = lane & 15;
    const int srow = tid >> 1, shalf = tid & 1;   // staging: 128 rows x 2 k-halves

    f32x4 acc[4][4];
#pragma unroll
    for (int i = 0; i < 4; ++i)
#pragma unroll
        for (int j = 0; j < 4; ++j) acc[i][j] = (f32x4)0.f;

    for (int kb = 0; kb < K; kb += 32) {
        {
            int gr = m0 + srow;
            const u16* ap = A + (size_t)gr * lda + kb + 16 * shalf;
            us8 c1 = *(const us8*)ap;
            us8 c2 = *(const us8*)(ap + 8);
            if (mixc) {
                const u16* pp = ap - ((gr & 2047) ? lda : 0);
                float pz = (gr & 2047) ? 1.f : 0.f;
                us8 p1 = *(const us8*)pp;
                us8 p2 = *(const us8*)(pp + 8);
                int kbase = kb + 16 * shalf;
#pragma unroll
                for (int e = 0; e < 8; ++e) {
                    float cu1 = b2f(c1[e]), cu2 = b2f(c2[e]);
                    c1[e] = f2b(cu1 + (pz * b2f(p1[e]) - cu1) * ldv(mixc, kbase + e, dt));
                    c2[e] = f2b(cu2 + (pz * b2f(p2[e]) - cu2) * ldv(mixc, kbase + 8 + e, dt));
                }
            }
            u16* dst = As + srow * 40 + 16 * shalf;
            *(us8*)dst = c1;
            *(us8*)(dst + 8) = c2;
        }
        {
            const u16* bp = BT + (size_t)(n0 + srow) * K + kb + 16 * shalf;
            u16* dst = Bs + srow * 40 + 16 * shalf;
            *(us8*)dst = *(const us8*)bp;
            *(us8*)(dst + 8) = *(const us8*)(bp + 8);
        }
        __syncthreads();
        bf16x8 af[4], bf[4];
#pragma unroll
        for (int fm = 0; fm < 4; ++fm) {
            const u16* p = As + (wr * 64 + fm * 16 + lc) * 40 + lg * 8;
            union { us8 s; bf16x8 v; } u;
            u.s = *(const us8*)p;
            af[fm] = u.v;
        }
#pragma unroll
        for (int fc = 0; fc < 4; ++fc) {
            const u16* p = Bs + (wc * 64 + fc * 16 + lc) * 40 + lg * 8;
            union { us8 s; bf16x8 v; } u;
            u.s = *(const us8*)p;
            bf[fc] = u.v;
        }
#pragma unroll
        for (int fm = 0; fm < 4; ++fm)
#pragma unroll
            for (int fc = 0; fc < 4; ++fc)
                acc[fm][fc] = __builtin_amdgcn_mfma_f32_16x16x32_bf16(
                    af[fm], bf[fc], acc[fm][fc], 0, 0, 0);
        __syncthreads();
    }

#pragma unroll
    for (int fm = 0; fm < 4; ++fm)
#pragma unroll
        for (int fc = 0; fc < 4; ++fc)
#pragma unroll
            for (int r = 0; r < 4; ++r)
                mf_epi(D, ldd, mode, bias, add, ldadd, dt,
                       m0 + wr * 64 + fm * 16 + lg * 4 + r,
                       n0 + wc * 64 + fc * 16 + lc, acc[fm][fc][r]);
}

// ---------- MFMA GEMM: 64x64 tile (for N<=1024 outputs) ----------
__global__ __launch_bounds__(256, 4) void k_mf64(
    const u16* __restrict__ A, int lda, const void* __restrict__ mixc,
    const u16* __restrict__ BT,
    void* __restrict__ D, int ldd,
    int K, int mode,
    const void* __restrict__ bias,
    const u16* __restrict__ add, int ldadd, const int* __restrict__ hdr)
{
    __shared__ u16 As[64 * 40];      // 5120 B
    __shared__ u16 Bs[64 * 40];      // 5120 B
    const int dt = hdr[0];
    const int tid = threadIdx.x;
    const int m0 = blockIdx.y * 64, n0 = blockIdx.x * 64;
    const int wid = tid >> 6, lane = tid & 63;
    const int wr = wid >> 1, wc = wid & 1;
    const int lg = lane >> 4, lc = lane & 15;
    const int srow = tid >> 2, sq = tid & 3;      // staging: 64 rows x 4 k-quarters

    f32x4 acc[2][2];
#pragma unroll
    for (int i = 0; i < 2; ++i)
#pragma unroll
        for (int j = 0; j < 2; ++j) acc[i][j] = (f32x4)0.f;

    for (int kb = 0; kb < K; kb += 32) {
        {
            int gr = m0 + srow;
            const u16* ap = A + (size_t)gr * lda + kb + 8 * sq;
            us8 c1 = *(const us8*)ap;
            if (mixc) {
                const u16* pp = ap - ((gr & 2047) ? lda : 0);
                float pz = (gr & 2047) ? 1.f : 0.f;
                us8 p1 = *(const us8*)pp;
                int kbase = kb + 8 * sq;
#pragma unroll
                for (int e = 0; e < 8; ++e) {
                    float cu = b2f(c1[e]);
                    c1[e] = f2b(cu + (pz * b2f(p1[e]) - cu) * ldv(mixc, kbase + e, dt));
                }
            }
            *(us8*)(As + srow * 40 + 8 * sq) = c1;
        }
        {
            const u16* bp = BT + (size_t)(n0 + srow) * K + kb + 8 * sq;
            *(us8*)(Bs + srow * 40 + 8 * sq) = *(const us8*)bp;
        }
        __syncthreads();
        bf16x8 af[2], bf[2];
#pragma unroll
        for (int fm = 0; fm < 2; ++fm) {
            const u16* p = As + (wr * 32 + fm * 16 + lc) * 40 + lg * 8;
            union { us8 s; bf16x8 v; } u;
            u.s = *(const us8*)p;
            af[fm] = u.v;
        }
#pragma unroll
        for (int fc = 0; fc < 2; ++fc) {
            const u16* p = Bs + (wc * 32 + fc * 16 + lc) * 40 + lg * 8;
            union { us8 s; bf16x8 v; } u;
            u.s = *(const us8*)p;
            bf[fc] = u.v;
        }
#pragma unroll
        for (int fm = 0; fm < 2; ++fm)
#pragma unroll
            for (int fc = 0; fc < 2; ++fc)
                acc[fm][fc] = __builtin_amdgcn_mfma_f32_16x16x32_bf16(
                    af[fm], bf[fc], acc[fm][fc], 0, 0, 0);
        __syncthreads();
    }

#pragma unroll
    for (int fm = 0; fm < 2; ++fm)
#pragma unroll
        for (int fc = 0; fc < 2; ++fc)
#pragma unroll
            for (int r = 0; r < 4; ++r)
                mf_epi(D, ldd, mode, bias, add, ldadd, dt,
                       m0 + wr * 32 + fm * 16 + lg * 4 + r,
                       n0 + wc * 32 + fc * 16 + lc, acc[fm][fc][r]);
}

// ---------- per-head prep ----------
__global__ __launch_bounds__(256) void k_prep(
    u16* __restrict__ k_bf, const u16* __restrict__ a_buf,
    const void* __restrict__ k_k, const void* __restrict__ k_a,
    u16* __restrict__ av, u16* __restrict__ bv, const int* __restrict__ hdr)
{
    const int dt = hdr[0];
    int ht = blockIdx.x * 4 + (threadIdx.x >> 6);
    int j = threadIdx.x & 63;
    int tok = ht >> 4, h = ht & 15, n = h * 64 + j;
    size_t idx = (size_t)tok * 1024 + n;
    float kv = b2f(k_bf[idx]);
    float a  = b2f(a_buf[idx]);
    float kk = kv * ldv(k_k, n, dt);
    float ss = wave_sum(kk * kk);
    float den = fmaxf(sqrtf(ss), 1e-12f);
    float kkn = kk / den;
    k_bf[idx] = f2b(kv * (1.f + (a - 1.f) * ldv(k_a, n, dt)));
    av[idx] = f2b(-kkn);
    bv[idx] = f2b(kkn * a);
}

// ---------- recurrence v9: v8 + cross-step ladder pipelining ----------
// R13 falsifier fired: reads are fast, the wall is the serial DPP chains under
// IN-ORDER wave issue — the o-ladder's latency (data-independent of next step)
// still blocks the next sa-ladder in program order. v9 carries pv = r*S from
// the previous step and runs {sa0, sa1, prev-o0, prev-o1} through ONE 4-way
// interleaved ladder: each chain's DPP latency is hidden by the other three.
// o-store lags one step (flush after loop). Per-value ladder math unchanged
// -> bit-identical output.
#define KREC_LOADS(T0)                                                          \
    {                                                                           \
        _Pragma("unroll")                                                       \
        for (int it = 0; it < 10; ++it) {                                       \
            const u16* sp = (it < 2) ? r_bf : (it < 4) ? dcy                    \
                          : (it < 6) ? km  : (it < 8) ? av : bv;                \
            int i = ((it & 1) << 8) + tid;                                      \
            int step = i >> 5, dp = i & 31;                                     \
            stg[it] = *(const uint32_t*)(sp +                                   \
                (size_t)(tbase + (T0) + step) * 1024 + h * 64 + dp * 2);        \
        }                                                                       \
        if (tid < 64)                                                           \
            stg[10] = v32[(size_t)(tbase + (T0) + (tid >> 2)) * 512             \
                          + h * 32 + jj0 + (tid & 3)];                          \
    }
#define KREC_WRITES(DST)                                                        \
    {                                                                           \
        u16* b_ = (u16*)&lds[DST][0];                                           \
        _Pragma("unroll")                                                       \
        for (int it = 0; it < 10; ++it) {                                       \
            int s = it >> 1;                                                    \
            int i = ((it & 1) << 8) + tid;                                      \
            int step = i >> 5, dp = i & 31;                                     \
            b_[s * 1280 + (2 * dp) * 20 + step]     = (u16)(stg[it] & 0xFFFFu); \
            b_[s * 1280 + (2 * dp + 1) * 20 + step] = (u16)(stg[it] >> 16);     \
        }                                                                       \
        if (tid < 64) lds[DST][3200 + (tid & 3) * 16 + (tid >> 2)] = stg[10];   \
    }
__device__ __forceinline__ float bfsel(uint32_t u, int hi) {
    return hi ? __uint_as_float(u & 0xFFFF0000u) : __uint_as_float(u << 16);
}
__global__ __launch_bounds__(256) void k_rec(
    const u16* __restrict__ r_bf, const u16* __restrict__ dcy,
    const u16* __restrict__ km, const u16* __restrict__ v_bf,
    const u16* __restrict__ av, const u16* __restrict__ bv,
    u16* __restrict__ o_buf)
{
    const int T = 2048;
    const int tid = threadIdx.x;
    int rq = blockIdx.x & 7, q = blockIdx.x >> 3;
    int wid = tid >> 6, lane = tid & 63;
    int bh = rq * 4 + (q >> 3);          // 0..31; 8 blocks of a bh share an XCD
    int jj0 = (q & 7) * 4;               // block's column-pair base
    int jj = jj0 + wid;                  // this wave's pair -> cols 2jj, 2jj+1
    int b = bh >> 4, h = bh & 15;
    int tbase = b * T;
    const uint32_t* v32 = (const uint32_t*)v_bf;
    uint32_t* o32 = (uint32_t*)o_buf;
    size_t oidx = (size_t)tbase * 512 + h * 32 + jj;   // store for step t-1 at step t

    __shared__ uint32_t lds[2][3264];
    uint32_t stg[11];

    // prologue: stage chunk 0
    KREC_LOADS(0)
    KREC_WRITES(0)
    __syncthreads();

    float S0 = 0.f, S1 = 0.f;
    float pv0 = 0.f, pv1 = 0.f;          // r*S of previous step (o pipeline)
    for (int c = 0; c < 128; ++c) {
        int cur = c & 1;
        bool more = (c + 1) < 128;
        if (more) KREC_LOADS((c + 1) * 16)          // issue early; hidden by compute
        const char* lbb = (const char*)&lds[cur][0];
        u32x2 rA[4], dA[4], kA[4], aA[4], bA[4];
        u32x4v vA[4];
#pragma unroll
        for (int qq = 0; qq < 4; ++qq) {
            rA[qq] = *(const u32x2*)(lbb + 0 * 2560 + lane * 40 + qq * 8);
            dA[qq] = *(const u32x2*)(lbb + 1 * 2560 + lane * 40 + qq * 8);
            kA[qq] = *(const u32x2*)(lbb + 2 * 2560 + lane * 40 + qq * 8);
            aA[qq] = *(const u32x2*)(lbb + 3 * 2560 + lane * 40 + qq * 8);
            bA[qq] = *(const u32x2*)(lbb + 4 * 2560 + lane * 40 + qq * 8);
            vA[qq] = *(const u32x4v*)(lbb + 12800 + wid * 64 + qq * 16);
        }
#pragma unroll
        for (int step = 0; step < 16; ++step) {
            const int qq = step >> 2, ee = (step >> 1) & 1, hi = step & 1;
            float rf  = bfsel(rA[qq][ee], hi);
            float df  = bfsel(dA[qq][ee], hi);
            float kf  = bfsel(kA[qq][ee], hi);
            float af  = bfsel(aA[qq][ee], hi);
            float bf_ = bfsel(bA[qq][ee], hi);
            uint32_t vv = vA[qq][step & 3];
            float vf0 = __uint_as_float(vv << 16);
            float vf1 = __uint_as_float(vv & 0xFFFF0000u);
            float m0 = af * S0, m1 = af * S1;
            float q0 = pv0, q1 = pv1;
            dpp_sum64_x4(m0, m1, q0, q1);   // sa(t) + o(t-1), latency-overlapped
            float sa0 = __int_as_float(__builtin_amdgcn_readlane(__float_as_int(m0), 63));
            float sa1 = __int_as_float(__builtin_amdgcn_readlane(__float_as_int(m1), 63));
            if (step > 0 || c > 0) {         // store o(t-1); skip very first step
                if (lane == 63)
                    o32[oidx] = (uint32_t)f2b(q0) | ((uint32_t)f2b(q1) << 16);
                oidx += 512;
            }
            float X0 = fmaf(kf, vf0, S0 * df);
            float X1 = fmaf(kf, vf1, S1 * df);
            S0 = fmaf(bf_, sa0, X0);
            S1 = fmaf(bf_, sa1, X1);
            pv0 = rf * S0;
            pv1 = rf * S1;
        }
        if (more) KREC_WRITES(cur ^ 1)
        __syncthreads();
    }
    // flush o for the final step (t = T-1)
    {
        float q0 = pv0, q1 = pv1, z0 = 0.f, z1 = 0.f;
        dpp_sum64_x4(q0, q1, z0, z1);
        if (lane == 63)
            o32[oidx] = (uint32_t)f2b(q0) | ((uint32_t)f2b(q1) << 16);
    }
}

// ---------- groupnorm + bonus + gate ----------
__global__ __launch_bounds__(256) void k_post(
    const u16* __restrict__ o_buf, const u16* __restrict__ r_bf,
    const u16* __restrict__ km, const u16* __restrict__ v_bf,
    const u16* __restrict__ g_buf, const void* __restrict__ r_k,
    const void* __restrict__ gnw, const void* __restrict__ gnb,
    u16* __restrict__ ao, const int* __restrict__ hdr)
{
    const int dt = hdr[0];
    int ht = blockIdx.x * 4 + (threadIdx.x >> 6);
    int j = threadIdx.x & 63;
    int tok = ht >> 4, h = ht & 15, n = h * 64 + j;
    size_t idx = (size_t)tok * 1024 + n;
    float o = b2f(o_buf[idx]);
    float mu = wave_sum(o) * (1.f/64.f);
    float d = o - mu;
    float var = wave_sum(d * d) * (1.f/64.f);
    float og = d * rsqrtf(var + 6.4e-4f) * ldv(gnw, n, dt) + ldv(gnb, n, dt);
    float r = b2f(r_bf[idx]), kmv = b2f(km[idx]), v = b2f(v_bf[idx]);
    float bonus = wave_sum(r * kmv * ldv(r_k, n, dt));
    float val = (og + bonus * v) * b2f(g_buf[idx]);
    ao[idx] = f2b(val);
}

// ---------- host ----------
extern "C" void kernel_launch(void* const* d_in, const int* in_sizes, int n_in,
                              void* d_out, int out_size, void* d_ws, size_t ws_size,
                              hipStream_t stream) {
    (void)in_sizes; (void)n_in; (void)out_size; (void)ws_size;
    const void* xP     = d_in[0];
    const void* pre_w  = d_in[1];
    const void* pre_b  = d_in[2];
    const void* attn_w = d_in[3];
    const void* attn_b = d_in[4];
    const void* ffn_w  = d_in[5];
    const void* ffn_b  = d_in[6];
    const void* x_r    = d_in[7];
    const void* x_w    = d_in[8];
    const void* x_k    = d_in[9];
    const void* x_v    = d_in[10];
    const void* x_a    = d_in[11];
    const void* x_g    = d_in[12];
    const void* W_r    = d_in[13];
    const void* W_k    = d_in[14];
    const void* W_v    = d_in[15];
    const void* W_o    = d_in[16];
    const void* w1     = d_in[17];
    const void* w2     = d_in[18];
    const void* w_b    = d_in[19];
    const void* a1     = d_in[20];
    const void* a2     = d_in[21];
    const void* a_b    = d_in[22];
    const void* g1     = d_in[23];
    const void* g2     = d_in[24];
    const void* k_k    = d_in[25];
    const void* k_a    = d_in[26];
    const void* r_k    = d_in[27];
    const void* gn_w   = d_in[28];
    const void* gn_b   = d_in[29];
    const void* ffn_xk = d_in[30];
    const void* WkeyP  = d_in[31];
    const void* WvalP  = d_in[32];

    char* ws = (char*)d_ws;
    const size_t SL = 8388608ull;          // [4096][1024] bf16 slab
    int* hdr    = (int*)(ws + 0);
    u16* hs     = (u16*)(ws + 4096 + SL*0);
    u16* resid1 = (u16*)(ws + 4096 + SL*1);
    u16* dcy    = (u16*)(ws + 4096 + SL*2);
    u16* r_bf   = (u16*)(ws + 4096 + SL*3);
    u16* k_bf   = (u16*)(ws + 4096 + SL*4);
    u16* v_bf   = (u16*)(ws + 4096 + SL*5);
    u16* av_bf  = (u16*)(ws + 4096 + SL*6);
    u16* bv_bf  = (u16*)(ws + 4096 + SL*7);
    u16* a_buf  = (u16*)(ws + 4096 + SL*8);
    u16* g_buf  = (u16*)(ws + 4096 + SL*9);
    u16* tmpw   = (u16*)(ws + 4096 + SL*10);
    u16* tmpa   = (u16*)(ws + 4096 + SL*10 + 524288);
    u16* tmpg   = (u16*)(ws + 4096 + SL*10 + 1048576);
    u16* wT     = (u16*)(ws + 4096 + SL*10 + 2097152);   // 8MB transpose scratch; peak ~90MB
    // overlays (later lifetimes)
    u16* o_buf  = a_buf;                   // a dead after k_prep
    u16* ao_in  = bv_bf;                   // bv dead after k_rec
    u16* hid2   = dcy;                     // dcy dead after k_rec
    u16* hs2    = hs;                      // hs dead after projections
    u16* ffh    = r_bf;                    // [4096,4096] bf16 over r,k,v,av (dead after k_post)

    dim3 blk(256);
    dim3 gm64(16, 64);                     // 64x64-tile grid for N=1024
    dim3 g4096(32, 32);
    dim3 t1024(32, 32), tKey(128, 32), tVal(32, 128), t64(32, 2), t128(32, 4);
    dim3 tl64(2, 32), tl128(4, 32);        // lora up-weight transposes
    k_probe<<<1, blk, 0, stream>>>((const u16*)xP, (const u16*)WkeyP, (const u16*)WvalP, hdr);
    k_ln_in<<<4096, blk, 0, stream>>>(xP, WkeyP, WvalP, pre_w, pre_b, attn_w, attn_b, resid1, hs, hdr);

    // attn projections (fused token-shift mix) -- all MFMA
    k_tr<<<t1024, blk, 0, stream>>>(W_r, 1024, 1024, wT, hdr);
    k_mf64<<<gm64, blk, 0, stream>>>(hs, 1024, x_r, wT, r_bf, 1024, 1024, 1, nullptr, nullptr, 0, hdr);
    k_tr<<<tl64, blk, 0, stream>>>(w1, 1024, 64, wT, hdr);
    k_mf64<<<dim3(1, 64), blk, 0, stream>>>(hs, 1024, x_w, wT, tmpw, 64, 1024, 2, nullptr, nullptr, 0, hdr);
    k_tr<<<t64, blk, 0, stream>>>(w2, 64, 1024, wT, hdr);
    k_mf64<<<gm64, blk, 0, stream>>>(tmpw, 64, nullptr, wT, dcy, 1024, 64, 4, w_b, nullptr, 0, hdr);
    k_tr<<<t1024, blk, 0, stream>>>(W_k, 1024, 1024, wT, hdr);
    k_mf64<<<gm64, blk, 0, stream>>>(hs, 1024, x_k, wT, k_bf, 1024, 1024, 1, nullptr, nullptr, 0, hdr);
    k_tr<<<t1024, blk, 0, stream>>>(W_v, 1024, 1024, wT, hdr);
    k_mf64<<<gm64, blk, 0, stream>>>(hs, 1024, x_v, wT, v_bf, 1024, 1024, 1, nullptr, nullptr, 0, hdr);
    k_tr<<<tl64, blk, 0, stream>>>(a1, 1024, 64, wT, hdr);
    k_mf64<<<dim3(1, 64), blk, 0, stream>>>(hs, 1024, x_a, wT, tmpa, 64, 1024, 1, nullptr, nullptr, 0, hdr);
    k_tr<<<t64, blk, 0, stream>>>(a2, 64, 1024, wT, hdr);
    k_mf64<<<gm64, blk, 0, stream>>>(tmpa, 64, nullptr, wT, a_buf, 1024, 64, 5, a_b, nullptr, 0, hdr);
    k_tr<<<tl128, blk, 0, stream>>>(g1, 1024, 128, wT, hdr);
    k_mf64<<<dim3(2, 64), blk, 0, stream>>>(hs, 1024, x_g, wT, tmpg, 128, 1024, 3, nullptr, nullptr, 0, hdr);
    k_tr<<<t128, blk, 0, stream>>>(g2, 128, 1024, wT, hdr);
    k_mf64<<<gm64, blk, 0, stream>>>(tmpg, 128, nullptr, wT, g_buf, 1024, 128, 1, nullptr, nullptr, 0, hdr);

    k_prep<<<16384, blk, 0, stream>>>(k_bf, a_buf, k_k, k_a, av_bf, bv_bf, hdr);
    k_rec<<<256, blk, 0, stream>>>(r_bf, dcy, k_bf, v_bf, av_bf, bv_bf, o_buf);
    k_post<<<16384, blk, 0, stream>>>(o_buf, r_bf, k_bf, v_bf, g_buf, r_k, gn_w, gn_b, ao_in, hdr);

    // output projection + residual -> hid2 (bf16)
    k_tr<<<t1024, blk, 0, stream>>>(W_o, 1024, 1024, wT, hdr);
    k_mf64<<<gm64, blk, 0, stream>>>(ao_in, 1024, nullptr, wT, hid2, 1024, 1024, 8, nullptr, resid1, 1024, hdr);

    // FFN; final GEMM writes FLOAT32 output
    k_ln_bf<<<4096, blk, 0, stream>>>(hid2, ffn_w, ffn_b, hs2, hdr);
    k_tr<<<tKey, blk, 0, stream>>>(WkeyP, 1024, 4096, wT, hdr);
    k_mf<<<g4096, blk, 0, stream>>>(hs2, 1024, ffn_xk, wT, ffh, 4096, 1024, 7, nullptr, nullptr, 0, hdr);
    k_tr<<<tVal, blk, 0, stream>>>(WvalP, 4096, 1024, wT, hdr);
    k_mf64<<<gm64, blk, 0, stream>>>(ffh, 4096, nullptr, wT, (float*)d_out, 1024, 4096, 6, nullptr, hid2, 1024, hdr);
}

// Round 16
// 1070.558 us; speedup vs baseline: 2.3242x; 1.1235x over previous
//
#include <hip/hip_runtime.h>
#include <hip/hip_bf16.h>
#include <cstdint>

typedef unsigned short u16;
typedef unsigned short us8 __attribute__((ext_vector_type(8)));
typedef __bf16 bf16x8 __attribute__((ext_vector_type(8)));
typedef float f32x4 __attribute__((ext_vector_type(4)));
typedef uint32_t u32x2 __attribute__((ext_vector_type(2)));
typedef uint32_t u32x4v __attribute__((ext_vector_type(4)));

// ---------- helpers ----------
__device__ __forceinline__ float b2f(u16 u) {
    union { float f; uint32_t i; } x; x.i = ((uint32_t)u) << 16; return x.f;
}
__device__ __forceinline__ u16 f2b(float f) {
    uint32_t u = __float_as_uint(f);
    uint32_t r = (u + 0x7FFFu + ((u >> 16) & 1u)) >> 16;
    return (u16)r;
}
__device__ __forceinline__ float sigm(float x) { return 1.0f / (1.0f + __expf(-x)); }
__device__ __forceinline__ float ldv(const void* p, size_t i, int dt) {
    return dt ? b2f(((const u16*)p)[i]) : ((const float*)p)[i];
}

__device__ __forceinline__ float wave_sum(float v) {
#pragma unroll
    for (int o = 32; o > 0; o >>= 1) v += __shfl_xor(v, o, 64);
    return v;
}
__device__ __forceinline__ void block_reduce2(float& a, float& b, float* sm) {
    int tid = threadIdx.x, wid = tid >> 6, lane = tid & 63;
    float as = wave_sum(a), bs = wave_sum(b);
    __syncthreads();
    if (lane == 0) { sm[wid] = as; sm[8 + wid] = bs; }
    __syncthreads();
    a = sm[0] + sm[1] + sm[2] + sm[3];
    b = sm[8] + sm[9] + sm[10] + sm[11];
}

// 4 independent 64-lane sums, rounds interleaved (in-order wave: hides DPP latency).
#define DPP1(x, ctrl, rm, bm) \
    x += __int_as_float(__builtin_amdgcn_update_dpp(0, __float_as_int(x), ctrl, rm, bm, true));
__device__ __forceinline__ void dpp_sum64_x4(float& a, float& b, float& c, float& d) {
#define RND(ctrl, rm, bm) \
    DPP1(a, ctrl, rm, bm) DPP1(b, ctrl, rm, bm) DPP1(c, ctrl, rm, bm) DPP1(d, ctrl, rm, bm)
    RND(0x111, 0xf, 0xf)   // row_shr:1
    RND(0x112, 0xf, 0xf)   // row_shr:2
    RND(0x114, 0xf, 0xf)   // row_shr:4
    RND(0x118, 0xf, 0xf)   // row_shr:8
    RND(0x142, 0xa, 0xf)   // row_bcast:15
    RND(0x143, 0xc, 0xf)   // row_bcast:31
#undef RND
}

// ---------- probe: dtype (hdr[0]) + which big array is x (hdr[1]) ----------
__global__ void k_probe(const u16* __restrict__ a0, const u16* __restrict__ a1,
                        const u16* __restrict__ a2, int* __restrict__ hdr) {
    __shared__ int wcnt;
    __shared__ float part[256];
    __shared__ float mag[3];
    int tid = threadIdx.x;
    if (tid == 0) wcnt = 0;
    __syncthreads();
    const u16* arr[3] = { a0, a1, a2 };
    int wild = 0;
    for (int s = 0; s < 3; ++s)
        for (int i = tid; i < 4096; i += 256) {
            u16 u = arr[s][i];
            int e = (u >> 7) & 0xFF;
            float av = fabsf(b2f(u));
            if (e == 0xFF || av > 100.f) wild++;
        }
    atomicAdd(&wcnt, wild);
    __syncthreads();
    int dt = (wcnt < 96) ? 1 : 0;
    for (int s = 0; s < 3; ++s) {
        float m = 0.f;
        if (dt) { for (int i = tid; i < 4096; i += 256) m += fabsf(b2f(arr[s][i])); }
        else    { const float* f = (const float*)arr[s];
                  for (int i = tid; i < 2048; i += 256) m += fabsf(f[i]); }
        part[tid] = m; __syncthreads();
        if (tid == 0) { float t = 0; for (int i = 0; i < 256; ++i) t += part[i]; mag[s] = t; }
        __syncthreads();
    }
    if (tid == 0) {
        int xs = 0;
        if (mag[1] > mag[xs]) xs = 1;
        if (mag[2] > mag[xs]) xs = 2;   // x ~N(0,1) vs 0.02-scale weights
        hdr[0] = dt; hdr[1] = xs;
    }
}

// ---------- double layernorm: x -> resid bf16, hs bf16 ----------
__global__ __launch_bounds__(256) void k_ln_in(
    const void* __restrict__ xa, const void* __restrict__ xb, const void* __restrict__ xc,
    const void* __restrict__ pw, const void* __restrict__ pb,
    const void* __restrict__ aw, const void* __restrict__ ab,
    u16* __restrict__ resid, u16* __restrict__ hs, const int* __restrict__ hdr)
{
    __shared__ float sm[16];
    const int dt = hdr[0], xs = hdr[1];
    const void* x = (xs == 0) ? xa : (xs == 1 ? xb : xc);
    int tok = blockIdx.x, tid = threadIdx.x;
    int c = tid * 4;
    size_t off = (size_t)tok * 1024 + c;
    float v0, v1, v2, v3;
    if (dt) {
        ushort4 xv = *(const ushort4*)((const u16*)x + off);
        v0 = b2f(xv.x); v1 = b2f(xv.y); v2 = b2f(xv.z); v3 = b2f(xv.w);
    } else {
        float4 xv = *(const float4*)((const float*)x + off);
        v0 = xv.x; v1 = xv.y; v2 = xv.z; v3 = xv.w;
    }
    float s = v0 + v1 + v2 + v3;
    float q = v0*v0 + v1*v1 + v2*v2 + v3*v3;
    block_reduce2(s, q, sm);
    float mean = s * (1.f/1024.f);
    float var  = q * (1.f/1024.f) - mean*mean;
    float rs = rsqrtf(var + 1e-5f);
    float h0 = (v0-mean)*rs*ldv(pw,c+0,dt) + ldv(pb,c+0,dt);
    float h1 = (v1-mean)*rs*ldv(pw,c+1,dt) + ldv(pb,c+1,dt);
    float h2 = (v2-mean)*rs*ldv(pw,c+2,dt) + ldv(pb,c+2,dt);
    float h3 = (v3-mean)*rs*ldv(pw,c+3,dt) + ldv(pb,c+3,dt);
    ushort4 rv; rv.x = f2b(h0); rv.y = f2b(h1); rv.z = f2b(h2); rv.w = f2b(h3);
    *(ushort4*)(resid + off) = rv;
    float s2 = h0 + h1 + h2 + h3;
    float q2 = h0*h0 + h1*h1 + h2*h2 + h3*h3;
    block_reduce2(s2, q2, sm);
    float m2 = s2 * (1.f/1024.f);
    float vr2 = q2 * (1.f/1024.f) - m2*m2;
    float rs2 = rsqrtf(vr2 + 1e-5f);
    ushort4 o;
    o.x = f2b((h0-m2)*rs2*ldv(aw,c+0,dt) + ldv(ab,c+0,dt));
    o.y = f2b((h1-m2)*rs2*ldv(aw,c+1,dt) + ldv(ab,c+1,dt));
    o.z = f2b((h2-m2)*rs2*ldv(aw,c+2,dt) + ldv(ab,c+2,dt));
    o.w = f2b((h3-m2)*rs2*ldv(aw,c+3,dt) + ldv(ab,c+3,dt));
    *(ushort4*)(hs + off) = o;
}

// ---------- layernorm bf16(ws) -> bf16 ----------
__global__ __launch_bounds__(256) void k_ln_bf(
    const u16* __restrict__ in, const void* __restrict__ w, const void* __restrict__ b,
    u16* __restrict__ out, const int* __restrict__ hdr)
{
    __shared__ float sm[16];
    const int dt = hdr[0];
    int tok = blockIdx.x, tid = threadIdx.x;
    int c = tid * 4;
    size_t off = (size_t)tok * 1024 + c;
    ushort4 xv = *(const ushort4*)(in + off);
    float v0 = b2f(xv.x), v1 = b2f(xv.y), v2 = b2f(xv.z), v3 = b2f(xv.w);
    float s = v0 + v1 + v2 + v3;
    float q = v0*v0 + v1*v1 + v2*v2 + v3*v3;
    block_reduce2(s, q, sm);
    float mean = s * (1.f/1024.f);
    float var  = q * (1.f/1024.f) - mean*mean;
    float rs = rsqrtf(var + 1e-5f);
    ushort4 o;
    o.x = f2b((v0-mean)*rs*ldv(w,c+0,dt) + ldv(b,c+0,dt));
    o.y = f2b((v1-mean)*rs*ldv(w,c+1,dt) + ldv(b,c+1,dt));
    o.z = f2b((v2-mean)*rs*ldv(w,c+2,dt) + ldv(b,c+2,dt));
    o.w = f2b((v3-mean)*rs*ldv(w,c+3,dt) + ldv(b,c+3,dt));
    *(ushort4*)(out + off) = o;
}

// ---------- weight transpose (kept for the two big FFN weights) ----------
__global__ __launch_bounds__(256) void k_tr(
    const void* __restrict__ W, int K, int N, u16* __restrict__ WT,
    const int* __restrict__ hdr)
{
    const int dt = hdr[0];
    __shared__ u16 t[32][33];
    int n0 = blockIdx.x * 32, k0 = blockIdx.y * 32;
    int tx = threadIdx.x & 31, ty = threadIdx.x >> 5;   // 32 x 8
#pragma unroll
    for (int r = 0; r < 32; r += 8) {
        int k = k0 + ty + r;
        t[ty + r][tx] = f2b(ldv(W, (size_t)k * N + n0 + tx, dt));
    }
    __syncthreads();
#pragma unroll
    for (int r = 0; r < 32; r += 8) {
        int n = n0 + ty + r;
        WT[(size_t)n * K + k0 + tx] = t[tx][ty + r];
    }
}

// ---------- fused transpose of ALL small weights in ONE launch ----------
// layout (u16 elements):
//   wTo   : [1024][1024]  W_o^T
//   wTrkv : [3072][1024]  W_r^T | W_k^T | W_v^T
//   BTu   : [256][1024]   w1^T | a1^T | g1^T
//   BT2   : [3072][128]   w2^T | a2^T | g2^T  (ld 128; K=64 groups use cols 0..63)
__global__ __launch_bounds__(256) void k_tr_all(
    const void* __restrict__ Wo, const void* __restrict__ Wr,
    const void* __restrict__ Wk, const void* __restrict__ Wv,
    const void* __restrict__ w1, const void* __restrict__ a1,
    const void* __restrict__ g1,
    const void* __restrict__ w2, const void* __restrict__ a2,
    const void* __restrict__ g2,
    u16* __restrict__ wTo, u16* __restrict__ wTrkv,
    u16* __restrict__ BTu, u16* __restrict__ BT2,
    const int* __restrict__ hdr)
{
    int bid = blockIdx.x;
    const void* W; int Nd, ldwt, xt, yt; u16* dst;
    if (bid < 4096) {
        int t = bid & 1023, w = bid >> 10;
        W = (w == 0) ? Wo : (w == 1) ? Wr : (w == 2) ? Wk : Wv;
        Nd = 1024; ldwt = 1024;
        dst = (w == 0) ? wTo : wTrkv + (size_t)(w - 1) * 1024 * 1024;
        xt = t & 31; yt = t >> 5;
    } else if (bid < 4352) {
        int t = bid - 4096;
        ldwt = 1024;
        if (t < 64)       { W = w1; dst = BTu;              Nd = 64;  xt = t & 1; yt = t >> 1; }
        else if (t < 128) { W = a1; dst = BTu + 64 * 1024;  Nd = 64;  t -= 64;  xt = t & 1; yt = t >> 1; }
        else              { W = g1; dst = BTu + 128 * 1024; Nd = 128; t -= 128; xt = t & 3; yt = t >> 2; }
    } else {
        int t = bid - 4352;
        ldwt = 128; Nd = 1024;
        if (t < 64)       { W = w2; dst = BT2; xt = t & 31; yt = t >> 5; }
        else if (t < 128) { W = a2; dst = BT2 + 1024 * 128; t -= 64;  xt = t & 31; yt = t >> 5; }
        else              { W = g2; dst = BT2 + 2048 * 128; t -= 128; xt = t & 31; yt = t >> 5; }
    }
    const int dt = hdr[0];
    __shared__ u16 tb[32][33];
    int n0 = xt * 32, k0 = yt * 32;
    int tx = threadIdx.x & 31, ty = threadIdx.x >> 5;
#pragma unroll
    for (int r = 0; r < 32; r += 8)
        tb[ty + r][tx] = f2b(ldv(W, (size_t)(k0 + ty + r) * Nd + n0 + tx, dt));
    __syncthreads();
#pragma unroll
    for (int r = 0; r < 32; r += 8)
        dst[(size_t)(n0 + ty + r) * ldwt + k0 + tx] = tb[tx][ty + r];
}

// ---------- shared epilogue ----------
// modes: 1=raw 2=tanh 3=sigm 4=exp(-0.6065*sigm(v+bias)) 5=sigm(v+bias)
//        6=F32 OUT v+add 7=relu^2 8=bf16 v+add
__device__ __forceinline__ void mf_epi(
    void* D, int ldd, int mode, const void* bias,
    const u16* add, int ldadd, int dt,
    int row, int colD, int colB, float v)
{
    size_t di = (size_t)row * ldd + colD;
    if (mode == 6) {
        ((float*)D)[di] = v + b2f(add[(size_t)row * ldadd + colD]);
        return;
    }
    float rr;
    switch (mode) {
        default: rr = v; break;
        case 2: rr = tanhf(v); break;
        case 3: rr = sigm(v); break;
        case 4: rr = __expf(-0.6065306597126334f * sigm(v + ldv(bias, colB, dt))); break;
        case 5: rr = sigm(v + ldv(bias, colB, dt)); break;
        case 7: { float t = fmaxf(v, 0.f); rr = t * t; } break;
        case 8: rr = v + b2f(add[(size_t)row * ldadd + colD]); break;
    }
    ((u16*)D)[di] = f2b(rr);
}

// ---------- MFMA GEMM: 128x128 tile (FFN-key, N=4096) ----------
__global__ __launch_bounds__(256, 2) void k_mf(
    const u16* __restrict__ A, int lda, const void* __restrict__ mixc,
    const u16* __restrict__ BT,
    void* __restrict__ D, int ldd,
    int K, int mode,
    const void* __restrict__ bias,
    const u16* __restrict__ add, int ldadd, const int* __restrict__ hdr)
{
    __shared__ u16 As[128 * 40];
    __shared__ u16 Bs[128 * 40];
    const int dt = hdr[0];
    const int tid = threadIdx.x;
    const int m0 = blockIdx.y * 128, n0 = blockIdx.x * 128;
    const int wid = tid >> 6, lane = tid & 63;
    const int wr = wid >> 1, wc = wid & 1;
    const int lg = lane >> 4, lc = lane & 15;
    const int srow = tid >> 1, shalf = tid & 1;

    f32x4 acc[4][4];
#pragma unroll
    for (int i = 0; i < 4; ++i)
#pragma unroll
        for (int j = 0; j < 4; ++j) acc[i][j] = (f32x4)0.f;

    for (int kb = 0; kb < K; kb += 32) {
        {
            int gr = m0 + srow;
            const u16* ap = A + (size_t)gr * lda + kb + 16 * shalf;
            us8 c1 = *(const us8*)ap;
            us8 c2 = *(const us8*)(ap + 8);
            if (mixc) {
                const u16* pp = ap - ((gr & 2047) ? lda : 0);
                float pz = (gr & 2047) ? 1.f : 0.f;
                us8 p1 = *(const us8*)pp;
                us8 p2 = *(const us8*)(pp + 8);
                int kbase = kb + 16 * shalf;
#pragma unroll
                for (int e = 0; e < 8; ++e) {
                    float cu1 = b2f(c1[e]), cu2 = b2f(c2[e]);
                    c1[e] = f2b(cu1 + (pz * b2f(p1[e]) - cu1) * ldv(mixc, kbase + e, dt));
                    c2[e] = f2b(cu2 + (pz * b2f(p2[e]) - cu2) * ldv(mixc, kbase + 8 + e, dt));
                }
            }
            u16* dst = As + srow * 40 + 16 * shalf;
            *(us8*)dst = c1;
            *(us8*)(dst + 8) = c2;
        }
        {
            const u16* bp = BT + (size_t)(n0 + srow) * K + kb + 16 * shalf;
            u16* dst = Bs + srow * 40 + 16 * shalf;
            *(us8*)dst = *(const us8*)bp;
            *(us8*)(dst + 8) = *(const us8*)(bp + 8);
        }
        __syncthreads();
        bf16x8 af[4], bf[4];
#pragma unroll
        for (int fm = 0; fm < 4; ++fm) {
            const u16* p = As + (wr * 64 + fm * 16 + lc) * 40 + lg * 8;
            union { us8 s; bf16x8 v; } u;
            u.s = *(const us8*)p;
            af[fm] = u.v;
        }
#pragma unroll
        for (int fc = 0; fc < 4; ++fc) {
            const u16* p = Bs + (wc * 64 + fc * 16 + lc) * 40 + lg * 8;
            union { us8 s; bf16x8 v; } u;
            u.s = *(const us8*)p;
            bf[fc] = u.v;
        }
#pragma unroll
        for (int fm = 0; fm < 4; ++fm)
#pragma unroll
            for (int fc = 0; fc < 4; ++fc)
                acc[fm][fc] = __builtin_amdgcn_mfma_f32_16x16x32_bf16(
                    af[fm], bf[fc], acc[fm][fc], 0, 0, 0);
        __syncthreads();
    }

#pragma unroll
    for (int fm = 0; fm < 4; ++fm)
#pragma unroll
        for (int fc = 0; fc < 4; ++fc)
#pragma unroll
            for (int r = 0; r < 4; ++r) {
                int row = m0 + wr * 64 + fm * 16 + lg * 4 + r;
                int col = n0 + wc * 64 + fc * 16 + lc;
                mf_epi(D, ldd, mode, bias, add, ldadd, dt, row, col, col, acc[fm][fc][r]);
            }
}

// ---------- grouped MFMA GEMM: 64x64 tile, per-n-group params ----------
// group g selected by n0 vs boundaries b1/b2 (wave-uniform). Per group:
// mix vector, K, A-col-offset, D slab (+col base), mode, bias. Verified
// k_mf64 body; merges W_r|W_k|W_v, the 3 lora-ups, the 3 lora-downs each
// into ONE launch. Bit-identical math per output.
__global__ __launch_bounds__(256, 4) void k_mf64g(
    const u16* __restrict__ A, int lda,
    const void* mx0, const void* mx1, const void* mx2,
    const u16* __restrict__ BT, int ldbt,
    void* D0, void* D1, void* D2, int ldd,
    int b1, int b2,
    int K0, int K1, int K2,
    int ao0, int ao1, int ao2,
    int dcb0, int dcb1, int dcb2,
    int md0, int md1, int md2,
    const void* bs0, const void* bs1, const void* bs2,
    const u16* __restrict__ add, int ldadd, const int* __restrict__ hdr)
{
    __shared__ u16 As[64 * 40];
    __shared__ u16 Bs[64 * 40];
    const int dt = hdr[0];
    const int tid = threadIdx.x;
    const int m0 = blockIdx.y * 64, n0 = blockIdx.x * 64;
    const int g = (n0 >= b2) ? 2 : (n0 >= b1) ? 1 : 0;
    const void* mixc = (g == 0) ? mx0 : (g == 1) ? mx1 : mx2;
    void* D    = (g == 0) ? D0  : (g == 1) ? D1  : D2;
    const int Kg   = (g == 0) ? K0  : (g == 1) ? K1  : K2;
    const int aoff = (g == 0) ? ao0 : (g == 1) ? ao1 : ao2;
    const int dcb  = (g == 0) ? dcb0: (g == 1) ? dcb1: dcb2;
    const int mode = (g == 0) ? md0 : (g == 1) ? md1 : md2;
    const void* bias = (g == 0) ? bs0 : (g == 1) ? bs1 : bs2;
    const int gbase = (g == 0) ? 0 : (g == 1) ? b1 : b2;
    const int wid = tid >> 6, lane = tid & 63;
    const int wr = wid >> 1, wc = wid & 1;
    const int lg = lane >> 4, lc = lane & 15;
    const int srow = tid >> 2, sq = tid & 3;

    f32x4 acc[2][2];
#pragma unroll
    for (int i = 0; i < 2; ++i)
#pragma unroll
        for (int j = 0; j < 2; ++j) acc[i][j] = (f32x4)0.f;

    for (int kb = 0; kb < Kg; kb += 32) {
        {
            int gr = m0 + srow;
            const u16* ap = A + (size_t)gr * lda + aoff + kb + 8 * sq;
            us8 c1 = *(const us8*)ap;
            if (mixc) {
                const u16* pp = ap - ((gr & 2047) ? lda : 0);
                float pz = (gr & 2047) ? 1.f : 0.f;
                us8 p1 = *(const us8*)pp;
                int kbase = kb + 8 * sq;
#pragma unroll
                for (int e = 0; e < 8; ++e) {
                    float cu = b2f(c1[e]);
                    c1[e] = f2b(cu + (pz * b2f(p1[e]) - cu) * ldv(mixc, kbase + e, dt));
                }
            }
            *(us8*)(As + srow * 40 + 8 * sq) = c1;
        }
        {
            const u16* bp = BT + (size_t)(n0 + srow) * ldbt + kb + 8 * sq;
            *(us8*)(Bs + srow * 40 + 8 * sq) = *(const us8*)bp;
        }
        __syncthreads();
        bf16x8 af[2], bf[2];
#pragma unroll
        for (int fm = 0; fm < 2; ++fm) {
            const u16* p = As + (wr * 32 + fm * 16 + lc) * 40 + lg * 8;
            union { us8 s; bf16x8 v; } u;
            u.s = *(const us8*)p;
            af[fm] = u.v;
        }
#pragma unroll
        for (int fc = 0; fc < 2; ++fc) {
            const u16* p = Bs + (wc * 32 + fc * 16 + lc) * 40 + lg * 8;
            union { us8 s; bf16x8 v; } u;
            u.s = *(const us8*)p;
            bf[fc] = u.v;
        }
#pragma unroll
        for (int fm = 0; fm < 2; ++fm)
#pragma unroll
            for (int fc = 0; fc < 2; ++fc)
                acc[fm][fc] = __builtin_amdgcn_mfma_f32_16x16x32_bf16(
                    af[fm], bf[fc], acc[fm][fc], 0, 0, 0);
        __syncthreads();
    }

#pragma unroll
    for (int fm = 0; fm < 2; ++fm)
#pragma unroll
        for (int fc = 0; fc < 2; ++fc)
#pragma unroll
            for (int r = 0; r < 4; ++r) {
                int row = m0 + wr * 32 + fm * 16 + lg * 4 + r;
                int col = n0 + wc * 32 + fc * 16 + lc;
                mf_epi(D, ldd, mode, bias, add, ldadd, dt,
                       row, col - dcb, col - gbase, acc[fm][fc][r]);
            }
}

// ---------- per-head prep ----------
__global__ __launch_bounds__(256) void k_prep(
    u16* __restrict__ k_bf, const u16* __restrict__ a_buf,
    const void* __restrict__ k_k, const void* __restrict__ k_a,
    u16* __restrict__ av, u16* __restrict__ bv, const int* __restrict__ hdr)
{
    const int dt = hdr[0];
    int ht = blockIdx.x * 4 + (threadIdx.x >> 6);
    int j = threadIdx.x & 63;
    int tok = ht >> 4, h = ht & 15, n = h * 64 + j;
    size_t idx = (size_t)tok * 1024 + n;
    float kv = b2f(k_bf[idx]);
    float a  = b2f(a_buf[idx]);
    float kk = kv * ldv(k_k, n, dt);
    float ss = wave_sum(kk * kk);
    float den = fmaxf(sqrtf(ss), 1e-12f);
    float kkn = kk / den;
    k_bf[idx] = f2b(kv * (1.f + (a - 1.f) * ldv(k_a, n, dt)));
    av[idx] = f2b(-kkn);
    bv[idx] = f2b(kkn * a);
}

// ---------- recurrence v9: LDS pipeline + cross-step 4-way ladder ----------
#define KREC_LOADS(T0)                                                          \
    {                                                                           \
        _Pragma("unroll")                                                       \
        for (int it = 0; it < 10; ++it) {                                       \
            const u16* sp = (it < 2) ? r_bf : (it < 4) ? dcy                    \
                          : (it < 6) ? km  : (it < 8) ? av : bv;                \
            int i = ((it & 1) << 8) + tid;                                      \
            int step = i >> 5, dp = i & 31;                                     \
            stg[it] = *(const uint32_t*)(sp +                                   \
                (size_t)(tbase + (T0) + step) * 1024 + h * 64 + dp * 2);        \
        }                                                                       \
        if (tid < 64)                                                           \
            stg[10] = v32[(size_t)(tbase + (T0) + (tid >> 2)) * 512             \
                          + h * 32 + jj0 + (tid & 3)];                          \
    }
#define KREC_WRITES(DST)                                                        \
    {                                                                           \
        u16* b_ = (u16*)&lds[DST][0];                                           \
        _Pragma("unroll")                                                       \
        for (int it = 0; it < 10; ++it) {                                       \
            int s = it >> 1;                                                    \
            int i = ((it & 1) << 8) + tid;                                      \
            int step = i >> 5, dp = i & 31;                                     \
            b_[s * 1280 + (2 * dp) * 20 + step]     = (u16)(stg[it] & 0xFFFFu); \
            b_[s * 1280 + (2 * dp + 1) * 20 + step] = (u16)(stg[it] >> 16);     \
        }                                                                       \
        if (tid < 64) lds[DST][3200 + (tid & 3) * 16 + (tid >> 2)] = stg[10];   \
    }
__device__ __forceinline__ float bfsel(uint32_t u, int hi) {
    return hi ? __uint_as_float(u & 0xFFFF0000u) : __uint_as_float(u << 16);
}
__global__ __launch_bounds__(256) void k_rec(
    const u16* __restrict__ r_bf, const u16* __restrict__ dcy,
    const u16* __restrict__ km, const u16* __restrict__ v_bf,
    const u16* __restrict__ av, const u16* __restrict__ bv,
    u16* __restrict__ o_buf)
{
    const int T = 2048;
    const int tid = threadIdx.x;
    int rq = blockIdx.x & 7, q = blockIdx.x >> 3;
    int wid = tid >> 6, lane = tid & 63;
    int bh = rq * 4 + (q >> 3);
    int jj0 = (q & 7) * 4;
    int jj = jj0 + wid;
    int b = bh >> 4, h = bh & 15;
    int tbase = b * T;
    const uint32_t* v32 = (const uint32_t*)v_bf;
    uint32_t* o32 = (uint32_t*)o_buf;
    size_t oidx = (size_t)tbase * 512 + h * 32 + jj;

    __shared__ uint32_t lds[2][3264];
    uint32_t stg[11];

    KREC_LOADS(0)
    KREC_WRITES(0)
    __syncthreads();

    float S0 = 0.f, S1 = 0.f;
    float pv0 = 0.f, pv1 = 0.f;
    for (int c = 0; c < 128; ++c) {
        int cur = c & 1;
        bool more = (c + 1) < 128;
        if (more) KREC_LOADS((c + 1) * 16)
        const char* lbb = (const char*)&lds[cur][0];
        u32x2 rA[4], dA[4], kA[4], aA[4], bA[4];
        u32x4v vA[4];
#pragma unroll
        for (int qq = 0; qq < 4; ++qq) {
            rA[qq] = *(const u32x2*)(lbb + 0 * 2560 + lane * 40 + qq * 8);
            dA[qq] = *(const u32x2*)(lbb + 1 * 2560 + lane * 40 + qq * 8);
            kA[qq] = *(const u32x2*)(lbb + 2 * 2560 + lane * 40 + qq * 8);
            aA[qq] = *(const u32x2*)(lbb + 3 * 2560 + lane * 40 + qq * 8);
            bA[qq] = *(const u32x2*)(lbb + 4 * 2560 + lane * 40 + qq * 8);
            vA[qq] = *(const u32x4v*)(lbb + 12800 + wid * 64 + qq * 16);
        }
#pragma unroll
        for (int step = 0; step < 16; ++step) {
            const int qq = step >> 2, ee = (step >> 1) & 1, hi = step & 1;
            float rf  = bfsel(rA[qq][ee], hi);
            float df  = bfsel(dA[qq][ee], hi);
            float kf  = bfsel(kA[qq][ee], hi);
            float af  = bfsel(aA[qq][ee], hi);
            float bf_ = bfsel(bA[qq][ee], hi);
            uint32_t vv = vA[qq][step & 3];
            float vf0 = __uint_as_float(vv << 16);
            float vf1 = __uint_as_float(vv & 0xFFFF0000u);
            float m0 = af * S0, m1 = af * S1;
            float q0 = pv0, q1 = pv1;
            dpp_sum64_x4(m0, m1, q0, q1);
            float sa0 = __int_as_float(__builtin_amdgcn_readlane(__float_as_int(m0), 63));
            float sa1 = __int_as_float(__builtin_amdgcn_readlane(__float_as_int(m1), 63));
            if (step > 0 || c > 0) {
                if (lane == 63)
                    o32[oidx] = (uint32_t)f2b(q0) | ((uint32_t)f2b(q1) << 16);
                oidx += 512;
            }
            float X0 = fmaf(kf, vf0, S0 * df);
            float X1 = fmaf(kf, vf1, S1 * df);
            S0 = fmaf(bf_, sa0, X0);
            S1 = fmaf(bf_, sa1, X1);
            pv0 = rf * S0;
            pv1 = rf * S1;
        }
        if (more) KREC_WRITES(cur ^ 1)
        __syncthreads();
    }
    {
        float q0 = pv0, q1 = pv1, z0 = 0.f, z1 = 0.f;
        dpp_sum64_x4(q0, q1, z0, z1);
        if (lane == 63)
            o32[oidx] = (uint32_t)f2b(q0) | ((uint32_t)f2b(q1) << 16);
    }
}

// ---------- groupnorm + bonus + gate ----------
__global__ __launch_bounds__(256) void k_post(
    const u16* __restrict__ o_buf, const u16* __restrict__ r_bf,
    const u16* __restrict__ km, const u16* __restrict__ v_bf,
    const u16* __restrict__ g_buf, const void* __restrict__ r_k,
    const void* __restrict__ gnw, const void* __restrict__ gnb,
    u16* __restrict__ ao, const int* __restrict__ hdr)
{
    const int dt = hdr[0];
    int ht = blockIdx.x * 4 + (threadIdx.x >> 6);
    int j = threadIdx.x & 63;
    int tok = ht >> 4, h = ht & 15, n = h * 64 + j;
    size_t idx = (size_t)tok * 1024 + n;
    float o = b2f(o_buf[idx]);
    float mu = wave_sum(o) * (1.f/64.f);
    float d = o - mu;
    float var = wave_sum(d * d) * (1.f/64.f);
    float og = d * rsqrtf(var + 6.4e-4f) * ldv(gnw, n, dt) + ldv(gnb, n, dt);
    float r = b2f(r_bf[idx]), kmv = b2f(km[idx]), v = b2f(v_bf[idx]);
    float bonus = wave_sum(r * kmv * ldv(r_k, n, dt));
    float val = (og + bonus * v) * b2f(g_buf[idx]);
    ao[idx] = f2b(val);
}

// ---------- host ----------
extern "C" void kernel_launch(void* const* d_in, const int* in_sizes, int n_in,
                              void* d_out, int out_size, void* d_ws, size_t ws_size,
                              hipStream_t stream) {
    (void)in_sizes; (void)n_in; (void)out_size; (void)ws_size;
    const void* xP     = d_in[0];
    const void* pre_w  = d_in[1];
    const void* pre_b  = d_in[2];
    const void* attn_w = d_in[3];
    const void* attn_b = d_in[4];
    const void* ffn_w  = d_in[5];
    const void* ffn_b  = d_in[6];
    const void* x_r    = d_in[7];
    const void* x_w    = d_in[8];
    const void* x_k    = d_in[9];
    const void* x_v    = d_in[10];
    const void* x_a    = d_in[11];
    const void* x_g    = d_in[12];
    const void* W_r    = d_in[13];
    const void* W_k    = d_in[14];
    const void* W_v    = d_in[15];
    const void* W_o    = d_in[16];
    const void* w1     = d_in[17];
    const void* w2     = d_in[18];
    const void* w_b    = d_in[19];
    const void* a1     = d_in[20];
    const void* a2     = d_in[21];
    const void* a_b    = d_in[22];
    const void* g1     = d_in[23];
    const void* g2     = d_in[24];
    const void* k_k    = d_in[25];
    const void* k_a    = d_in[26];
    const void* r_k    = d_in[27];
    const void* gn_w   = d_in[28];
    const void* gn_b   = d_in[29];
    const void* ffn_xk = d_in[30];
    const void* WkeyP  = d_in[31];
    const void* WvalP  = d_in[32];

    char* ws = (char*)d_ws;
    const size_t SL = 8388608ull;          // [4096][1024] bf16 slab
    int* hdr    = (int*)(ws + 0);
    u16* hs     = (u16*)(ws + 4096 + SL*0);
    u16* resid1 = (u16*)(ws + 4096 + SL*1);
    u16* dcy    = (u16*)(ws + 4096 + SL*2);
    u16* r_bf   = (u16*)(ws + 4096 + SL*3);
    u16* k_bf   = (u16*)(ws + 4096 + SL*4);
    u16* v_bf   = (u16*)(ws + 4096 + SL*5);
    u16* av_bf  = (u16*)(ws + 4096 + SL*6);
    u16* bv_bf  = (u16*)(ws + 4096 + SL*7);
    u16* a_buf  = (u16*)(ws + 4096 + SL*8);
    u16* g_buf  = (u16*)(ws + 4096 + SL*9);
    u16* tmp    = (u16*)(ws + 4096 + SL*10);               // [4096][256] 2MB
    char* wTB   = ws + 4096 + SL*10 + 2097152;             // 9.25MB packed
    u16* wTo    = (u16*)(wTB);                             // 2MB
    u16* wTrkv  = (u16*)(wTB + 2097152);                   // 6MB
    u16* BTu    = (u16*)(wTB + 8388608);                   // 0.5MB
    u16* BT2    = (u16*)(wTB + 8912896);                   // 0.75MB
    u16* wTbig  = (u16*)(wTB);                             // 8MB reuse (WkeyT/WvalT)
    // overlays (later lifetimes)
    u16* o_buf  = a_buf;
    u16* ao_in  = bv_bf;
    u16* hid2   = dcy;
    u16* hs2    = hs;
    u16* ffh    = r_bf;

    dim3 blk(256);
    const int HUGE = 1 << 30;
    k_probe<<<1, blk, 0, stream>>>((const u16*)xP, (const u16*)WkeyP, (const u16*)WvalP, hdr);
    k_ln_in<<<4096, blk, 0, stream>>>(xP, WkeyP, WvalP, pre_w, pre_b, attn_w, attn_b, resid1, hs, hdr);

    // all small-weight transposes in one launch
    k_tr_all<<<4608, blk, 0, stream>>>(W_o, W_r, W_k, W_v, w1, a1, g1, w2, a2, g2,
                                       wTo, wTrkv, BTu, BT2, hdr);

    // r|k|v projections (fused token-shift mix) -- ONE launch, N=3072
    k_mf64g<<<dim3(48, 64), blk, 0, stream>>>(hs, 1024, x_r, x_k, x_v,
        wTrkv, 1024, r_bf, k_bf, v_bf, 1024, 1024, 2048,
        1024, 1024, 1024, 0, 0, 0, 0, 1024, 2048,
        1, 1, 1, nullptr, nullptr, nullptr, nullptr, 0, hdr);

    // lora ups w|a|g -> tmp[4096][256] -- ONE launch, N=256
    k_mf64g<<<dim3(4, 64), blk, 0, stream>>>(hs, 1024, x_w, x_a, x_g,
        BTu, 1024, tmp, tmp, tmp, 256, 64, 128,
        1024, 1024, 1024, 0, 0, 0, 0, 0, 0,
        2, 1, 3, nullptr, nullptr, nullptr, nullptr, 0, hdr);

    // lora downs -> dcy|a_buf|g_buf -- ONE launch, N=3072 (K=64/64/128)
    k_mf64g<<<dim3(48, 64), blk, 0, stream>>>(tmp, 256, nullptr, nullptr, nullptr,
        BT2, 128, dcy, a_buf, g_buf, 1024, 1024, 2048,
        64, 64, 128, 0, 64, 128, 0, 1024, 2048,
        4, 5, 1, w_b, a_b, nullptr, nullptr, 0, hdr);

    k_prep<<<16384, blk, 0, stream>>>(k_bf, a_buf, k_k, k_a, av_bf, bv_bf, hdr);
    k_rec<<<256, blk, 0, stream>>>(r_bf, dcy, k_bf, v_bf, av_bf, bv_bf, o_buf);
    k_post<<<16384, blk, 0, stream>>>(o_buf, r_bf, k_bf, v_bf, g_buf, r_k, gn_w, gn_b, ao_in, hdr);

    // output projection + residual -> hid2 (bf16)
    k_mf64g<<<dim3(16, 64), blk, 0, stream>>>(ao_in, 1024, nullptr, nullptr, nullptr,
        wTo, 1024, hid2, hid2, hid2, 1024, HUGE, HUGE,
        1024, 1024, 1024, 0, 0, 0, 0, 0, 0,
        8, 8, 8, nullptr, nullptr, nullptr, resid1, 1024, hdr);

    // FFN; final GEMM writes FLOAT32 output
    k_ln_bf<<<4096, blk, 0, stream>>>(hid2, ffn_w, ffn_b, hs2, hdr);
    k_tr<<<dim3(128, 32), blk, 0, stream>>>(WkeyP, 1024, 4096, wTbig, hdr);
    k_mf<<<dim3(32, 32), blk, 0, stream>>>(hs2, 1024, ffn_xk, wTbig, ffh, 4096, 1024, 7, nullptr, nullptr, 0, hdr);
    k_tr<<<dim3(32, 128), blk, 0, stream>>>(WvalP, 4096, 1024, wTbig, hdr);
    k_mf64g<<<dim3(16, 64), blk, 0, stream>>>(ffh, 4096, nullptr, nullptr, nullptr,
        wTbig, 4096, d_out, d_out, d_out, 1024, HUGE, HUGE,
        4096, 4096, 4096, 0, 0, 0, 0, 0, 0,
        6, 6, 6, nullptr, nullptr, nullptr, hid2, 1024, hdr);
}